// Round 1
// baseline (1405.451 us; speedup 1.0000x reference)
//
#include <hip/hip_runtime.h>
#include <math.h>

#define N_NODES 50000
#define N_EDGES 1600000
#define DIN 16
#define H 256
#define RPB 16
#define LN_EPS 1e-5f

// ---------------- edge dtype detect + convert ----------------
__global__ void k_detect(const void* ei, int* flag) {
    const long long* p = (const long long*)ei;
    bool is64 = true;
    for (int i = 0; i < 8; ++i) {
        long long v = p[i];
        if (v < 0 || v >= N_NODES) is64 = false;
    }
    *flag = is64 ? 1 : 0;
}

__global__ void k_convert(const void* ei, const int* flag, int* es, int* ed) {
    int e = blockIdx.x * blockDim.x + threadIdx.x;
    if (e >= N_EDGES) return;
    if (*flag) {
        const long long* p = (const long long*)ei;
        es[e] = (int)p[e];
        ed[e] = (int)p[N_EDGES + e];
    } else {
        const int* p = (const int*)ei;
        es[e] = p[e];
        ed[e] = p[N_EDGES + e];
    }
}

// ---------------- degree + normalization ----------------
__global__ void k_init(float* deg, int* cnt) {
    int i = blockIdx.x * blockDim.x + threadIdx.x;
    if (i < N_NODES) { deg[i] = 2.0f; cnt[i] = 0; }
}

__global__ void k_deg(const int* ed, const float* ew, float* deg, int* cnt) {
    int e = blockIdx.x * blockDim.x + threadIdx.x;
    if (e >= N_EDGES) return;
    int d = ed[e];
    atomicAdd(&deg[d], ew[e]);
    atomicAdd(&cnt[d], 1);
}

__global__ void k_rsqrt(float* deg) {
    int i = blockIdx.x * blockDim.x + threadIdx.x;
    if (i < N_NODES) deg[i] = rsqrtf(deg[i]);   // deg >= 2 always
}

// ---------------- exclusive scan of cnt -> offs (chunk 1024) ----------------
__global__ void k_scan1(const int* cnt, int* bsum) {
    __shared__ int ws_[4];
    int b = blockIdx.x, t = threadIdx.x;
    int s = 0;
    for (int k = 0; k < 4; ++k) {
        int idx = b * 1024 + k * 256 + t;
        if (idx < N_NODES) s += cnt[idx];
    }
    for (int d = 32; d; d >>= 1) s += __shfl_down(s, d, 64);
    if ((t & 63) == 0) ws_[t >> 6] = s;
    __syncthreads();
    if (t == 0) bsum[b] = ws_[0] + ws_[1] + ws_[2] + ws_[3];
}

__global__ void k_scan2(const int* bsum, int* bsoff, int* offs, int nblk) {
    if (threadIdx.x == 0) {
        int run = 0;
        for (int i = 0; i < nblk; ++i) { bsoff[i] = run; run += bsum[i]; }
        offs[N_NODES] = run;
    }
}

__global__ void k_scan3(const int* cnt, const int* bsoff, int* offs) {
    __shared__ int wsum[4];
    int b = blockIdx.x, t = threadIdx.x;
    int lane = t & 63, wv = t >> 6;
    int base = b * 1024 + t * 4;
    int v[4];
    for (int k = 0; k < 4; ++k) {
        int idx = base + k;
        v[k] = (idx < N_NODES) ? cnt[idx] : 0;
    }
    int ts = v[0] + v[1] + v[2] + v[3];
    int sc = ts;
    for (int d = 1; d < 64; d <<= 1) {
        int u = __shfl_up(sc, d, 64);
        if (lane >= d) sc += u;
    }
    if (lane == 63) wsum[wv] = sc;
    __syncthreads();
    int wpre = 0;
    for (int i = 0; i < wv; ++i) wpre += wsum[i];
    int ex = wpre + sc - ts + bsoff[b];
    for (int k = 0; k < 4; ++k) {
        int idx = base + k;
        if (idx < N_NODES) offs[idx] = ex;
        ex += v[k];
    }
}

__global__ void k_cursor(const int* offs, int* cursor) {
    int i = blockIdx.x * blockDim.x + threadIdx.x;
    if (i < N_NODES) cursor[i] = offs[i];
}

__global__ void k_fill(const int* es, const int* ed, const float* ew, const float* dis,
                       int* cursor, int* csr_s, float* csr_c) {
    int e = blockIdx.x * blockDim.x + threadIdx.x;
    if (e >= N_EDGES) return;
    int s = es[e], d = ed[e];
    int p = atomicAdd(&cursor[d], 1);
    csr_s[p] = s;
    csr_c[p] = dis[s] * ew[e] * dis[d];
}

// ---------------- transpose Wih [768,256] -> WihT [256,768] ----------------
__global__ void k_wih_t(const float* Wih, float* WihT) {
    int idx = blockIdx.x * blockDim.x + threadIdx.x;
    if (idx >= 768 * 256) return;
    int j = idx / 256, k = idx % 256;
    WihT[k * 768 + j] = Wih[idx];
}

// ---------------- aggregation in DIN space (layer 1) ----------------
__global__ __launch_bounds__(256) void k_agg0(const float* x, const int* offs, const int* csr_s,
                                              const float* csr_c, const float* dis, float* agg0) {
    int t = threadIdx.x;
    int r = blockIdx.x * 16 + (t >> 4);
    int dd = t & 15;
    float di = dis[r];
    float acc = 2.0f * di * di * x[(long long)r * DIN + dd];
    int e0 = offs[r], e1 = offs[r + 1];
    for (int e = e0; e < e1; ++e) {
        int s = csr_s[e];
        float c = csr_c[e];
        acc = fmaf(c, x[(long long)s * DIN + dd], acc);
    }
    agg0[(long long)r * DIN + dd] = acc;
}

// ---------------- SpMM in H space (layer 2 aggregation) ----------------
__global__ __launch_bounds__(256) void k_spmm(const float* hin, float* hout, const int* offs,
                                              const int* csr_s, const float* csr_c, const float* dis) {
    int t = threadIdx.x;
    int wv = t >> 6, lane = t & 63;
    int row = blockIdx.x * 4 + wv;
    const float4* h4 = (const float4*)hin;
    float di = dis[row];
    float cself = 2.0f * di * di;
    float4 v = h4[(long long)row * 64 + lane];
    float4 acc;
    acc.x = cself * v.x; acc.y = cself * v.y; acc.z = cself * v.z; acc.w = cself * v.w;
    int e0 = offs[row], e1 = offs[row + 1];
    for (int e = e0; e < e1; ++e) {
        int s = csr_s[e];
        float c = csr_c[e];
        float4 u = h4[(long long)s * 64 + lane];
        acc.x = fmaf(c, u.x, acc.x);
        acc.y = fmaf(c, u.y, acc.y);
        acc.z = fmaf(c, u.z, acc.z);
        acc.w = fmaf(c, u.w, acc.w);
    }
    ((float4*)hout)[(long long)row * 64 + lane] = acc;
}

// ---------------- row GEMM (K -> 256) + bias + LN [+ relu] ----------------
template <int K, bool RELU>
__global__ __launch_bounds__(256) void k_gemm_ln(const float* in, float* out, const float* W,
                                                 const float* bias, const float* g, const float* be) {
    __shared__ float s[RPB][H + 1];
    __shared__ float smu[RPB], srs[RPB];
    int t = threadIdx.x;
    long long rowbase = (long long)blockIdx.x * RPB;
    for (int idx = t; idx < RPB * K; idx += 256) {
        int r = idx / K, k = idx % K;
        s[r][k] = in[(rowbase + r) * K + k];
    }
    __syncthreads();
    float acc[RPB];
    float bb0 = bias[t];
#pragma unroll
    for (int r = 0; r < RPB; ++r) acc[r] = bb0;
    for (int k = 0; k < K; ++k) {
        float wv = W[k * H + t];
#pragma unroll
        for (int r = 0; r < RPB; ++r) acc[r] = fmaf(s[r][k], wv, acc[r]);
    }
    __syncthreads();
#pragma unroll
    for (int r = 0; r < RPB; ++r) s[r][t] = acc[r];
    __syncthreads();
    int lane = t & 63, wv2 = t >> 6;
    for (int rr = wv2; rr < RPB; rr += 4) {
        float v0 = s[rr][lane], v1 = s[rr][lane + 64], v2 = s[rr][lane + 128], v3 = s[rr][lane + 192];
        float sm = v0 + v1 + v2 + v3;
        float sq = v0 * v0 + v1 * v1 + v2 * v2 + v3 * v3;
        for (int d = 32; d; d >>= 1) {
            sm += __shfl_down(sm, d, 64);
            sq += __shfl_down(sq, d, 64);
        }
        if (lane == 0) {
            float mu = sm * (1.0f / H);
            float var = sq * (1.0f / H) - mu * mu;
            smu[rr] = mu;
            srs[rr] = rsqrtf(var + LN_EPS);
        }
    }
    __syncthreads();
    float gg = g[t], bb = be[t];
#pragma unroll
    for (int r = 0; r < RPB; ++r) {
        float h = (acc[r] - smu[r]) * srs[r] * gg + bb;
        if (RELU) h = fmaxf(h, 0.0f);
        out[(rowbase + r) * H + t] = h;
    }
}

// ---------------- GRU step (h0 = 0): temporal = (1-z)*n, in-place ----------------
__global__ __launch_bounds__(256) void k_gru(float* hbuf, const float* WihT,
                                             const float* bih, const float* bhh) {
    __shared__ float s[RPB][H + 1];
    int t = threadIdx.x;
    long long rowbase = (long long)blockIdx.x * RPB;
    for (int idx = t; idx < RPB * H; idx += 256) {
        int r = idx >> 8, k = idx & 255;
        s[r][k] = hbuf[(rowbase + r) * H + k];
    }
    __syncthreads();
    float ar[RPB], az[RPB], an[RPB];
    float br = bih[t], bz = bih[t + H], bn = bih[t + 2 * H];
#pragma unroll
    for (int r = 0; r < RPB; ++r) { ar[r] = br; az[r] = bz; an[r] = bn; }
    for (int k = 0; k < H; ++k) {
        float w0 = WihT[k * 768 + t];
        float w1 = WihT[k * 768 + t + H];
        float w2 = WihT[k * 768 + t + 2 * H];
#pragma unroll
        for (int r = 0; r < RPB; ++r) {
            float a = s[r][k];
            ar[r] = fmaf(a, w0, ar[r]);
            az[r] = fmaf(a, w1, az[r]);
            an[r] = fmaf(a, w2, an[r]);
        }
    }
    float hr = bhh[t], hz = bhh[t + H], hn = bhh[t + 2 * H];
    __syncthreads();
#pragma unroll
    for (int r = 0; r < RPB; ++r) {
        float rg = 1.0f / (1.0f + expf(-(ar[r] + hr)));
        float zg = 1.0f / (1.0f + expf(-(az[r] + hz)));
        float ng = tanhf(an[r] + rg * hn);
        hbuf[(rowbase + r) * H + t] = (1.0f - zg) * ng;
    }
}

// ---------------- decoder layer 1: relu([temporal, x] @ Wd1 + bd1), in-place ----------------
__global__ __launch_bounds__(256) void k_d1(float* hbuf, const float* x, const float* Wd1,
                                            const float* bd1) {
    __shared__ float s[RPB][H + 1];
    __shared__ float sx[RPB][DIN];
    int t = threadIdx.x;
    long long rowbase = (long long)blockIdx.x * RPB;
    for (int idx = t; idx < RPB * H; idx += 256) {
        int r = idx >> 8, k = idx & 255;
        s[r][k] = hbuf[(rowbase + r) * H + k];
    }
    {
        int r = t >> 4, k = t & 15;
        sx[r][k] = x[(rowbase + r) * DIN + k];
    }
    __syncthreads();
    float acc[RPB];
    float bb = bd1[t];
#pragma unroll
    for (int r = 0; r < RPB; ++r) acc[r] = bb;
    for (int k = 0; k < H; ++k) {
        float wv = Wd1[k * H + t];
#pragma unroll
        for (int r = 0; r < RPB; ++r) acc[r] = fmaf(s[r][k], wv, acc[r]);
    }
    for (int k = 0; k < DIN; ++k) {
        float wv = Wd1[(H + k) * H + t];
#pragma unroll
        for (int r = 0; r < RPB; ++r) acc[r] = fmaf(sx[r][k], wv, acc[r]);
    }
    __syncthreads();
#pragma unroll
    for (int r = 0; r < RPB; ++r) hbuf[(rowbase + r) * H + t] = fmaxf(acc[r], 0.0f);
}

// ---------------- decoder layers 2+3 fused: pred = clip(relu(d1@Wd2+bd2)@Wd3+bd3) ----------------
__global__ __launch_bounds__(128) void k_d23(const float* hbuf, const float* Wd2, const float* bd2,
                                             const float* Wd3, const float* bd3, float* out) {
    __shared__ float s[RPB][H + 1];
    __shared__ float d2s[RPB][129];
    int t = threadIdx.x;  // 0..127
    long long rowbase = (long long)blockIdx.x * RPB;
    for (int idx = t; idx < RPB * H; idx += 128) {
        int r = idx >> 8, k = idx & 255;
        s[r][k] = hbuf[(rowbase + r) * H + k];
    }
    __syncthreads();
    float acc[RPB];
    float bb = bd2[t];
#pragma unroll
    for (int r = 0; r < RPB; ++r) acc[r] = bb;
    for (int k = 0; k < H; ++k) {
        float wv = Wd2[k * 128 + t];
#pragma unroll
        for (int r = 0; r < RPB; ++r) acc[r] = fmaf(s[r][k], wv, acc[r]);
    }
#pragma unroll
    for (int r = 0; r < RPB; ++r) d2s[r][t] = fmaxf(acc[r], 0.0f);
    __syncthreads();
    if (t < 32) {
        int r = t >> 1, c = t & 1;
        float a = bd3[c];
        for (int k = 0; k < 128; ++k) a = fmaf(d2s[r][k], Wd3[k * 2 + c], a);
        a = fminf(fmaxf(a, -5.0f), 5.0f);
        out[(rowbase + r) * 2 + c] = a;
    }
}

extern "C" void kernel_launch(void* const* d_in, const int* in_sizes, int n_in,
                              void* d_out, int out_size, void* d_ws, size_t ws_size,
                              hipStream_t stream) {
    const float* x   = (const float*)d_in[0];
    const void*  ei  = d_in[1];
    const float* ew  = (const float*)d_in[2];
    const float* W1  = (const float*)d_in[3];
    const float* b1  = (const float*)d_in[4];
    const float* g1  = (const float*)d_in[5];
    const float* be1 = (const float*)d_in[6];
    const float* W2  = (const float*)d_in[7];
    const float* b2  = (const float*)d_in[8];
    const float* g2  = (const float*)d_in[9];
    const float* be2 = (const float*)d_in[10];
    const float* Wih = (const float*)d_in[11];
    const float* bih = (const float*)d_in[13];
    const float* bhh = (const float*)d_in[14];
    const float* Wd1 = (const float*)d_in[15];
    const float* bd1 = (const float*)d_in[16];
    const float* Wd2 = (const float*)d_in[17];
    const float* bd2 = (const float*)d_in[18];
    const float* Wd3 = (const float*)d_in[19];
    const float* bd3 = (const float*)d_in[20];
    float* out = (float*)d_out;

    char* w = (char*)d_ws;
    size_t pos = 0;
    auto carve = [&](size_t bytes) -> void* {
        void* p = w + pos;
        pos += (bytes + 255) & ~(size_t)255;
        return p;
    };
    int*   flag  = (int*)  carve(4);
    int*   es    = (int*)  carve(sizeof(int) * N_EDGES);
    int*   ed    = (int*)  carve(sizeof(int) * N_EDGES);
    float* dis   = (float*)carve(sizeof(float) * N_NODES);
    int*   cnt   = (int*)  carve(sizeof(int) * N_NODES);
    int*   offs  = (int*)  carve(sizeof(int) * (N_NODES + 1));
    int*   bsum  = (int*)  carve(sizeof(int) * 64);
    int*   bsoff = (int*)  carve(sizeof(int) * 64);
    int*   csr_s = (int*)  carve(sizeof(int) * N_EDGES);
    float* csr_c = (float*)carve(sizeof(float) * N_EDGES);
    float* WihT  = (float*)carve(sizeof(float) * 768 * 256);
    float* agg0  = (float*)carve(sizeof(float) * (size_t)N_NODES * DIN);
    float* A     = (float*)carve(sizeof(float) * (size_t)N_NODES * H);
    float* Bb    = (float*)carve(sizeof(float) * (size_t)N_NODES * H);
    (void)pos; (void)ws_size; (void)in_sizes; (void)n_in; (void)out_size;

    int gE = (N_EDGES + 255) / 256;
    int gN = (N_NODES + 255) / 256;
    int nscan = (N_NODES + 1023) / 1024;  // 49

    k_detect<<<1, 1, 0, stream>>>(ei, flag);
    k_convert<<<gE, 256, 0, stream>>>(ei, flag, es, ed);
    k_init<<<gN, 256, 0, stream>>>(dis, cnt);
    k_deg<<<gE, 256, 0, stream>>>(ed, ew, dis, cnt);
    k_rsqrt<<<gN, 256, 0, stream>>>(dis);
    k_scan1<<<nscan, 256, 0, stream>>>(cnt, bsum);
    k_scan2<<<1, 64, 0, stream>>>(bsum, bsoff, offs, nscan);
    k_scan3<<<nscan, 256, 0, stream>>>(cnt, bsoff, offs);
    k_cursor<<<gN, 256, 0, stream>>>(offs, cnt);
    k_fill<<<gE, 256, 0, stream>>>(es, ed, ew, dis, cnt, csr_s, csr_c);
    k_wih_t<<<(768 * 256 + 255) / 256, 256, 0, stream>>>(Wih, WihT);

    k_agg0<<<N_NODES / 16, 256, 0, stream>>>(x, offs, csr_s, csr_c, dis, agg0);
    k_gemm_ln<DIN, true><<<N_NODES / RPB, 256, 0, stream>>>(agg0, A, W1, b1, g1, be1);
    k_spmm<<<N_NODES / 4, 256, 0, stream>>>(A, Bb, offs, csr_s, csr_c, dis);
    k_gemm_ln<H, false><<<N_NODES / RPB, 256, 0, stream>>>(Bb, Bb, W2, b2, g2, be2);
    k_gru<<<N_NODES / RPB, 256, 0, stream>>>(Bb, WihT, bih, bhh);
    k_d1<<<N_NODES / RPB, 256, 0, stream>>>(Bb, x, Wd1, bd1);
    k_d23<<<N_NODES / RPB, 128, 0, stream>>>(Bb, Wd2, bd2, Wd3, bd3, out);
}

// Round 2
// 939.298 us; speedup vs baseline: 1.4963x; 1.4963x over previous
//
#include <hip/hip_runtime.h>
#include <math.h>

#define N_NODES 50000
#define N_EDGES 1600000
#define DIN 16
#define H 256
#define RPB 16
#define LN_EPS 1e-5f

typedef __attribute__((ext_vector_type(8))) unsigned short u16x8;
typedef __attribute__((ext_vector_type(8))) __bf16 bf16x8;
typedef __attribute__((ext_vector_type(4))) float f32x4;

__device__ inline unsigned short f2bf(float f) {
    unsigned u = __builtin_bit_cast(unsigned, f);
    return (unsigned short)((u + 0x7FFFu + ((u >> 16) & 1u)) >> 16);
}

// ---------------- edge dtype detect + convert ----------------
__global__ void k_detect(const void* ei, int* flag) {
    const long long* p = (const long long*)ei;
    bool is64 = true;
    for (int i = 0; i < 8; ++i) {
        long long v = p[i];
        if (v < 0 || v >= N_NODES) is64 = false;
    }
    *flag = is64 ? 1 : 0;
}

__global__ void k_convert(const void* ei, const int* flag, int* es, int* ed) {
    int e = blockIdx.x * blockDim.x + threadIdx.x;
    if (e >= N_EDGES) return;
    if (*flag) {
        const long long* p = (const long long*)ei;
        es[e] = (int)p[e];
        ed[e] = (int)p[N_EDGES + e];
    } else {
        const int* p = (const int*)ei;
        es[e] = p[e];
        ed[e] = p[N_EDGES + e];
    }
}

// ---------------- degree + normalization ----------------
__global__ void k_init(float* deg, int* cnt) {
    int i = blockIdx.x * blockDim.x + threadIdx.x;
    if (i < N_NODES) { deg[i] = 2.0f; cnt[i] = 0; }
}

__global__ void k_deg(const int* ed, const float* ew, float* deg, int* cnt) {
    int e = blockIdx.x * blockDim.x + threadIdx.x;
    if (e >= N_EDGES) return;
    int d = ed[e];
    atomicAdd(&deg[d], ew[e]);
    atomicAdd(&cnt[d], 1);
}

__global__ void k_rsqrt(float* deg) {
    int i = blockIdx.x * blockDim.x + threadIdx.x;
    if (i < N_NODES) deg[i] = rsqrtf(deg[i]);   // deg >= 2 always
}

// ---------------- exclusive scan of cnt -> offs (chunk 1024) ----------------
__global__ void k_scan1(const int* cnt, int* bsum) {
    __shared__ int ws_[4];
    int b = blockIdx.x, t = threadIdx.x;
    int s = 0;
    for (int k = 0; k < 4; ++k) {
        int idx = b * 1024 + k * 256 + t;
        if (idx < N_NODES) s += cnt[idx];
    }
    for (int d = 32; d; d >>= 1) s += __shfl_down(s, d, 64);
    if ((t & 63) == 0) ws_[t >> 6] = s;
    __syncthreads();
    if (t == 0) bsum[b] = ws_[0] + ws_[1] + ws_[2] + ws_[3];
}

__global__ void k_scan2(const int* bsum, int* bsoff, int* offs, int nblk) {
    if (threadIdx.x == 0) {
        int run = 0;
        for (int i = 0; i < nblk; ++i) { bsoff[i] = run; run += bsum[i]; }
        offs[N_NODES] = run;
    }
}

__global__ void k_scan3(const int* cnt, const int* bsoff, int* offs) {
    __shared__ int wsum[4];
    int b = blockIdx.x, t = threadIdx.x;
    int lane = t & 63, wv = t >> 6;
    int base = b * 1024 + t * 4;
    int v[4];
    for (int k = 0; k < 4; ++k) {
        int idx = base + k;
        v[k] = (idx < N_NODES) ? cnt[idx] : 0;
    }
    int ts = v[0] + v[1] + v[2] + v[3];
    int sc = ts;
    for (int d = 1; d < 64; d <<= 1) {
        int u = __shfl_up(sc, d, 64);
        if (lane >= d) sc += u;
    }
    if (lane == 63) wsum[wv] = sc;
    __syncthreads();
    int wpre = 0;
    for (int i = 0; i < wv; ++i) wpre += wsum[i];
    int ex = wpre + sc - ts + bsoff[b];
    for (int k = 0; k < 4; ++k) {
        int idx = base + k;
        if (idx < N_NODES) offs[idx] = ex;
        ex += v[k];
    }
}

__global__ void k_cursor(const int* offs, int* cursor) {
    int i = blockIdx.x * blockDim.x + threadIdx.x;
    if (i < N_NODES) cursor[i] = offs[i];
}

__global__ void k_fill(const int* es, const int* ed, const float* ew, const float* dis,
                       int* cursor, int* csr_s, float* csr_c) {
    int e = blockIdx.x * blockDim.x + threadIdx.x;
    if (e >= N_EDGES) return;
    int s = es[e], d = ed[e];
    int p = atomicAdd(&cursor[d], 1);
    csr_s[p] = s;
    csr_c[p] = dis[s] * ew[e] * dis[d];
}

// ---------------- weight prep: fp32 -> bf16 (with transpose where needed) ----------------
__global__ void k_wihbf(const float* Wih, unsigned short* Wg) {
    int idx = blockIdx.x * blockDim.x + threadIdx.x;
    if (idx < 768 * 256) Wg[idx] = f2bf(Wih[idx]);   // already [out_col][k]
}

__global__ void k_w2t(const float* W2, unsigned short* W2T) {  // W2[k][n] -> W2T[n][k]
    int idx = blockIdx.x * blockDim.x + threadIdx.x;
    if (idx >= 256 * 256) return;
    int k = idx >> 8, n = idx & 255;
    W2T[n * 256 + k] = f2bf(W2[idx]);
}

__global__ void k_wd1t(const float* Wd1, unsigned short* T) {  // Wd1[272][256] -> T[n][288] (k padded)
    int idx = blockIdx.x * blockDim.x + threadIdx.x;
    if (idx >= 256 * 288) return;
    int n = idx / 288, k = idx % 288;
    T[idx] = (k < 272) ? f2bf(Wd1[k * 256 + n]) : (unsigned short)0;
}

__global__ void k_wd2t(const float* Wd2, unsigned short* T) {  // Wd2[256][128] -> T[n][256]
    int idx = blockIdx.x * blockDim.x + threadIdx.x;
    if (idx >= 256 * 128) return;
    int k = idx >> 7, n = idx & 127;
    T[n * 256 + k] = f2bf(Wd2[idx]);
}

// fill decoder-input x columns: din[row][256+j] = bf16(x[row][j]) (j<16), 0 pad to 288
__global__ void k_xfill(const float* x, unsigned short* din) {
    int idx = blockIdx.x * blockDim.x + threadIdx.x;
    if (idx >= N_NODES * 32) return;
    int row = idx >> 5, j = idx & 31;
    din[(long long)row * 288 + 256 + j] = (j < 16) ? f2bf(x[row * DIN + j]) : (unsigned short)0;
}

// ---------------- aggregation in DIN space (layer 1) ----------------
__global__ __launch_bounds__(256) void k_agg0(const float* x, const int* offs, const int* csr_s,
                                              const float* csr_c, const float* dis, float* agg0) {
    int t = threadIdx.x;
    int r = blockIdx.x * 16 + (t >> 4);
    int dd = t & 15;
    float di = dis[r];
    float acc = 2.0f * di * di * x[(long long)r * DIN + dd];
    int e0 = offs[r], e1 = offs[r + 1];
    for (int e = e0; e < e1; ++e) {
        int s = csr_s[e];
        float c = csr_c[e];
        acc = fmaf(c, x[(long long)s * DIN + dd], acc);
    }
    agg0[(long long)r * DIN + dd] = acc;
}

// ---------------- SpMM in H space (layer 2 aggregation) ----------------
__global__ __launch_bounds__(256) void k_spmm(const float* hin, float* hout, const int* offs,
                                              const int* csr_s, const float* csr_c, const float* dis) {
    int t = threadIdx.x;
    int wv = t >> 6, lane = t & 63;
    int row = blockIdx.x * 4 + wv;
    const float4* h4 = (const float4*)hin;
    float di = dis[row];
    float cself = 2.0f * di * di;
    float4 v = h4[(long long)row * 64 + lane];
    float4 acc;
    acc.x = cself * v.x; acc.y = cself * v.y; acc.z = cself * v.z; acc.w = cself * v.w;
    int e0 = offs[row], e1 = offs[row + 1];
    for (int e = e0; e < e1; ++e) {
        int s = csr_s[e];
        float c = csr_c[e];
        float4 u = h4[(long long)s * 64 + lane];
        acc.x = fmaf(c, u.x, acc.x);
        acc.y = fmaf(c, u.y, acc.y);
        acc.z = fmaf(c, u.z, acc.z);
        acc.w = fmaf(c, u.w, acc.w);
    }
    ((float4*)hout)[(long long)row * 64 + lane] = acc;
}

// ---------------- layer-1 GEMM (16 -> 256) + bias + LN + relu (fp32 VALU) ----------------
template <int K, bool RELU>
__global__ __launch_bounds__(256) void k_gemm_ln(const float* in, float* out, const float* W,
                                                 const float* bias, const float* g, const float* be) {
    __shared__ float s[RPB][H + 1];
    __shared__ float smu[RPB], srs[RPB];
    int t = threadIdx.x;
    long long rowbase = (long long)blockIdx.x * RPB;
    for (int idx = t; idx < RPB * K; idx += 256) {
        int r = idx / K, k = idx % K;
        s[r][k] = in[(rowbase + r) * K + k];
    }
    __syncthreads();
    float acc[RPB];
    float bb0 = bias[t];
#pragma unroll
    for (int r = 0; r < RPB; ++r) acc[r] = bb0;
    for (int k = 0; k < K; ++k) {
        float wv = W[k * H + t];
#pragma unroll
        for (int r = 0; r < RPB; ++r) acc[r] = fmaf(s[r][k], wv, acc[r]);
    }
    __syncthreads();
#pragma unroll
    for (int r = 0; r < RPB; ++r) s[r][t] = acc[r];
    __syncthreads();
    int lane = t & 63, wv2 = t >> 6;
    for (int rr = wv2; rr < RPB; rr += 4) {
        float v0 = s[rr][lane], v1 = s[rr][lane + 64], v2 = s[rr][lane + 128], v3 = s[rr][lane + 192];
        float sm = v0 + v1 + v2 + v3;
        float sq = v0 * v0 + v1 * v1 + v2 * v2 + v3 * v3;
        for (int d = 32; d; d >>= 1) {
            sm += __shfl_down(sm, d, 64);
            sq += __shfl_down(sq, d, 64);
        }
        if (lane == 0) {
            float mu = sm * (1.0f / H);
            float var = sq * (1.0f / H) - mu * mu;
            smu[rr] = mu;
            srs[rr] = rsqrtf(var + LN_EPS);
        }
    }
    __syncthreads();
    float gg = g[t], bb = be[t];
#pragma unroll
    for (int r = 0; r < RPB; ++r) {
        float h = (acc[r] - smu[r]) * srs[r] * gg + bb;
        if (RELU) h = fmaxf(h, 0.0f);
        out[(rowbase + r) * H + t] = h;
    }
}

// ---------------- MFMA row-GEMM kernels (wave = 16 rows) ----------------
// frag layout (16x16x32 bf16): A lane l: row l&15, k=8*(l>>4)+j ; B lane l: col l&15, same k ;
// D lane l: col l&15, row 4*(l>>4)+reg

// layer-2 GEMM + bias + LN, fp32 in -> bf16 out
__global__ __launch_bounds__(256) void k_ln_mfma(const float* __restrict__ in,
        const unsigned short* __restrict__ WT, const float* __restrict__ bias,
        const float* __restrict__ g, const float* __restrict__ be,
        unsigned short* __restrict__ outbf) {
    int t = threadIdx.x;
    int wv = t >> 6, l = t & 63;
    int lr = l & 15, lg = l >> 4;
    int rb = blockIdx.x * 64 + wv * 16;
    int arow = rb + lr; if (arow >= N_NODES) arow = N_NODES - 1;
    bf16x8 af[8];
    const float* ap = in + (long long)arow * H + lg * 8;
#pragma unroll
    for (int ks = 0; ks < 8; ++ks) {
        float4 u0 = *(const float4*)(ap + ks * 32);
        float4 u1 = *(const float4*)(ap + ks * 32 + 4);
        u16x8 v;
        v[0] = f2bf(u0.x); v[1] = f2bf(u0.y); v[2] = f2bf(u0.z); v[3] = f2bf(u0.w);
        v[4] = f2bf(u1.x); v[5] = f2bf(u1.y); v[6] = f2bf(u1.z); v[7] = f2bf(u1.w);
        af[ks] = __builtin_bit_cast(bf16x8, v);
    }
    f32x4 acc[16];
#pragma unroll
    for (int ct = 0; ct < 16; ++ct) acc[ct] = (f32x4){0.f, 0.f, 0.f, 0.f};
    for (int ct = 0; ct < 16; ++ct) {
        const unsigned short* wr = WT + (ct * 16 + lr) * H + lg * 8;
#pragma unroll
        for (int ks = 0; ks < 8; ++ks) {
            bf16x8 bfv = __builtin_bit_cast(bf16x8, *(const u16x8*)(wr + ks * 32));
            acc[ct] = __builtin_amdgcn_mfma_f32_16x16x32_bf16(af[ks], bfv, acc[ct], 0, 0, 0);
        }
    }
#pragma unroll
    for (int ct = 0; ct < 16; ++ct) {
        float bb = bias[ct * 16 + lr];
#pragma unroll
        for (int q = 0; q < 4; ++q) acc[ct][q] += bb;
    }
    float mean[4], rstd[4];
#pragma unroll
    for (int q = 0; q < 4; ++q) {
        float s = 0.f, s2 = 0.f;
#pragma unroll
        for (int ct = 0; ct < 16; ++ct) { float v = acc[ct][q]; s += v; s2 += v * v; }
#pragma unroll
        for (int m = 1; m < 16; m <<= 1) { s += __shfl_xor(s, m, 64); s2 += __shfl_xor(s2, m, 64); }
        float mu = s * (1.0f / H);
        mean[q] = mu;
        rstd[q] = rsqrtf(s2 * (1.0f / H) - mu * mu + LN_EPS);
    }
#pragma unroll
    for (int ct = 0; ct < 16; ++ct) {
        int col = ct * 16 + lr;
        float gg = g[col], bb = be[col];
#pragma unroll
        for (int q = 0; q < 4; ++q) {
            int row = rb + lg * 4 + q;
            if (row < N_NODES) {
                float nv = (acc[ct][q] - mean[q]) * rstd[q] * gg + bb;
                outbf[(long long)row * H + col] = f2bf(nv);
            }
        }
    }
}

// GRU step (h0=0): out = (1-z)*n, bf16 in -> bf16 din[.][0..255]
__global__ __launch_bounds__(256) void k_gru_mfma(const unsigned short* __restrict__ h2,
        const unsigned short* __restrict__ Wg, const float* __restrict__ bih,
        const float* __restrict__ bhh, unsigned short* __restrict__ din) {
    int t = threadIdx.x;
    int wv = t >> 6, l = t & 63;
    int lr = l & 15, lg = l >> 4;
    int rb = blockIdx.x * 64 + wv * 16;
    int arow = rb + lr; if (arow >= N_NODES) arow = N_NODES - 1;
    bf16x8 af[8];
    const unsigned short* ap = h2 + (long long)arow * H + lg * 8;
#pragma unroll
    for (int ks = 0; ks < 8; ++ks) af[ks] = __builtin_bit_cast(bf16x8, *(const u16x8*)(ap + ks * 32));
    for (int ct = 0; ct < 16; ++ct) {
        f32x4 aR = (f32x4){0.f, 0.f, 0.f, 0.f};
        f32x4 aZ = aR, aN = aR;
        const unsigned short* w0 = Wg + (ct * 16 + lr) * H + lg * 8;
        const unsigned short* w1 = w0 + 256 * H;
        const unsigned short* w2 = w0 + 512 * H;
#pragma unroll
        for (int ks = 0; ks < 8; ++ks) {
            aR = __builtin_amdgcn_mfma_f32_16x16x32_bf16(af[ks],
                    __builtin_bit_cast(bf16x8, *(const u16x8*)(w0 + ks * 32)), aR, 0, 0, 0);
            aZ = __builtin_amdgcn_mfma_f32_16x16x32_bf16(af[ks],
                    __builtin_bit_cast(bf16x8, *(const u16x8*)(w1 + ks * 32)), aZ, 0, 0, 0);
            aN = __builtin_amdgcn_mfma_f32_16x16x32_bf16(af[ks],
                    __builtin_bit_cast(bf16x8, *(const u16x8*)(w2 + ks * 32)), aN, 0, 0, 0);
        }
        int col = ct * 16 + lr;
        float bR = bih[col] + bhh[col];
        float bZ = bih[col + 256] + bhh[col + 256];
        float bN = bih[col + 512];
        float hN = bhh[col + 512];
#pragma unroll
        for (int q = 0; q < 4; ++q) {
            int row = rb + lg * 4 + q;
            float r = 1.0f / (1.0f + expf(-(aR[q] + bR)));
            float z = 1.0f / (1.0f + expf(-(aZ[q] + bZ)));
            float n = tanhf(aN[q] + bN + r * hN);
            float o = (1.0f - z) * n;
            if (row < N_NODES) din[(long long)row * 288 + col] = f2bf(o);
        }
    }
}

// decoder layer 1: relu(din @ Wd1T + bd1), K=288, bf16 -> bf16
__global__ __launch_bounds__(256) void k_d1_mfma(const unsigned short* __restrict__ din,
        const unsigned short* __restrict__ WT, const float* __restrict__ bias,
        unsigned short* __restrict__ outbf) {
    int t = threadIdx.x;
    int wv = t >> 6, l = t & 63;
    int lr = l & 15, lg = l >> 4;
    int rb = blockIdx.x * 64 + wv * 16;
    int arow = rb + lr; if (arow >= N_NODES) arow = N_NODES - 1;
    bf16x8 af[9];
    const unsigned short* ap = din + (long long)arow * 288 + lg * 8;
#pragma unroll
    for (int ks = 0; ks < 9; ++ks) af[ks] = __builtin_bit_cast(bf16x8, *(const u16x8*)(ap + ks * 32));
    f32x4 acc[16];
#pragma unroll
    for (int ct = 0; ct < 16; ++ct) acc[ct] = (f32x4){0.f, 0.f, 0.f, 0.f};
    for (int ct = 0; ct < 16; ++ct) {
        const unsigned short* wr = WT + (ct * 16 + lr) * 288 + lg * 8;
#pragma unroll
        for (int ks = 0; ks < 9; ++ks) {
            bf16x8 bfv = __builtin_bit_cast(bf16x8, *(const u16x8*)(wr + ks * 32));
            acc[ct] = __builtin_amdgcn_mfma_f32_16x16x32_bf16(af[ks], bfv, acc[ct], 0, 0, 0);
        }
    }
#pragma unroll
    for (int ct = 0; ct < 16; ++ct) {
        int col = ct * 16 + lr;
        float bb = bias[col];
#pragma unroll
        for (int q = 0; q < 4; ++q) {
            int row = rb + lg * 4 + q;
            if (row < N_NODES) {
                float v = fmaxf(acc[ct][q] + bb, 0.0f);
                outbf[(long long)row * H + col] = f2bf(v);
            }
        }
    }
}

// decoder layers 2+3: d2 = relu(d1 @ Wd2T + bd2) [N=128]; pred = clip(d2 @ Wd3 + bd3)
__global__ __launch_bounds__(256) void k_d23_mfma(const unsigned short* __restrict__ d1,
        const unsigned short* __restrict__ WT, const float* __restrict__ bd2,
        const float* __restrict__ Wd3, const float* __restrict__ bd3, float* __restrict__ out) {
    int t = threadIdx.x;
    int wv = t >> 6, l = t & 63;
    int lr = l & 15, lg = l >> 4;
    int rb = blockIdx.x * 64 + wv * 16;
    int arow = rb + lr; if (arow >= N_NODES) arow = N_NODES - 1;
    bf16x8 af[8];
    const unsigned short* ap = d1 + (long long)arow * H + lg * 8;
#pragma unroll
    for (int ks = 0; ks < 8; ++ks) af[ks] = __builtin_bit_cast(bf16x8, *(const u16x8*)(ap + ks * 32));
    f32x4 acc[8];
#pragma unroll
    for (int ct = 0; ct < 8; ++ct) acc[ct] = (f32x4){0.f, 0.f, 0.f, 0.f};
    for (int ct = 0; ct < 8; ++ct) {
        const unsigned short* wr = WT + (ct * 16 + lr) * H + lg * 8;
#pragma unroll
        for (int ks = 0; ks < 8; ++ks) {
            bf16x8 bfv = __builtin_bit_cast(bf16x8, *(const u16x8*)(wr + ks * 32));
            acc[ct] = __builtin_amdgcn_mfma_f32_16x16x32_bf16(af[ks], bfv, acc[ct], 0, 0, 0);
        }
    }
    float p0[4] = {0.f, 0.f, 0.f, 0.f}, p1[4] = {0.f, 0.f, 0.f, 0.f};
#pragma unroll
    for (int ct = 0; ct < 8; ++ct) {
        int col = ct * 16 + lr;
        float bb = bd2[col];
        float2 w3 = *(const float2*)(Wd3 + col * 2);
#pragma unroll
        for (int q = 0; q < 4; ++q) {
            float v = fmaxf(acc[ct][q] + bb, 0.0f);
            p0[q] = fmaf(v, w3.x, p0[q]);
            p1[q] = fmaf(v, w3.y, p1[q]);
        }
    }
#pragma unroll
    for (int q = 0; q < 4; ++q) {
#pragma unroll
        for (int m = 1; m < 16; m <<= 1) {
            p0[q] += __shfl_xor(p0[q], m, 64);
            p1[q] += __shfl_xor(p1[q], m, 64);
        }
    }
    if (lr == 0) {
#pragma unroll
        for (int q = 0; q < 4; ++q) {
            int row = rb + lg * 4 + q;
            if (row < N_NODES) {
                float a = fminf(fmaxf(p0[q] + bd3[0], -5.0f), 5.0f);
                float b = fminf(fmaxf(p1[q] + bd3[1], -5.0f), 5.0f);
                out[(long long)row * 2] = a;
                out[(long long)row * 2 + 1] = b;
            }
        }
    }
}

extern "C" void kernel_launch(void* const* d_in, const int* in_sizes, int n_in,
                              void* d_out, int out_size, void* d_ws, size_t ws_size,
                              hipStream_t stream) {
    const float* x   = (const float*)d_in[0];
    const void*  ei  = d_in[1];
    const float* ew  = (const float*)d_in[2];
    const float* W1  = (const float*)d_in[3];
    const float* b1  = (const float*)d_in[4];
    const float* g1  = (const float*)d_in[5];
    const float* be1 = (const float*)d_in[6];
    const float* W2  = (const float*)d_in[7];
    const float* b2  = (const float*)d_in[8];
    const float* g2  = (const float*)d_in[9];
    const float* be2 = (const float*)d_in[10];
    const float* Wih = (const float*)d_in[11];
    const float* bih = (const float*)d_in[13];
    const float* bhh = (const float*)d_in[14];
    const float* Wd1 = (const float*)d_in[15];
    const float* bd1 = (const float*)d_in[16];
    const float* Wd2 = (const float*)d_in[17];
    const float* bd2 = (const float*)d_in[18];
    const float* Wd3 = (const float*)d_in[19];
    const float* bd3 = (const float*)d_in[20];
    float* out = (float*)d_out;

    char* w = (char*)d_ws;
    size_t pos = 0;
    auto carve = [&](size_t bytes) -> void* {
        void* p = w + pos;
        pos += (bytes + 255) & ~(size_t)255;
        return p;
    };
    int*   flag  = (int*)  carve(4);
    int*   es    = (int*)  carve(sizeof(int) * N_EDGES);
    int*   ed    = (int*)  carve(sizeof(int) * N_EDGES);
    float* dis   = (float*)carve(sizeof(float) * N_NODES);
    int*   cnt   = (int*)  carve(sizeof(int) * N_NODES);
    int*   offs  = (int*)  carve(sizeof(int) * (N_NODES + 1));
    int*   bsum  = (int*)  carve(sizeof(int) * 64);
    int*   bsoff = (int*)  carve(sizeof(int) * 64);
    int*   csr_s = (int*)  carve(sizeof(int) * N_EDGES);
    float* csr_c = (float*)carve(sizeof(float) * N_EDGES);
    unsigned short* Wg   = (unsigned short*)carve(2 * 768 * 256);
    unsigned short* W2T  = (unsigned short*)carve(2 * 256 * 256);
    unsigned short* Wd1T = (unsigned short*)carve(2 * 256 * 288);
    unsigned short* Wd2T = (unsigned short*)carve(2 * 128 * 256);
    float* agg0  = (float*)carve(sizeof(float) * (size_t)N_NODES * DIN);
    float* A     = (float*)carve(sizeof(float) * (size_t)N_NODES * H);
    float* Bb    = (float*)carve(sizeof(float) * (size_t)N_NODES * H);
    // aliases over dead fp32 regions
    unsigned short* h2bf = (unsigned short*)A;                               // 25.6 MB, after spmm
    unsigned short* d1bf = (unsigned short*)((char*)A + (size_t)N_NODES * H * 2);  // second half of A
    unsigned short* din  = (unsigned short*)Bb;                              // 28.8 MB, after ln_mfma
    (void)pos; (void)ws_size; (void)in_sizes; (void)n_in; (void)out_size;

    int gE = (N_EDGES + 255) / 256;
    int gN = (N_NODES + 255) / 256;
    int nscan = (N_NODES + 1023) / 1024;  // 49
    int nbm = (N_NODES + 63) / 64;        // 782 blocks for wave=16-row MFMA kernels

    k_detect<<<1, 1, 0, stream>>>(ei, flag);
    k_convert<<<gE, 256, 0, stream>>>(ei, flag, es, ed);
    k_init<<<gN, 256, 0, stream>>>(dis, cnt);
    k_deg<<<gE, 256, 0, stream>>>(ed, ew, dis, cnt);
    k_rsqrt<<<gN, 256, 0, stream>>>(dis);
    k_scan1<<<nscan, 256, 0, stream>>>(cnt, bsum);
    k_scan2<<<1, 64, 0, stream>>>(bsum, bsoff, offs, nscan);
    k_scan3<<<nscan, 256, 0, stream>>>(cnt, bsoff, offs);
    k_cursor<<<gN, 256, 0, stream>>>(offs, cnt);
    k_fill<<<gE, 256, 0, stream>>>(es, ed, ew, dis, cnt, csr_s, csr_c);
    k_wihbf<<<(768 * 256 + 255) / 256, 256, 0, stream>>>(Wih, Wg);
    k_w2t<<<(256 * 256 + 255) / 256, 256, 0, stream>>>(W2, W2T);
    k_wd1t<<<(256 * 288 + 255) / 256, 256, 0, stream>>>(Wd1, Wd1T);
    k_wd2t<<<(256 * 128 + 255) / 256, 256, 0, stream>>>(Wd2, Wd2T);

    k_agg0<<<N_NODES / 16, 256, 0, stream>>>(x, offs, csr_s, csr_c, dis, agg0);
    k_gemm_ln<DIN, true><<<N_NODES / RPB, 256, 0, stream>>>(agg0, A, W1, b1, g1, be1);
    k_spmm<<<N_NODES / 4, 256, 0, stream>>>(A, Bb, offs, csr_s, csr_c, dis);
    k_ln_mfma<<<nbm, 256, 0, stream>>>(Bb, W2T, b2, g2, be2, h2bf);     // A now dead -> h2bf
    k_xfill<<<(N_NODES * 32 + 255) / 256, 256, 0, stream>>>(x, din);    // Bb now dead -> din
    k_gru_mfma<<<nbm, 256, 0, stream>>>(h2bf, Wg, bih, bhh, din);
    k_d1_mfma<<<nbm, 256, 0, stream>>>(din, Wd1T, bd1, d1bf);
    k_d23_mfma<<<nbm, 256, 0, stream>>>(d1bf, Wd2T, bd2, Wd3, bd3, out);
}

// Round 3
// 803.209 us; speedup vs baseline: 1.7498x; 1.1694x over previous
//
#include <hip/hip_runtime.h>
#include <math.h>

#define N_NODES 50000
#define N_EDGES 1600000
#define DIN 16
#define H 256
#define RPB 16
#define LN_EPS 1e-5f

typedef __attribute__((ext_vector_type(8))) unsigned short u16x8;
typedef __attribute__((ext_vector_type(8))) __bf16 bf16x8;
typedef __attribute__((ext_vector_type(4))) float f32x4;

__device__ inline unsigned short f2bf(float f) {
    unsigned u = __builtin_bit_cast(unsigned, f);
    return (unsigned short)((u + 0x7FFFu + ((u >> 16) & 1u)) >> 16);
}
__device__ inline float bf2f(unsigned short u) {
    return __builtin_bit_cast(float, ((unsigned)u) << 16);
}

// ---------------- edge dtype detect ----------------
__global__ void k_detect(const void* ei, int* flag) {
    const long long* p = (const long long*)ei;
    bool is64 = true;
    for (int i = 0; i < 8; ++i) {
        long long v = p[i];
        if (v < 0 || v >= N_NODES) is64 = false;
    }
    *flag = is64 ? 1 : 0;
}

// ---------------- init deg/cnt ----------------
__global__ void k_init(float* deg, int* cnt) {
    int i = blockIdx.x * blockDim.x + threadIdx.x;
    if (i < N_NODES) { deg[i] = 2.0f; cnt[i] = 0; }
}

// ---------------- convert edges + degree accumulation (fused) ----------------
__global__ void k_convert(const void* ei, const int* flag, int* es, int* ed,
                          const float* ew, float* deg, int* cnt) {
    int e = blockIdx.x * blockDim.x + threadIdx.x;
    if (e >= N_EDGES) return;
    int s, d;
    if (*flag) {
        const long long* p = (const long long*)ei;
        s = (int)p[e];
        d = (int)p[N_EDGES + e];
    } else {
        const int* p = (const int*)ei;
        s = p[e];
        d = p[N_EDGES + e];
    }
    es[e] = s;
    ed[e] = d;
    atomicAdd(&deg[d], ew[e]);
    atomicAdd(&cnt[d], 1);
}

__global__ void k_rsqrt(float* deg) {
    int i = blockIdx.x * blockDim.x + threadIdx.x;
    if (i < N_NODES) deg[i] = rsqrtf(deg[i]);   // deg >= 2 always
}

// ---------------- exclusive scan of cnt -> offs (chunk 1024) ----------------
__global__ void k_scan1(const int* cnt, int* bsum) {
    __shared__ int ws_[4];
    int b = blockIdx.x, t = threadIdx.x;
    int s = 0;
    for (int k = 0; k < 4; ++k) {
        int idx = b * 1024 + k * 256 + t;
        if (idx < N_NODES) s += cnt[idx];
    }
    for (int d = 32; d; d >>= 1) s += __shfl_down(s, d, 64);
    if ((t & 63) == 0) ws_[t >> 6] = s;
    __syncthreads();
    if (t == 0) bsum[b] = ws_[0] + ws_[1] + ws_[2] + ws_[3];
}

__global__ void k_scan2(const int* bsum, int* bsoff, int* offs, int nblk) {
    if (threadIdx.x == 0) {
        int run = 0;
        for (int i = 0; i < nblk; ++i) { bsoff[i] = run; run += bsum[i]; }
        offs[N_NODES] = run;
    }
}

__global__ void k_scan3(const int* cnt, const int* bsoff, int* offs, int* cursor) {
    __shared__ int wsum[4];
    int b = blockIdx.x, t = threadIdx.x;
    int lane = t & 63, wv = t >> 6;
    int base = b * 1024 + t * 4;
    int v[4];
    for (int k = 0; k < 4; ++k) {
        int idx = base + k;
        v[k] = (idx < N_NODES) ? cnt[idx] : 0;
    }
    int ts = v[0] + v[1] + v[2] + v[3];
    int sc = ts;
    for (int d = 1; d < 64; d <<= 1) {
        int u = __shfl_up(sc, d, 64);
        if (lane >= d) sc += u;
    }
    if (lane == 63) wsum[wv] = sc;
    __syncthreads();
    int wpre = 0;
    for (int i = 0; i < wv; ++i) wpre += wsum[i];
    int ex = wpre + sc - ts + bsoff[b];
    for (int k = 0; k < 4; ++k) {
        int idx = base + k;
        if (idx < N_NODES) { offs[idx] = ex; cursor[idx] = ex; }
        ex += v[k];
    }
}

__global__ void k_fill(const int* es, const int* ed, const float* ew, const float* dis,
                       int* cursor, int* csr_s, float* csr_c) {
    int e = blockIdx.x * blockDim.x + threadIdx.x;
    if (e >= N_EDGES) return;
    int s = es[e], d = ed[e];
    int p = atomicAdd(&cursor[d], 1);
    csr_s[p] = s;
    csr_c[p] = dis[s] * ew[e] * dis[d];
}

// ---------------- weight prep: fp32 -> bf16 (with transpose where needed) ----------------
__global__ void k_wihbf(const float* Wih, unsigned short* Wg) {
    int idx = blockIdx.x * blockDim.x + threadIdx.x;
    if (idx < 768 * 256) Wg[idx] = f2bf(Wih[idx]);   // already [out_col][k]
}

__global__ void k_w2t(const float* W2, unsigned short* W2T) {  // W2[k][n] -> W2T[n][k]
    int idx = blockIdx.x * blockDim.x + threadIdx.x;
    if (idx >= 256 * 256) return;
    int k = idx >> 8, n = idx & 255;
    W2T[n * 256 + k] = f2bf(W2[idx]);
}

__global__ void k_wd1t(const float* Wd1, unsigned short* T) {  // Wd1[272][256] -> T[n][288] (k padded)
    int idx = blockIdx.x * blockDim.x + threadIdx.x;
    if (idx >= 256 * 288) return;
    int n = idx / 288, k = idx % 288;
    T[idx] = (k < 272) ? f2bf(Wd1[k * 256 + n]) : (unsigned short)0;
}

__global__ void k_wd2t(const float* Wd2, unsigned short* T) {  // Wd2[256][128] -> T[n][256]
    int idx = blockIdx.x * blockDim.x + threadIdx.x;
    if (idx >= 256 * 128) return;
    int k = idx >> 7, n = idx & 127;
    T[n * 256 + k] = f2bf(Wd2[idx]);
}

// fill decoder-input x columns: din[row][256+j] = bf16(x[row][j]) (j<16), 0 pad to 288
__global__ void k_xfill(const float* x, unsigned short* din) {
    int idx = blockIdx.x * blockDim.x + threadIdx.x;
    if (idx >= N_NODES * 32) return;
    int row = idx >> 5, j = idx & 31;
    din[(long long)row * 288 + 256 + j] = (j < 16) ? f2bf(x[row * DIN + j]) : (unsigned short)0;
}

// ---------------- aggregation in DIN space (layer 1) ----------------
__global__ __launch_bounds__(256) void k_agg0(const float* x, const int* offs, const int* csr_s,
                                              const float* csr_c, const float* dis, float* agg0) {
    int t = threadIdx.x;
    int r = blockIdx.x * 16 + (t >> 4);
    int dd = t & 15;
    float di = dis[r];
    float acc = 2.0f * di * di * x[(long long)r * DIN + dd];
    int e0 = offs[r], e1 = offs[r + 1];
    for (int e = e0; e < e1; ++e) {
        int s = csr_s[e];
        float c = csr_c[e];
        acc = fmaf(c, x[(long long)s * DIN + dd], acc);
    }
    agg0[(long long)r * DIN + dd] = acc;
}

// ---------------- SpMM in H space (layer 2 aggregation), bf16 rows ----------------
__global__ __launch_bounds__(256) void k_spmm(const unsigned short* __restrict__ hin,
                                              unsigned short* __restrict__ hout, const int* offs,
                                              const int* csr_s, const float* csr_c, const float* dis) {
    int t = threadIdx.x;
    int wv = t >> 6, lane = t & 63;
    int row = blockIdx.x * 4 + wv;
    const ushort4* h4 = (const ushort4*)hin;
    float di = dis[row];
    float cself = 2.0f * di * di;
    ushort4 v = h4[(long long)row * 64 + lane];
    float a0 = cself * bf2f(v.x), a1 = cself * bf2f(v.y);
    float a2 = cself * bf2f(v.z), a3 = cself * bf2f(v.w);
    int e0 = offs[row], e1 = offs[row + 1];
    for (int e = e0; e < e1; ++e) {
        int s = csr_s[e];
        float c = csr_c[e];
        ushort4 u = h4[(long long)s * 64 + lane];
        a0 = fmaf(c, bf2f(u.x), a0);
        a1 = fmaf(c, bf2f(u.y), a1);
        a2 = fmaf(c, bf2f(u.z), a2);
        a3 = fmaf(c, bf2f(u.w), a3);
    }
    ushort4 o;
    o.x = f2bf(a0); o.y = f2bf(a1); o.z = f2bf(a2); o.w = f2bf(a3);
    ((ushort4*)hout)[(long long)row * 64 + lane] = o;
}

// ---------------- layer-1 GEMM (16 -> 256) + bias + LN + relu (fp32 VALU), bf16 out ----------------
template <int K, bool RELU>
__global__ __launch_bounds__(256) void k_gemm_ln(const float* in, unsigned short* out, const float* W,
                                                 const float* bias, const float* g, const float* be) {
    __shared__ float s[RPB][H + 1];
    __shared__ float smu[RPB], srs[RPB];
    int t = threadIdx.x;
    long long rowbase = (long long)blockIdx.x * RPB;
    for (int idx = t; idx < RPB * K; idx += 256) {
        int r = idx / K, k = idx % K;
        s[r][k] = in[(rowbase + r) * K + k];
    }
    __syncthreads();
    float acc[RPB];
    float bb0 = bias[t];
#pragma unroll
    for (int r = 0; r < RPB; ++r) acc[r] = bb0;
    for (int k = 0; k < K; ++k) {
        float wv = W[k * H + t];
#pragma unroll
        for (int r = 0; r < RPB; ++r) acc[r] = fmaf(s[r][k], wv, acc[r]);
    }
    __syncthreads();
#pragma unroll
    for (int r = 0; r < RPB; ++r) s[r][t] = acc[r];
    __syncthreads();
    int lane = t & 63, wv2 = t >> 6;
    for (int rr = wv2; rr < RPB; rr += 4) {
        float v0 = s[rr][lane], v1 = s[rr][lane + 64], v2 = s[rr][lane + 128], v3 = s[rr][lane + 192];
        float sm = v0 + v1 + v2 + v3;
        float sq = v0 * v0 + v1 * v1 + v2 * v2 + v3 * v3;
        for (int d = 32; d; d >>= 1) {
            sm += __shfl_down(sm, d, 64);
            sq += __shfl_down(sq, d, 64);
        }
        if (lane == 0) {
            float mu = sm * (1.0f / H);
            float var = sq * (1.0f / H) - mu * mu;
            smu[rr] = mu;
            srs[rr] = rsqrtf(var + LN_EPS);
        }
    }
    __syncthreads();
    float gg = g[t], bb = be[t];
#pragma unroll
    for (int r = 0; r < RPB; ++r) {
        float h = (acc[r] - smu[r]) * srs[r] * gg + bb;
        if (RELU) h = fmaxf(h, 0.0f);
        out[(rowbase + r) * H + t] = f2bf(h);
    }
}

// ---------------- MFMA row-GEMM kernels ----------------
// frag layout (16x16x32 bf16): A lane l: row l&15, k=8*(l>>4)+j ; B lane l: col l&15, same k ;
// D lane l: col l&15, row 4*(l>>4)+reg

// layer-2 GEMM + bias + LN, bf16 in -> bf16 out
__global__ __launch_bounds__(256) void k_ln_mfma(const unsigned short* __restrict__ in,
        const unsigned short* __restrict__ WT, const float* __restrict__ bias,
        const float* __restrict__ g, const float* __restrict__ be,
        unsigned short* __restrict__ outbf) {
    int t = threadIdx.x;
    int wv = t >> 6, l = t & 63;
    int lr = l & 15, lg = l >> 4;
    int rb = blockIdx.x * 64 + wv * 16;
    int arow = rb + lr; if (arow >= N_NODES) arow = N_NODES - 1;
    bf16x8 af[8];
    const unsigned short* ap = in + (long long)arow * H + lg * 8;
#pragma unroll
    for (int ks = 0; ks < 8; ++ks) af[ks] = __builtin_bit_cast(bf16x8, *(const u16x8*)(ap + ks * 32));
    f32x4 acc[16];
#pragma unroll
    for (int ct = 0; ct < 16; ++ct) acc[ct] = (f32x4){0.f, 0.f, 0.f, 0.f};
    for (int ct = 0; ct < 16; ++ct) {
        const unsigned short* wr = WT + (ct * 16 + lr) * H + lg * 8;
#pragma unroll
        for (int ks = 0; ks < 8; ++ks) {
            bf16x8 bfv = __builtin_bit_cast(bf16x8, *(const u16x8*)(wr + ks * 32));
            acc[ct] = __builtin_amdgcn_mfma_f32_16x16x32_bf16(af[ks], bfv, acc[ct], 0, 0, 0);
        }
    }
#pragma unroll
    for (int ct = 0; ct < 16; ++ct) {
        float bb = bias[ct * 16 + lr];
#pragma unroll
        for (int q = 0; q < 4; ++q) acc[ct][q] += bb;
    }
    float mean[4], rstd[4];
#pragma unroll
    for (int q = 0; q < 4; ++q) {
        float s = 0.f, s2 = 0.f;
#pragma unroll
        for (int ct = 0; ct < 16; ++ct) { float v = acc[ct][q]; s += v; s2 += v * v; }
#pragma unroll
        for (int m = 1; m < 16; m <<= 1) { s += __shfl_xor(s, m, 64); s2 += __shfl_xor(s2, m, 64); }
        float mu = s * (1.0f / H);
        mean[q] = mu;
        rstd[q] = rsqrtf(s2 * (1.0f / H) - mu * mu + LN_EPS);
    }
#pragma unroll
    for (int ct = 0; ct < 16; ++ct) {
        int col = ct * 16 + lr;
        float gg = g[col], bb = be[col];
#pragma unroll
        for (int q = 0; q < 4; ++q) {
            int row = rb + lg * 4 + q;
            if (row < N_NODES) {
                float nv = (acc[ct][q] - mean[q]) * rstd[q] * gg + bb;
                outbf[(long long)row * H + col] = f2bf(nv);
            }
        }
    }
}

// GRU step (h0=0): out = (1-z)*n, bf16 in -> bf16 din[.][0..255]; 32 rows/wave
__global__ __launch_bounds__(256) void k_gru_mfma(const unsigned short* __restrict__ h2,
        const unsigned short* __restrict__ Wg, const float* __restrict__ bih,
        const float* __restrict__ bhh, unsigned short* __restrict__ din) {
    int t = threadIdx.x;
    int wv = t >> 6, l = t & 63;
    int lr = l & 15, lg = l >> 4;
    int rb = blockIdx.x * 128 + wv * 32;
    int rA = rb + lr;      if (rA >= N_NODES) rA = N_NODES - 1;
    int rB = rb + 16 + lr; if (rB >= N_NODES) rB = N_NODES - 1;
    bf16x8 afA[8], afB[8];
    const unsigned short* apA = h2 + (long long)rA * H + lg * 8;
    const unsigned short* apB = h2 + (long long)rB * H + lg * 8;
#pragma unroll
    for (int ks = 0; ks < 8; ++ks) {
        afA[ks] = __builtin_bit_cast(bf16x8, *(const u16x8*)(apA + ks * 32));
        afB[ks] = __builtin_bit_cast(bf16x8, *(const u16x8*)(apB + ks * 32));
    }
    for (int ct = 0; ct < 16; ++ct) {
        f32x4 z4 = (f32x4){0.f, 0.f, 0.f, 0.f};
        f32x4 aRA = z4, aZA = z4, aNA = z4, aRB = z4, aZB = z4, aNB = z4;
        const unsigned short* w0 = Wg + (ct * 16 + lr) * H + lg * 8;
        const unsigned short* w1 = w0 + 256 * H;
        const unsigned short* w2 = w0 + 512 * H;
#pragma unroll
        for (int ks = 0; ks < 8; ++ks) {
            bf16x8 b0 = __builtin_bit_cast(bf16x8, *(const u16x8*)(w0 + ks * 32));
            bf16x8 b1 = __builtin_bit_cast(bf16x8, *(const u16x8*)(w1 + ks * 32));
            bf16x8 b2 = __builtin_bit_cast(bf16x8, *(const u16x8*)(w2 + ks * 32));
            aRA = __builtin_amdgcn_mfma_f32_16x16x32_bf16(afA[ks], b0, aRA, 0, 0, 0);
            aRB = __builtin_amdgcn_mfma_f32_16x16x32_bf16(afB[ks], b0, aRB, 0, 0, 0);
            aZA = __builtin_amdgcn_mfma_f32_16x16x32_bf16(afA[ks], b1, aZA, 0, 0, 0);
            aZB = __builtin_amdgcn_mfma_f32_16x16x32_bf16(afB[ks], b1, aZB, 0, 0, 0);
            aNA = __builtin_amdgcn_mfma_f32_16x16x32_bf16(afA[ks], b2, aNA, 0, 0, 0);
            aNB = __builtin_amdgcn_mfma_f32_16x16x32_bf16(afB[ks], b2, aNB, 0, 0, 0);
        }
        int col = ct * 16 + lr;
        float bR = bih[col] + bhh[col];
        float bZ = bih[col + 256] + bhh[col + 256];
        float bN = bih[col + 512];
        float hN = bhh[col + 512];
#pragma unroll
        for (int q = 0; q < 4; ++q) {
            {
                int row = rb + lg * 4 + q;
                float r = 1.0f / (1.0f + expf(-(aRA[q] + bR)));
                float z = 1.0f / (1.0f + expf(-(aZA[q] + bZ)));
                float n = tanhf(aNA[q] + bN + r * hN);
                if (row < N_NODES) din[(long long)row * 288 + col] = f2bf((1.0f - z) * n);
            }
            {
                int row = rb + 16 + lg * 4 + q;
                float r = 1.0f / (1.0f + expf(-(aRB[q] + bR)));
                float z = 1.0f / (1.0f + expf(-(aZB[q] + bZ)));
                float n = tanhf(aNB[q] + bN + r * hN);
                if (row < N_NODES) din[(long long)row * 288 + col] = f2bf((1.0f - z) * n);
            }
        }
    }
}

// decoder layer 1: relu(din @ Wd1T + bd1), K=288, bf16 -> bf16
__global__ __launch_bounds__(256) void k_d1_mfma(const unsigned short* __restrict__ din,
        const unsigned short* __restrict__ WT, const float* __restrict__ bias,
        unsigned short* __restrict__ outbf) {
    int t = threadIdx.x;
    int wv = t >> 6, l = t & 63;
    int lr = l & 15, lg = l >> 4;
    int rb = blockIdx.x * 64 + wv * 16;
    int arow = rb + lr; if (arow >= N_NODES) arow = N_NODES - 1;
    bf16x8 af[9];
    const unsigned short* ap = din + (long long)arow * 288 + lg * 8;
#pragma unroll
    for (int ks = 0; ks < 9; ++ks) af[ks] = __builtin_bit_cast(bf16x8, *(const u16x8*)(ap + ks * 32));
    f32x4 acc[16];
#pragma unroll
    for (int ct = 0; ct < 16; ++ct) acc[ct] = (f32x4){0.f, 0.f, 0.f, 0.f};
    for (int ct = 0; ct < 16; ++ct) {
        const unsigned short* wr = WT + (ct * 16 + lr) * 288 + lg * 8;
#pragma unroll
        for (int ks = 0; ks < 9; ++ks) {
            bf16x8 bfv = __builtin_bit_cast(bf16x8, *(const u16x8*)(wr + ks * 32));
            acc[ct] = __builtin_amdgcn_mfma_f32_16x16x32_bf16(af[ks], bfv, acc[ct], 0, 0, 0);
        }
    }
#pragma unroll
    for (int ct = 0; ct < 16; ++ct) {
        int col = ct * 16 + lr;
        float bb = bias[col];
#pragma unroll
        for (int q = 0; q < 4; ++q) {
            int row = rb + lg * 4 + q;
            if (row < N_NODES) {
                float v = fmaxf(acc[ct][q] + bb, 0.0f);
                outbf[(long long)row * H + col] = f2bf(v);
            }
        }
    }
}

// decoder layers 2+3: d2 = relu(d1 @ Wd2T + bd2) [N=128]; pred = clip(d2 @ Wd3 + bd3)
__global__ __launch_bounds__(256) void k_d23_mfma(const unsigned short* __restrict__ d1,
        const unsigned short* __restrict__ WT, const float* __restrict__ bd2,
        const float* __restrict__ Wd3, const float* __restrict__ bd3, float* __restrict__ out) {
    int t = threadIdx.x;
    int wv = t >> 6, l = t & 63;
    int lr = l & 15, lg = l >> 4;
    int rb = blockIdx.x * 64 + wv * 16;
    int arow = rb + lr; if (arow >= N_NODES) arow = N_NODES - 1;
    bf16x8 af[8];
    const unsigned short* ap = d1 + (long long)arow * H + lg * 8;
#pragma unroll
    for (int ks = 0; ks < 8; ++ks) af[ks] = __builtin_bit_cast(bf16x8, *(const u16x8*)(ap + ks * 32));
    f32x4 acc[8];
#pragma unroll
    for (int ct = 0; ct < 8; ++ct) acc[ct] = (f32x4){0.f, 0.f, 0.f, 0.f};
    for (int ct = 0; ct < 8; ++ct) {
        const unsigned short* wr = WT + (ct * 16 + lr) * H + lg * 8;
#pragma unroll
        for (int ks = 0; ks < 8; ++ks) {
            bf16x8 bfv = __builtin_bit_cast(bf16x8, *(const u16x8*)(wr + ks * 32));
            acc[ct] = __builtin_amdgcn_mfma_f32_16x16x32_bf16(af[ks], bfv, acc[ct], 0, 0, 0);
        }
    }
    float p0[4] = {0.f, 0.f, 0.f, 0.f}, p1[4] = {0.f, 0.f, 0.f, 0.f};
#pragma unroll
    for (int ct = 0; ct < 8; ++ct) {
        int col = ct * 16 + lr;
        float bb = bd2[col];
        float2 w3 = *(const float2*)(Wd3 + col * 2);
#pragma unroll
        for (int q = 0; q < 4; ++q) {
            float v = fmaxf(acc[ct][q] + bb, 0.0f);
            p0[q] = fmaf(v, w3.x, p0[q]);
            p1[q] = fmaf(v, w3.y, p1[q]);
        }
    }
#pragma unroll
    for (int q = 0; q < 4; ++q) {
#pragma unroll
        for (int m = 1; m < 16; m <<= 1) {
            p0[q] += __shfl_xor(p0[q], m, 64);
            p1[q] += __shfl_xor(p1[q], m, 64);
        }
    }
    if (lr == 0) {
#pragma unroll
        for (int q = 0; q < 4; ++q) {
            int row = rb + lg * 4 + q;
            if (row < N_NODES) {
                float a = fminf(fmaxf(p0[q] + bd3[0], -5.0f), 5.0f);
                float b = fminf(fmaxf(p1[q] + bd3[1], -5.0f), 5.0f);
                out[(long long)row * 2] = a;
                out[(long long)row * 2 + 1] = b;
            }
        }
    }
}

extern "C" void kernel_launch(void* const* d_in, const int* in_sizes, int n_in,
                              void* d_out, int out_size, void* d_ws, size_t ws_size,
                              hipStream_t stream) {
    const float* x   = (const float*)d_in[0];
    const void*  ei  = d_in[1];
    const float* ew  = (const float*)d_in[2];
    const float* W1  = (const float*)d_in[3];
    const float* b1  = (const float*)d_in[4];
    const float* g1  = (const float*)d_in[5];
    const float* be1 = (const float*)d_in[6];
    const float* W2  = (const float*)d_in[7];
    const float* b2  = (const float*)d_in[8];
    const float* g2  = (const float*)d_in[9];
    const float* be2 = (const float*)d_in[10];
    const float* Wih = (const float*)d_in[11];
    const float* bih = (const float*)d_in[13];
    const float* bhh = (const float*)d_in[14];
    const float* Wd1 = (const float*)d_in[15];
    const float* bd1 = (const float*)d_in[16];
    const float* Wd2 = (const float*)d_in[17];
    const float* bd2 = (const float*)d_in[18];
    const float* Wd3 = (const float*)d_in[19];
    const float* bd3 = (const float*)d_in[20];
    float* out = (float*)d_out;

    char* w = (char*)d_ws;
    size_t pos = 0;
    auto carve = [&](size_t bytes) -> void* {
        void* p = w + pos;
        pos += (bytes + 255) & ~(size_t)255;
        return p;
    };
    int*   flag  = (int*)  carve(4);
    int*   es    = (int*)  carve(sizeof(int) * N_EDGES);
    int*   ed    = (int*)  carve(sizeof(int) * N_EDGES);
    float* dis   = (float*)carve(sizeof(float) * N_NODES);
    int*   cnt   = (int*)  carve(sizeof(int) * N_NODES);
    int*   offs  = (int*)  carve(sizeof(int) * (N_NODES + 1));
    int*   bsum  = (int*)  carve(sizeof(int) * 64);
    int*   bsoff = (int*)  carve(sizeof(int) * 64);
    int*   csr_s = (int*)  carve(sizeof(int) * N_EDGES);
    float* csr_c = (float*)carve(sizeof(float) * N_EDGES);
    unsigned short* Wg   = (unsigned short*)carve(2 * 768 * 256);
    unsigned short* W2T  = (unsigned short*)carve(2 * 256 * 256);
    unsigned short* Wd1T = (unsigned short*)carve(2 * 256 * 288);
    unsigned short* Wd2T = (unsigned short*)carve(2 * 128 * 256);
    float* agg0  = (float*)carve(sizeof(float) * (size_t)N_NODES * DIN);
    unsigned short* Abf = (unsigned short*)carve(2 * (size_t)N_NODES * H);  // h1 bf16
    unsigned short* Bbf = (unsigned short*)carve(2 * (size_t)N_NODES * H);  // agg(h1) bf16
    unsigned short* din = (unsigned short*)carve(2 * (size_t)N_NODES * 288); // [temporal, x] bf16
    // aliases over dead regions
    unsigned short* h2bf = Abf;   // after spmm consumed Abf
    unsigned short* d1bf = Bbf;   // after ln_mfma consumed Bbf
    (void)pos; (void)ws_size; (void)in_sizes; (void)n_in; (void)out_size;

    int gE = (N_EDGES + 255) / 256;
    int gN = (N_NODES + 255) / 256;
    int nscan = (N_NODES + 1023) / 1024;  // 49
    int nbm = (N_NODES + 63) / 64;        // 782 blocks for 16-row/wave MFMA kernels
    int nbg = (N_NODES + 127) / 128;      // 391 blocks for 32-row/wave GRU

    k_detect<<<1, 1, 0, stream>>>(ei, flag);
    k_init<<<gN, 256, 0, stream>>>(dis, cnt);
    k_convert<<<gE, 256, 0, stream>>>(ei, flag, es, ed, ew, dis, cnt);
    k_rsqrt<<<gN, 256, 0, stream>>>(dis);
    k_scan1<<<nscan, 256, 0, stream>>>(cnt, bsum);
    k_scan2<<<1, 64, 0, stream>>>(bsum, bsoff, offs, nscan);
    k_scan3<<<nscan, 256, 0, stream>>>(cnt, bsoff, offs, cnt);  // cnt reused as cursor
    k_fill<<<gE, 256, 0, stream>>>(es, ed, ew, dis, cnt, csr_s, csr_c);
    k_wihbf<<<(768 * 256 + 255) / 256, 256, 0, stream>>>(Wih, Wg);
    k_w2t<<<(256 * 256 + 255) / 256, 256, 0, stream>>>(W2, W2T);
    k_wd1t<<<(256 * 288 + 255) / 256, 256, 0, stream>>>(Wd1, Wd1T);
    k_wd2t<<<(256 * 128 + 255) / 256, 256, 0, stream>>>(Wd2, Wd2T);

    k_agg0<<<N_NODES / 16, 256, 0, stream>>>(x, offs, csr_s, csr_c, dis, agg0);
    k_gemm_ln<DIN, true><<<N_NODES / RPB, 256, 0, stream>>>(agg0, Abf, W1, b1, g1, be1);
    k_spmm<<<N_NODES / 4, 256, 0, stream>>>(Abf, Bbf, offs, csr_s, csr_c, dis);
    k_ln_mfma<<<nbm, 256, 0, stream>>>(Bbf, W2T, b2, g2, be2, h2bf);    // Abf dead -> h2bf
    k_xfill<<<(N_NODES * 32 + 255) / 256, 256, 0, stream>>>(x, din);
    k_gru_mfma<<<nbg, 256, 0, stream>>>(h2bf, Wg, bih, bhh, din);
    k_d1_mfma<<<nbm, 256, 0, stream>>>(din, Wd1T, bd1, d1bf);           // Bbf dead -> d1bf
    k_d23_mfma<<<nbm, 256, 0, stream>>>(d1bf, Wd2T, bd2, Wd3, bd3, out);
}

// Round 4
// 732.320 us; speedup vs baseline: 1.9192x; 1.0968x over previous
//
#include <hip/hip_runtime.h>
#include <math.h>

#define N_NODES 50000
#define N_EDGES 1600000
#define DIN 16
#define H 256
#define RPB 16
#define LN_EPS 1e-5f

typedef __attribute__((ext_vector_type(8))) unsigned short u16x8;
typedef __attribute__((ext_vector_type(8))) __bf16 bf16x8;
typedef __attribute__((ext_vector_type(4))) float f32x4;

__device__ inline unsigned short f2bf(float f) {
    unsigned u = __builtin_bit_cast(unsigned, f);
    return (unsigned short)((u + 0x7FFFu + ((u >> 16) & 1u)) >> 16);
}
__device__ inline float bf2f(unsigned short u) {
    return __builtin_bit_cast(float, ((unsigned)u) << 16);
}

// ---------------- edge dtype detect ----------------
__global__ void k_detect(const void* ei, int* flag) {
    const long long* p = (const long long*)ei;
    bool is64 = true;
    for (int i = 0; i < 8; ++i) {
        long long v = p[i];
        if (v < 0 || v >= N_NODES) is64 = false;
    }
    *flag = is64 ? 1 : 0;
}

// ---------------- init deg/cnt ----------------
__global__ void k_init(float* deg, int* cnt) {
    int i = blockIdx.x * blockDim.x + threadIdx.x;
    if (i < N_NODES) { deg[i] = 2.0f; cnt[i] = 0; }
}

// ---------------- convert edges + degree accumulation (fused) ----------------
__global__ void k_convert(const void* ei, const int* flag, int* es, int* ed,
                          const float* ew, float* deg, int* cnt) {
    int e = blockIdx.x * blockDim.x + threadIdx.x;
    if (e >= N_EDGES) return;
    int s, d;
    if (*flag) {
        const long long* p = (const long long*)ei;
        s = (int)p[e];
        d = (int)p[N_EDGES + e];
    } else {
        const int* p = (const int*)ei;
        s = p[e];
        d = p[N_EDGES + e];
    }
    es[e] = s;
    ed[e] = d;
    atomicAdd(&deg[d], ew[e]);
    atomicAdd(&cnt[d], 1);
}

__global__ void k_rsqrt(float* deg) {
    int i = blockIdx.x * blockDim.x + threadIdx.x;
    if (i < N_NODES) deg[i] = rsqrtf(deg[i]);   // deg >= 2 always
}

// ---------------- exclusive scan of cnt -> offs (chunk 1024) ----------------
__global__ void k_scan1(const int* cnt, int* bsum) {
    __shared__ int ws_[4];
    int b = blockIdx.x, t = threadIdx.x;
    int s = 0;
    for (int k = 0; k < 4; ++k) {
        int idx = b * 1024 + k * 256 + t;
        if (idx < N_NODES) s += cnt[idx];
    }
    for (int d = 32; d; d >>= 1) s += __shfl_down(s, d, 64);
    if ((t & 63) == 0) ws_[t >> 6] = s;
    __syncthreads();
    if (t == 0) bsum[b] = ws_[0] + ws_[1] + ws_[2] + ws_[3];
}

__global__ void k_scan2(const int* bsum, int* bsoff, int* offs, int nblk) {
    if (threadIdx.x == 0) {
        int run = 0;
        for (int i = 0; i < nblk; ++i) { bsoff[i] = run; run += bsum[i]; }
        offs[N_NODES] = run;
    }
}

__global__ void k_scan3(const int* cnt, const int* bsoff, int* offs, int* cursor) {
    __shared__ int wsum[4];
    int b = blockIdx.x, t = threadIdx.x;
    int lane = t & 63, wv = t >> 6;
    int base = b * 1024 + t * 4;
    int v[4];
    for (int k = 0; k < 4; ++k) {
        int idx = base + k;
        v[k] = (idx < N_NODES) ? cnt[idx] : 0;
    }
    int ts = v[0] + v[1] + v[2] + v[3];
    int sc = ts;
    for (int d = 1; d < 64; d <<= 1) {
        int u = __shfl_up(sc, d, 64);
        if (lane >= d) sc += u;
    }
    if (lane == 63) wsum[wv] = sc;
    __syncthreads();
    int wpre = 0;
    for (int i = 0; i < wv; ++i) wpre += wsum[i];
    int ex = wpre + sc - ts + bsoff[b];
    for (int k = 0; k < 4; ++k) {
        int idx = base + k;
        if (idx < N_NODES) { offs[idx] = ex; cursor[idx] = ex; }
        ex += v[k];
    }
}

__global__ void k_fill(const int* es, const int* ed, const float* ew, const float* dis,
                       int* cursor, int* csr_s, float* csr_c) {
    int e = blockIdx.x * blockDim.x + threadIdx.x;
    if (e >= N_EDGES) return;
    int s = es[e], d = ed[e];
    int p = atomicAdd(&cursor[d], 1);
    csr_s[p] = s;
    csr_c[p] = dis[s] * ew[e] * dis[d];
}

// ---------------- weight prep: fp32 -> bf16 (with transpose where needed) ----------------
__global__ void k_wihbf(const float* Wih, unsigned short* Wg) {
    int idx = blockIdx.x * blockDim.x + threadIdx.x;
    if (idx < 768 * 256) Wg[idx] = f2bf(Wih[idx]);   // already [out_col][k]
}

__global__ void k_w2t(const float* W2, unsigned short* W2T) {  // W2[k][n] -> W2T[n][k]
    int idx = blockIdx.x * blockDim.x + threadIdx.x;
    if (idx >= 256 * 256) return;
    int k = idx >> 8, n = idx & 255;
    W2T[n * 256 + k] = f2bf(W2[idx]);
}

__global__ void k_wd1t(const float* Wd1, unsigned short* T) {  // Wd1[272][256] -> T[n][288] (k padded)
    int idx = blockIdx.x * blockDim.x + threadIdx.x;
    if (idx >= 256 * 288) return;
    int n = idx / 288, k = idx % 288;
    T[idx] = (k < 272) ? f2bf(Wd1[k * 256 + n]) : (unsigned short)0;
}

__global__ void k_wd2t(const float* Wd2, unsigned short* T) {  // Wd2[256][128] -> T[n][256]
    int idx = blockIdx.x * blockDim.x + threadIdx.x;
    if (idx >= 256 * 128) return;
    int k = idx >> 7, n = idx & 127;
    T[n * 256 + k] = f2bf(Wd2[idx]);
}

// fill decoder-input x columns: din[row][256+j] = bf16(x[row][j]) (j<16), 0 pad to 288
__global__ void k_xfill(const float* x, unsigned short* din) {
    int idx = blockIdx.x * blockDim.x + threadIdx.x;
    if (idx >= N_NODES * 32) return;
    int row = idx >> 5, j = idx & 31;
    din[(long long)row * 288 + 256 + j] = (j < 16) ? f2bf(x[row * DIN + j]) : (unsigned short)0;
}

// ---------------- aggregation in DIN space (layer 1), 8-deep MLP ----------------
__global__ __launch_bounds__(256) void k_agg0(const float* __restrict__ x, const int* __restrict__ offs,
                                              const int* __restrict__ csr_s, const float* __restrict__ csr_c,
                                              const float* __restrict__ dis, float* __restrict__ agg0) {
    int t = threadIdx.x;
    int r = blockIdx.x * 16 + (t >> 4);
    int dd = t & 15;
    float di = dis[r];
    float acc = 2.0f * di * di * x[(long long)r * DIN + dd];
    int e0 = offs[r], e1 = offs[r + 1];
    for (int e = e0; e < e1; e += 8) {
        int ss[8]; float cc[8]; float xx[8];
#pragma unroll
        for (int j = 0; j < 8; ++j) {
            int idx = e + j;
            bool ok = idx < e1;
            ss[j] = ok ? csr_s[idx] : r;
            cc[j] = ok ? csr_c[idx] : 0.0f;
        }
#pragma unroll
        for (int j = 0; j < 8; ++j) xx[j] = x[(long long)ss[j] * DIN + dd];
#pragma unroll
        for (int j = 0; j < 8; ++j) acc = fmaf(cc[j], xx[j], acc);
    }
    agg0[(long long)r * DIN + dd] = acc;
}

// ---------------- SpMM in H space (layer 2 aggregation), bf16 rows, 8-deep MLP ----------------
__global__ __launch_bounds__(256) void k_spmm(const unsigned short* __restrict__ hin,
                                              unsigned short* __restrict__ hout, const int* __restrict__ offs,
                                              const int* __restrict__ csr_s, const float* __restrict__ csr_c,
                                              const float* __restrict__ dis) {
    int t = threadIdx.x;
    int wv = t >> 6, lane = t & 63;
    int row = blockIdx.x * 4 + wv;
    const ushort4* h4 = (const ushort4*)hin;
    float di = dis[row];
    float cself = 2.0f * di * di;
    ushort4 v = h4[(long long)row * 64 + lane];
    float a0 = cself * bf2f(v.x), a1 = cself * bf2f(v.y);
    float a2 = cself * bf2f(v.z), a3 = cself * bf2f(v.w);
    int e0 = offs[row], e1 = offs[row + 1];
    for (int e = e0; e < e1; e += 8) {
        int ss[8]; float cc[8]; ushort4 uu[8];
#pragma unroll
        for (int j = 0; j < 8; ++j) {
            int idx = e + j;
            bool ok = idx < e1;
            ss[j] = ok ? csr_s[idx] : row;
            cc[j] = ok ? csr_c[idx] : 0.0f;
        }
#pragma unroll
        for (int j = 0; j < 8; ++j) uu[j] = h4[(long long)ss[j] * 64 + lane];
#pragma unroll
        for (int j = 0; j < 8; ++j) {
            a0 = fmaf(cc[j], bf2f(uu[j].x), a0);
            a1 = fmaf(cc[j], bf2f(uu[j].y), a1);
            a2 = fmaf(cc[j], bf2f(uu[j].z), a2);
            a3 = fmaf(cc[j], bf2f(uu[j].w), a3);
        }
    }
    ushort4 o;
    o.x = f2bf(a0); o.y = f2bf(a1); o.z = f2bf(a2); o.w = f2bf(a3);
    ((ushort4*)hout)[(long long)row * 64 + lane] = o;
}

// ---------------- layer-1 GEMM (16 -> 256) + bias + LN + relu (fp32 VALU), bf16 out ----------------
template <int K, bool RELU>
__global__ __launch_bounds__(256) void k_gemm_ln(const float* in, unsigned short* out, const float* W,
                                                 const float* bias, const float* g, const float* be) {
    __shared__ float s[RPB][H + 1];
    __shared__ float smu[RPB], srs[RPB];
    int t = threadIdx.x;
    long long rowbase = (long long)blockIdx.x * RPB;
    for (int idx = t; idx < RPB * K; idx += 256) {
        int r = idx / K, k = idx % K;
        s[r][k] = in[(rowbase + r) * K + k];
    }
    __syncthreads();
    float acc[RPB];
    float bb0 = bias[t];
#pragma unroll
    for (int r = 0; r < RPB; ++r) acc[r] = bb0;
    for (int k = 0; k < K; ++k) {
        float wv = W[k * H + t];
#pragma unroll
        for (int r = 0; r < RPB; ++r) acc[r] = fmaf(s[r][k], wv, acc[r]);
    }
    __syncthreads();
#pragma unroll
    for (int r = 0; r < RPB; ++r) s[r][t] = acc[r];
    __syncthreads();
    int lane = t & 63, wv2 = t >> 6;
    for (int rr = wv2; rr < RPB; rr += 4) {
        float v0 = s[rr][lane], v1 = s[rr][lane + 64], v2 = s[rr][lane + 128], v3 = s[rr][lane + 192];
        float sm = v0 + v1 + v2 + v3;
        float sq = v0 * v0 + v1 * v1 + v2 * v2 + v3 * v3;
        for (int d = 32; d; d >>= 1) {
            sm += __shfl_down(sm, d, 64);
            sq += __shfl_down(sq, d, 64);
        }
        if (lane == 0) {
            float mu = sm * (1.0f / H);
            float var = sq * (1.0f / H) - mu * mu;
            smu[rr] = mu;
            srs[rr] = rsqrtf(var + LN_EPS);
        }
    }
    __syncthreads();
    float gg = g[t], bb = be[t];
#pragma unroll
    for (int r = 0; r < RPB; ++r) {
        float h = (acc[r] - smu[r]) * srs[r] * gg + bb;
        if (RELU) h = fmaxf(h, 0.0f);
        out[(rowbase + r) * H + t] = f2bf(h);
    }
}

// ---------------- MFMA row-GEMM kernels ----------------
// frag layout (16x16x32 bf16): A lane l: row l&15, k=8*(l>>4)+j ; B lane l: col l&15, same k ;
// D lane l: col l&15, row 4*(l>>4)+reg

// layer-2 GEMM + bias + LN, bf16 in -> bf16 out
__global__ __launch_bounds__(256) void k_ln_mfma(const unsigned short* __restrict__ in,
        const unsigned short* __restrict__ WT, const float* __restrict__ bias,
        const float* __restrict__ g, const float* __restrict__ be,
        unsigned short* __restrict__ outbf) {
    int t = threadIdx.x;
    int wv = t >> 6, l = t & 63;
    int lr = l & 15, lg = l >> 4;
    int rb = blockIdx.x * 64 + wv * 16;
    int arow = rb + lr; if (arow >= N_NODES) arow = N_NODES - 1;
    bf16x8 af[8];
    const unsigned short* ap = in + (long long)arow * H + lg * 8;
#pragma unroll
    for (int ks = 0; ks < 8; ++ks) af[ks] = __builtin_bit_cast(bf16x8, *(const u16x8*)(ap + ks * 32));
    f32x4 acc[16];
#pragma unroll
    for (int ct = 0; ct < 16; ++ct) acc[ct] = (f32x4){0.f, 0.f, 0.f, 0.f};
    for (int ct = 0; ct < 16; ++ct) {
        const unsigned short* wr = WT + (ct * 16 + lr) * H + lg * 8;
#pragma unroll
        for (int ks = 0; ks < 8; ++ks) {
            bf16x8 bfv = __builtin_bit_cast(bf16x8, *(const u16x8*)(wr + ks * 32));
            acc[ct] = __builtin_amdgcn_mfma_f32_16x16x32_bf16(af[ks], bfv, acc[ct], 0, 0, 0);
        }
    }
#pragma unroll
    for (int ct = 0; ct < 16; ++ct) {
        float bb = bias[ct * 16 + lr];
#pragma unroll
        for (int q = 0; q < 4; ++q) acc[ct][q] += bb;
    }
    float mean[4], rstd[4];
#pragma unroll
    for (int q = 0; q < 4; ++q) {
        float s = 0.f, s2 = 0.f;
#pragma unroll
        for (int ct = 0; ct < 16; ++ct) { float v = acc[ct][q]; s += v; s2 += v * v; }
#pragma unroll
        for (int m = 1; m < 16; m <<= 1) { s += __shfl_xor(s, m, 64); s2 += __shfl_xor(s2, m, 64); }
        float mu = s * (1.0f / H);
        mean[q] = mu;
        rstd[q] = rsqrtf(s2 * (1.0f / H) - mu * mu + LN_EPS);
    }
#pragma unroll
    for (int ct = 0; ct < 16; ++ct) {
        int col = ct * 16 + lr;
        float gg = g[col], bb = be[col];
#pragma unroll
        for (int q = 0; q < 4; ++q) {
            int row = rb + lg * 4 + q;
            if (row < N_NODES) {
                float nv = (acc[ct][q] - mean[q]) * rstd[q] * gg + bb;
                outbf[(long long)row * H + col] = f2bf(nv);
            }
        }
    }
}

// GRU step (h0=0): out = (1-z)*n, bf16 in -> bf16 din[.][0..255]; 32 rows/wave
__global__ __launch_bounds__(256) void k_gru_mfma(const unsigned short* __restrict__ h2,
        const unsigned short* __restrict__ Wg, const float* __restrict__ bih,
        const float* __restrict__ bhh, unsigned short* __restrict__ din) {
    int t = threadIdx.x;
    int wv = t >> 6, l = t & 63;
    int lr = l & 15, lg = l >> 4;
    int rb = blockIdx.x * 128 + wv * 32;
    int rA = rb + lr;      if (rA >= N_NODES) rA = N_NODES - 1;
    int rB = rb + 16 + lr; if (rB >= N_NODES) rB = N_NODES - 1;
    bf16x8 afA[8], afB[8];
    const unsigned short* apA = h2 + (long long)rA * H + lg * 8;
    const unsigned short* apB = h2 + (long long)rB * H + lg * 8;
#pragma unroll
    for (int ks = 0; ks < 8; ++ks) {
        afA[ks] = __builtin_bit_cast(bf16x8, *(const u16x8*)(apA + ks * 32));
        afB[ks] = __builtin_bit_cast(bf16x8, *(const u16x8*)(apB + ks * 32));
    }
    for (int ct = 0; ct < 16; ++ct) {
        f32x4 z4 = (f32x4){0.f, 0.f, 0.f, 0.f};
        f32x4 aRA = z4, aZA = z4, aNA = z4, aRB = z4, aZB = z4, aNB = z4;
        const unsigned short* w0 = Wg + (ct * 16 + lr) * H + lg * 8;
        const unsigned short* w1 = w0 + 256 * H;
        const unsigned short* w2 = w0 + 512 * H;
#pragma unroll
        for (int ks = 0; ks < 8; ++ks) {
            bf16x8 b0 = __builtin_bit_cast(bf16x8, *(const u16x8*)(w0 + ks * 32));
            bf16x8 b1 = __builtin_bit_cast(bf16x8, *(const u16x8*)(w1 + ks * 32));
            bf16x8 b2 = __builtin_bit_cast(bf16x8, *(const u16x8*)(w2 + ks * 32));
            aRA = __builtin_amdgcn_mfma_f32_16x16x32_bf16(afA[ks], b0, aRA, 0, 0, 0);
            aRB = __builtin_amdgcn_mfma_f32_16x16x32_bf16(afB[ks], b0, aRB, 0, 0, 0);
            aZA = __builtin_amdgcn_mfma_f32_16x16x32_bf16(afA[ks], b1, aZA, 0, 0, 0);
            aZB = __builtin_amdgcn_mfma_f32_16x16x32_bf16(afB[ks], b1, aZB, 0, 0, 0);
            aNA = __builtin_amdgcn_mfma_f32_16x16x32_bf16(afA[ks], b2, aNA, 0, 0, 0);
            aNB = __builtin_amdgcn_mfma_f32_16x16x32_bf16(afB[ks], b2, aNB, 0, 0, 0);
        }
        int col = ct * 16 + lr;
        float bR = bih[col] + bhh[col];
        float bZ = bih[col + 256] + bhh[col + 256];
        float bN = bih[col + 512];
        float hN = bhh[col + 512];
#pragma unroll
        for (int q = 0; q < 4; ++q) {
            {
                int row = rb + lg * 4 + q;
                float r = 1.0f / (1.0f + expf(-(aRA[q] + bR)));
                float z = 1.0f / (1.0f + expf(-(aZA[q] + bZ)));
                float n = tanhf(aNA[q] + bN + r * hN);
                if (row < N_NODES) din[(long long)row * 288 + col] = f2bf((1.0f - z) * n);
            }
            {
                int row = rb + 16 + lg * 4 + q;
                float r = 1.0f / (1.0f + expf(-(aRB[q] + bR)));
                float z = 1.0f / (1.0f + expf(-(aZB[q] + bZ)));
                float n = tanhf(aNB[q] + bN + r * hN);
                if (row < N_NODES) din[(long long)row * 288 + col] = f2bf((1.0f - z) * n);
            }
        }
    }
}

// decoder layer 1: relu(din @ Wd1T + bd1), K=288, bf16 -> bf16
__global__ __launch_bounds__(256) void k_d1_mfma(const unsigned short* __restrict__ din,
        const unsigned short* __restrict__ WT, const float* __restrict__ bias,
        unsigned short* __restrict__ outbf) {
    int t = threadIdx.x;
    int wv = t >> 6, l = t & 63;
    int lr = l & 15, lg = l >> 4;
    int rb = blockIdx.x * 64 + wv * 16;
    int arow = rb + lr; if (arow >= N_NODES) arow = N_NODES - 1;
    bf16x8 af[9];
    const unsigned short* ap = din + (long long)arow * 288 + lg * 8;
#pragma unroll
    for (int ks = 0; ks < 9; ++ks) af[ks] = __builtin_bit_cast(bf16x8, *(const u16x8*)(ap + ks * 32));
    f32x4 acc[16];
#pragma unroll
    for (int ct = 0; ct < 16; ++ct) acc[ct] = (f32x4){0.f, 0.f, 0.f, 0.f};
    for (int ct = 0; ct < 16; ++ct) {
        const unsigned short* wr = WT + (ct * 16 + lr) * 288 + lg * 8;
#pragma unroll
        for (int ks = 0; ks < 9; ++ks) {
            bf16x8 bfv = __builtin_bit_cast(bf16x8, *(const u16x8*)(wr + ks * 32));
            acc[ct] = __builtin_amdgcn_mfma_f32_16x16x32_bf16(af[ks], bfv, acc[ct], 0, 0, 0);
        }
    }
#pragma unroll
    for (int ct = 0; ct < 16; ++ct) {
        int col = ct * 16 + lr;
        float bb = bias[col];
#pragma unroll
        for (int q = 0; q < 4; ++q) {
            int row = rb + lg * 4 + q;
            if (row < N_NODES) {
                float v = fmaxf(acc[ct][q] + bb, 0.0f);
                outbf[(long long)row * H + col] = f2bf(v);
            }
        }
    }
}

// decoder layers 2+3: d2 = relu(d1 @ Wd2T + bd2) [N=128]; pred = clip(d2 @ Wd3 + bd3)
__global__ __launch_bounds__(256) void k_d23_mfma(const unsigned short* __restrict__ d1,
        const unsigned short* __restrict__ WT, const float* __restrict__ bd2,
        const float* __restrict__ Wd3, const float* __restrict__ bd3, float* __restrict__ out) {
    int t = threadIdx.x;
    int wv = t >> 6, l = t & 63;
    int lr = l & 15, lg = l >> 4;
    int rb = blockIdx.x * 64 + wv * 16;
    int arow = rb + lr; if (arow >= N_NODES) arow = N_NODES - 1;
    bf16x8 af[8];
    const unsigned short* ap = d1 + (long long)arow * H + lg * 8;
#pragma unroll
    for (int ks = 0; ks < 8; ++ks) af[ks] = __builtin_bit_cast(bf16x8, *(const u16x8*)(ap + ks * 32));
    f32x4 acc[8];
#pragma unroll
    for (int ct = 0; ct < 8; ++ct) acc[ct] = (f32x4){0.f, 0.f, 0.f, 0.f};
    for (int ct = 0; ct < 8; ++ct) {
        const unsigned short* wr = WT + (ct * 16 + lr) * H + lg * 8;
#pragma unroll
        for (int ks = 0; ks < 8; ++ks) {
            bf16x8 bfv = __builtin_bit_cast(bf16x8, *(const u16x8*)(wr + ks * 32));
            acc[ct] = __builtin_amdgcn_mfma_f32_16x16x32_bf16(af[ks], bfv, acc[ct], 0, 0, 0);
        }
    }
    float p0[4] = {0.f, 0.f, 0.f, 0.f}, p1[4] = {0.f, 0.f, 0.f, 0.f};
#pragma unroll
    for (int ct = 0; ct < 8; ++ct) {
        int col = ct * 16 + lr;
        float bb = bd2[col];
        float2 w3 = *(const float2*)(Wd3 + col * 2);
#pragma unroll
        for (int q = 0; q < 4; ++q) {
            float v = fmaxf(acc[ct][q] + bb, 0.0f);
            p0[q] = fmaf(v, w3.x, p0[q]);
            p1[q] = fmaf(v, w3.y, p1[q]);
        }
    }
#pragma unroll
    for (int q = 0; q < 4; ++q) {
#pragma unroll
        for (int m = 1; m < 16; m <<= 1) {
            p0[q] += __shfl_xor(p0[q], m, 64);
            p1[q] += __shfl_xor(p1[q], m, 64);
        }
    }
    if (lr == 0) {
#pragma unroll
        for (int q = 0; q < 4; ++q) {
            int row = rb + lg * 4 + q;
            if (row < N_NODES) {
                float a = fminf(fmaxf(p0[q] + bd3[0], -5.0f), 5.0f);
                float b = fminf(fmaxf(p1[q] + bd3[1], -5.0f), 5.0f);
                out[(long long)row * 2] = a;
                out[(long long)row * 2 + 1] = b;
            }
        }
    }
}

extern "C" void kernel_launch(void* const* d_in, const int* in_sizes, int n_in,
                              void* d_out, int out_size, void* d_ws, size_t ws_size,
                              hipStream_t stream) {
    const float* x   = (const float*)d_in[0];
    const void*  ei  = d_in[1];
    const float* ew  = (const float*)d_in[2];
    const float* W1  = (const float*)d_in[3];
    const float* b1  = (const float*)d_in[4];
    const float* g1  = (const float*)d_in[5];
    const float* be1 = (const float*)d_in[6];
    const float* W2  = (const float*)d_in[7];
    const float* b2  = (const float*)d_in[8];
    const float* g2  = (const float*)d_in[9];
    const float* be2 = (const float*)d_in[10];
    const float* Wih = (const float*)d_in[11];
    const float* bih = (const float*)d_in[13];
    const float* bhh = (const float*)d_in[14];
    const float* Wd1 = (const float*)d_in[15];
    const float* bd1 = (const float*)d_in[16];
    const float* Wd2 = (const float*)d_in[17];
    const float* bd2 = (const float*)d_in[18];
    const float* Wd3 = (const float*)d_in[19];
    const float* bd3 = (const float*)d_in[20];
    float* out = (float*)d_out;

    char* w = (char*)d_ws;
    size_t pos = 0;
    auto carve = [&](size_t bytes) -> void* {
        void* p = w + pos;
        pos += (bytes + 255) & ~(size_t)255;
        return p;
    };
    int*   flag  = (int*)  carve(4);
    int*   es    = (int*)  carve(sizeof(int) * N_EDGES);
    int*   ed    = (int*)  carve(sizeof(int) * N_EDGES);
    float* dis   = (float*)carve(sizeof(float) * N_NODES);
    int*   cnt   = (int*)  carve(sizeof(int) * N_NODES);
    int*   offs  = (int*)  carve(sizeof(int) * (N_NODES + 1));
    int*   bsum  = (int*)  carve(sizeof(int) * 64);
    int*   bsoff = (int*)  carve(sizeof(int) * 64);
    int*   csr_s = (int*)  carve(sizeof(int) * N_EDGES);
    float* csr_c = (float*)carve(sizeof(float) * N_EDGES);
    unsigned short* Wg   = (unsigned short*)carve(2 * 768 * 256);
    unsigned short* W2T  = (unsigned short*)carve(2 * 256 * 256);
    unsigned short* Wd1T = (unsigned short*)carve(2 * 256 * 288);
    unsigned short* Wd2T = (unsigned short*)carve(2 * 128 * 256);
    float* agg0  = (float*)carve(sizeof(float) * (size_t)N_NODES * DIN);
    unsigned short* Abf = (unsigned short*)carve(2 * (size_t)N_NODES * H);  // h1 bf16
    unsigned short* Bbf = (unsigned short*)carve(2 * (size_t)N_NODES * H);  // agg(h1) bf16
    unsigned short* din = (unsigned short*)carve(2 * (size_t)N_NODES * 288); // [temporal, x] bf16
    // aliases over dead regions
    unsigned short* h2bf = Abf;   // after spmm consumed Abf
    unsigned short* d1bf = Bbf;   // after ln_mfma consumed Bbf
    (void)pos; (void)ws_size; (void)in_sizes; (void)n_in; (void)out_size;

    int gE = (N_EDGES + 255) / 256;
    int gN = (N_NODES + 255) / 256;
    int nscan = (N_NODES + 1023) / 1024;  // 49
    int nbm = (N_NODES + 63) / 64;        // 782 blocks for 16-row/wave MFMA kernels
    int nbg = (N_NODES + 127) / 128;      // 391 blocks for 32-row/wave GRU

    k_detect<<<1, 1, 0, stream>>>(ei, flag);
    k_init<<<gN, 256, 0, stream>>>(dis, cnt);
    k_convert<<<gE, 256, 0, stream>>>(ei, flag, es, ed, ew, dis, cnt);
    k_rsqrt<<<gN, 256, 0, stream>>>(dis);
    k_scan1<<<nscan, 256, 0, stream>>>(cnt, bsum);
    k_scan2<<<1, 64, 0, stream>>>(bsum, bsoff, offs, nscan);
    k_scan3<<<nscan, 256, 0, stream>>>(cnt, bsoff, offs, cnt);  // cnt reused as cursor
    k_fill<<<gE, 256, 0, stream>>>(es, ed, ew, dis, cnt, csr_s, csr_c);
    k_wihbf<<<(768 * 256 + 255) / 256, 256, 0, stream>>>(Wih, Wg);
    k_w2t<<<(256 * 256 + 255) / 256, 256, 0, stream>>>(W2, W2T);
    k_wd1t<<<(256 * 288 + 255) / 256, 256, 0, stream>>>(Wd1, Wd1T);
    k_wd2t<<<(256 * 128 + 255) / 256, 256, 0, stream>>>(Wd2, Wd2T);

    k_agg0<<<N_NODES / 16, 256, 0, stream>>>(x, offs, csr_s, csr_c, dis, agg0);
    k_gemm_ln<DIN, true><<<N_NODES / RPB, 256, 0, stream>>>(agg0, Abf, W1, b1, g1, be1);
    k_spmm<<<N_NODES / 4, 256, 0, stream>>>(Abf, Bbf, offs, csr_s, csr_c, dis);
    k_ln_mfma<<<nbm, 256, 0, stream>>>(Bbf, W2T, b2, g2, be2, h2bf);    // Abf dead -> h2bf
    k_xfill<<<(N_NODES * 32 + 255) / 256, 256, 0, stream>>>(x, din);
    k_gru_mfma<<<nbg, 256, 0, stream>>>(h2bf, Wg, bih, bhh, din);
    k_d1_mfma<<<nbm, 256, 0, stream>>>(din, Wd1T, bd1, d1bf);           // Bbf dead -> d1bf
    k_d23_mfma<<<nbm, 256, 0, stream>>>(d1bf, Wd2T, bd2, Wd3, bd3, out);
}

// Round 5
// 682.923 us; speedup vs baseline: 2.0580x; 1.0723x over previous
//
#include <hip/hip_runtime.h>
#include <math.h>

#define N_NODES 50000
#define N_EDGES 1600000
#define DIN 16
#define H 256
#define RPB 16
#define LN_EPS 1e-5f
#define FIXS 8388608.0f   // 2^23

typedef __attribute__((ext_vector_type(8))) unsigned short u16x8;
typedef __attribute__((ext_vector_type(8))) __bf16 bf16x8;
typedef __attribute__((ext_vector_type(4))) float f32x4;

__device__ inline unsigned short f2bf(float f) {
    unsigned u = __builtin_bit_cast(unsigned, f);
    return (unsigned short)((u + 0x7FFFu + ((u >> 16) & 1u)) >> 16);
}
__device__ inline float bf2f(unsigned short u) {
    return __builtin_bit_cast(float, ((unsigned)u) << 16);
}

// ---------------- edge dtype detect ----------------
__global__ void k_detect(const void* ei, int* flag) {
    const long long* p = (const long long*)ei;
    bool is64 = true;
    for (int i = 0; i < 8; ++i) {
        long long v = p[i];
        if (v < 0 || v >= N_NODES) is64 = false;
    }
    *flag = is64 ? 1 : 0;
}

// ---------------- init padded histogram ----------------
__global__ void k_init(unsigned long long* hist) {
    int i = blockIdx.x * blockDim.x + threadIdx.x;
    if (i < N_NODES) hist[(size_t)i * 8] = 0ULL;
}

// ---------------- histogram: one padded u64 atomic per edge ----------------
// bits [43:63] = count, bits [0:42] = sum(ew) in 23-bit fixed point
__global__ void k_hist(const void* ei, const int* flag, const float* ew,
                       unsigned long long* hist) {
    int e = blockIdx.x * blockDim.x + threadIdx.x;
    if (e >= N_EDGES) return;
    int d;
    if (*flag) d = (int)((const long long*)ei)[N_EDGES + e];
    else       d = ((const int*)ei)[N_EDGES + e];
    unsigned long long w = (unsigned long long)llrintf(ew[e] * FIXS);
    atomicAdd(&hist[(size_t)d * 8], (1ULL << 43) | w);
}

// ---------------- decode histogram -> dis, cnt ----------------
__global__ void k_decode(const unsigned long long* hist, float* dis, int* cnt) {
    int i = blockIdx.x * blockDim.x + threadIdx.x;
    if (i >= N_NODES) return;
    unsigned long long v = hist[(size_t)i * 8];
    int c = (int)(v >> 43);
    float wsum = (float)(v & ((1ULL << 43) - 1)) * (1.0f / FIXS);
    cnt[i] = c;
    dis[i] = rsqrtf(wsum + 2.0f);   // A_hat = A + 2I
}

// ---------------- xp = bf16(dis[i] * x[i]) ----------------
__global__ void k_xpb(const float* x, const float* dis, unsigned short* xpb) {
    int idx = blockIdx.x * blockDim.x + threadIdx.x;
    if (idx >= N_NODES * DIN) return;
    xpb[idx] = f2bf(dis[idx >> 4] * x[idx]);
}

// ---------------- exclusive scan of cnt -> offs (chunk 1024) ----------------
__global__ void k_scan1(const int* cnt, int* bsum) {
    __shared__ int ws_[4];
    int b = blockIdx.x, t = threadIdx.x;
    int s = 0;
    for (int k = 0; k < 4; ++k) {
        int idx = b * 1024 + k * 256 + t;
        if (idx < N_NODES) s += cnt[idx];
    }
    for (int d = 32; d; d >>= 1) s += __shfl_down(s, d, 64);
    if ((t & 63) == 0) ws_[t >> 6] = s;
    __syncthreads();
    if (t == 0) bsum[b] = ws_[0] + ws_[1] + ws_[2] + ws_[3];
}

__global__ void k_scan2(const int* bsum, int* bsoff, int* offs, int nblk) {
    if (threadIdx.x == 0) {
        int run = 0;
        for (int i = 0; i < nblk; ++i) { bsoff[i] = run; run += bsum[i]; }
        offs[N_NODES] = run;
    }
}

__global__ void k_scan3(const int* cnt, const int* bsoff, int* offs, int* cursor) {
    __shared__ int wsum[4];
    int b = blockIdx.x, t = threadIdx.x;
    int lane = t & 63, wv = t >> 6;
    int base = b * 1024 + t * 4;
    int v[4];
    for (int k = 0; k < 4; ++k) {
        int idx = base + k;
        v[k] = (idx < N_NODES) ? cnt[idx] : 0;
    }
    int ts = v[0] + v[1] + v[2] + v[3];
    int sc = ts;
    for (int d = 1; d < 64; d <<= 1) {
        int u = __shfl_up(sc, d, 64);
        if (lane >= d) sc += u;
    }
    if (lane == 63) wsum[wv] = sc;
    __syncthreads();
    int wpre = 0;
    for (int i = 0; i < wv; ++i) wpre += wsum[i];
    int ex = wpre + sc - ts + bsoff[b];
    for (int k = 0; k < 4; ++k) {
        int idx = base + k;
        if (idx < N_NODES) { offs[idx] = ex; cursor[(size_t)idx * 16] = ex; }
        ex += v[k];
    }
}

// ---------------- CSR fill: packed (ew || src) u64, padded cursor ----------------
__global__ void k_fill(const void* ei, const int* flag, const float* ew,
                       int* cursor, unsigned long long* csr) {
    int e = blockIdx.x * blockDim.x + threadIdx.x;
    if (e >= N_EDGES) return;
    int s, d;
    if (*flag) {
        const long long* p = (const long long*)ei;
        s = (int)p[e];
        d = (int)p[N_EDGES + e];
    } else {
        const int* p = (const int*)ei;
        s = p[e];
        d = p[N_EDGES + e];
    }
    int p = atomicAdd(&cursor[(size_t)d * 16], 1);
    csr[p] = ((unsigned long long)__builtin_bit_cast(unsigned, ew[e]) << 32) | (unsigned)s;
}

// ---------------- weight prep: fp32 -> bf16 (with transpose where needed) ----------------
__global__ void k_wihbf(const float* Wih, unsigned short* Wg) {
    int idx = blockIdx.x * blockDim.x + threadIdx.x;
    if (idx < 768 * 256) Wg[idx] = f2bf(Wih[idx]);   // already [out_col][k]
}

__global__ void k_w2t(const float* W2, unsigned short* W2T) {  // W2[k][n] -> W2T[n][k]
    int idx = blockIdx.x * blockDim.x + threadIdx.x;
    if (idx >= 256 * 256) return;
    int k = idx >> 8, n = idx & 255;
    W2T[n * 256 + k] = f2bf(W2[idx]);
}

__global__ void k_wd1t(const float* Wd1, unsigned short* T) {  // Wd1[272][256] -> T[n][288] (k padded)
    int idx = blockIdx.x * blockDim.x + threadIdx.x;
    if (idx >= 256 * 288) return;
    int n = idx / 288, k = idx % 288;
    T[idx] = (k < 272) ? f2bf(Wd1[k * 256 + n]) : (unsigned short)0;
}

__global__ void k_wd2t(const float* Wd2, unsigned short* T) {  // Wd2[256][128] -> T[n][256]
    int idx = blockIdx.x * blockDim.x + threadIdx.x;
    if (idx >= 256 * 128) return;
    int k = idx >> 7, n = idx & 127;
    T[n * 256 + k] = f2bf(Wd2[idx]);
}

// fill decoder-input x columns: din[row][256+j] = bf16(x[row][j]) (j<16), 0 pad to 288
__global__ void k_xfill(const float* x, unsigned short* din) {
    int idx = blockIdx.x * blockDim.x + threadIdx.x;
    if (idx >= N_NODES * 32) return;
    int row = idx >> 5, j = idx & 31;
    din[(long long)row * 288 + 256 + j] = (j < 16) ? f2bf(x[row * DIN + j]) : (unsigned short)0;
}

// ---------------- aggregation in DIN space (layer 1): agg = dis[r]*sum(ew*xp[s]) + 2*dis[r]*xp[r] ----------------
__global__ __launch_bounds__(256) void k_agg0(const unsigned short* __restrict__ xpb,
                                              const int* __restrict__ offs,
                                              const unsigned long long* __restrict__ csr,
                                              const float* __restrict__ dis, float* __restrict__ agg0) {
    int t = threadIdx.x;
    int r = blockIdx.x * 16 + (t >> 4);
    int dd = t & 15;
    float di = dis[r];
    float xself = bf2f(xpb[(long long)r * DIN + dd]);
    float acc = 0.0f;
    int e0 = offs[r], e1 = offs[r + 1];
    for (int e = e0; e < e1; e += 8) {
        unsigned long long vv[8];
#pragma unroll
        for (int j = 0; j < 8; ++j) {
            int idx = e + j;
            vv[j] = (idx < e1) ? csr[idx] : (unsigned long long)(unsigned)r;  // ew bits = 0
        }
        float xx[8];
#pragma unroll
        for (int j = 0; j < 8; ++j) {
            int s = (int)(unsigned)(vv[j] & 0xffffffffu);
            xx[j] = bf2f(xpb[(long long)s * DIN + dd]);
        }
#pragma unroll
        for (int j = 0; j < 8; ++j) {
            float c = __builtin_bit_cast(float, (unsigned)(vv[j] >> 32));
            acc = fmaf(c, xx[j], acc);
        }
    }
    agg0[(long long)r * DIN + dd] = di * acc + 2.0f * di * xself;
}

// ---------------- SpMM in H space: out = dis[d]*sum(ew*h1p[s]) + 2*dis[d]*h1p[d] ----------------
__global__ __launch_bounds__(256) void k_spmm(const unsigned short* __restrict__ hin,
                                              unsigned short* __restrict__ hout,
                                              const int* __restrict__ offs,
                                              const unsigned long long* __restrict__ csr,
                                              const float* __restrict__ dis) {
    int t = threadIdx.x;
    int wv = t >> 6, lane = t & 63;
    int row = blockIdx.x * 4 + wv;
    const ushort4* h4 = (const ushort4*)hin;
    float di = dis[row];
    ushort4 vs = h4[(long long)row * 64 + lane];
    float a0 = 0.f, a1 = 0.f, a2 = 0.f, a3 = 0.f;
    int e0 = offs[row], e1 = offs[row + 1];
    for (int e = e0; e < e1; e += 8) {
        unsigned long long vv[8];
#pragma unroll
        for (int j = 0; j < 8; ++j) {
            int idx = e + j;
            vv[j] = (idx < e1) ? csr[idx] : (unsigned long long)(unsigned)row;
        }
        ushort4 uu[8];
#pragma unroll
        for (int j = 0; j < 8; ++j) {
            int s = (int)(unsigned)(vv[j] & 0xffffffffu);
            uu[j] = h4[(long long)s * 64 + lane];
        }
#pragma unroll
        for (int j = 0; j < 8; ++j) {
            float c = __builtin_bit_cast(float, (unsigned)(vv[j] >> 32));
            a0 = fmaf(c, bf2f(uu[j].x), a0);
            a1 = fmaf(c, bf2f(uu[j].y), a1);
            a2 = fmaf(c, bf2f(uu[j].z), a2);
            a3 = fmaf(c, bf2f(uu[j].w), a3);
        }
    }
    ushort4 o;
    o.x = f2bf(di * a0 + 2.0f * di * bf2f(vs.x));
    o.y = f2bf(di * a1 + 2.0f * di * bf2f(vs.y));
    o.z = f2bf(di * a2 + 2.0f * di * bf2f(vs.z));
    o.w = f2bf(di * a3 + 2.0f * di * bf2f(vs.w));
    ((ushort4*)hout)[(long long)row * 64 + lane] = o;
}

// ---------------- layer-1 GEMM (16 -> 256) + bias + LN + relu, out scaled by dis (h1p) ----------------
template <int K, bool RELU>
__global__ __launch_bounds__(256) void k_gemm_ln(const float* in, unsigned short* out, const float* W,
                                                 const float* bias, const float* g, const float* be,
                                                 const float* dis) {
    __shared__ float s[RPB][H + 1];
    __shared__ float smu[RPB], srs[RPB];
    int t = threadIdx.x;
    long long rowbase = (long long)blockIdx.x * RPB;
    for (int idx = t; idx < RPB * K; idx += 256) {
        int r = idx / K, k = idx % K;
        s[r][k] = in[(rowbase + r) * K + k];
    }
    __syncthreads();
    float acc[RPB];
    float bb0 = bias[t];
#pragma unroll
    for (int r = 0; r < RPB; ++r) acc[r] = bb0;
    for (int k = 0; k < K; ++k) {
        float wv = W[k * H + t];
#pragma unroll
        for (int r = 0; r < RPB; ++r) acc[r] = fmaf(s[r][k], wv, acc[r]);
    }
    __syncthreads();
#pragma unroll
    for (int r = 0; r < RPB; ++r) s[r][t] = acc[r];
    __syncthreads();
    int lane = t & 63, wv2 = t >> 6;
    for (int rr = wv2; rr < RPB; rr += 4) {
        float v0 = s[rr][lane], v1 = s[rr][lane + 64], v2 = s[rr][lane + 128], v3 = s[rr][lane + 192];
        float sm = v0 + v1 + v2 + v3;
        float sq = v0 * v0 + v1 * v1 + v2 * v2 + v3 * v3;
        for (int d = 32; d; d >>= 1) {
            sm += __shfl_down(sm, d, 64);
            sq += __shfl_down(sq, d, 64);
        }
        if (lane == 0) {
            float mu = sm * (1.0f / H);
            float var = sq * (1.0f / H) - mu * mu;
            smu[rr] = mu;
            srs[rr] = rsqrtf(var + LN_EPS);
        }
    }
    __syncthreads();
    float gg = g[t], bb = be[t];
#pragma unroll
    for (int r = 0; r < RPB; ++r) {
        float h = (acc[r] - smu[r]) * srs[r] * gg + bb;
        if (RELU) h = fmaxf(h, 0.0f);
        out[(rowbase + r) * H + t] = f2bf(h * dis[rowbase + r]);
    }
}

// ---------------- MFMA row-GEMM kernels ----------------
// frag layout (16x16x32 bf16): A lane l: row l&15, k=8*(l>>4)+j ; B lane l: col l&15, same k ;
// D lane l: col l&15, row 4*(l>>4)+reg

// layer-2 GEMM + bias + LN, bf16 in -> bf16 out
__global__ __launch_bounds__(256) void k_ln_mfma(const unsigned short* __restrict__ in,
        const unsigned short* __restrict__ WT, const float* __restrict__ bias,
        const float* __restrict__ g, const float* __restrict__ be,
        unsigned short* __restrict__ outbf) {
    int t = threadIdx.x;
    int wv = t >> 6, l = t & 63;
    int lr = l & 15, lg = l >> 4;
    int rb = blockIdx.x * 64 + wv * 16;
    int arow = rb + lr; if (arow >= N_NODES) arow = N_NODES - 1;
    bf16x8 af[8];
    const unsigned short* ap = in + (long long)arow * H + lg * 8;
#pragma unroll
    for (int ks = 0; ks < 8; ++ks) af[ks] = __builtin_bit_cast(bf16x8, *(const u16x8*)(ap + ks * 32));
    f32x4 acc[16];
#pragma unroll
    for (int ct = 0; ct < 16; ++ct) acc[ct] = (f32x4){0.f, 0.f, 0.f, 0.f};
    for (int ct = 0; ct < 16; ++ct) {
        const unsigned short* wr = WT + (ct * 16 + lr) * H + lg * 8;
#pragma unroll
        for (int ks = 0; ks < 8; ++ks) {
            bf16x8 bfv = __builtin_bit_cast(bf16x8, *(const u16x8*)(wr + ks * 32));
            acc[ct] = __builtin_amdgcn_mfma_f32_16x16x32_bf16(af[ks], bfv, acc[ct], 0, 0, 0);
        }
    }
#pragma unroll
    for (int ct = 0; ct < 16; ++ct) {
        float bb = bias[ct * 16 + lr];
#pragma unroll
        for (int q = 0; q < 4; ++q) acc[ct][q] += bb;
    }
    float mean[4], rstd[4];
#pragma unroll
    for (int q = 0; q < 4; ++q) {
        float s = 0.f, s2 = 0.f;
#pragma unroll
        for (int ct = 0; ct < 16; ++ct) { float v = acc[ct][q]; s += v; s2 += v * v; }
#pragma unroll
        for (int m = 1; m < 16; m <<= 1) { s += __shfl_xor(s, m, 64); s2 += __shfl_xor(s2, m, 64); }
        float mu = s * (1.0f / H);
        mean[q] = mu;
        rstd[q] = rsqrtf(s2 * (1.0f / H) - mu * mu + LN_EPS);
    }
#pragma unroll
    for (int ct = 0; ct < 16; ++ct) {
        int col = ct * 16 + lr;
        float gg = g[col], bb = be[col];
#pragma unroll
        for (int q = 0; q < 4; ++q) {
            int row = rb + lg * 4 + q;
            if (row < N_NODES) {
                float nv = (acc[ct][q] - mean[q]) * rstd[q] * gg + bb;
                outbf[(long long)row * H + col] = f2bf(nv);
            }
        }
    }
}

// GRU step (h0=0): out = (1-z)*n, bf16 in -> bf16 din[.][0..255]; 32 rows/wave
__global__ __launch_bounds__(256) void k_gru_mfma(const unsigned short* __restrict__ h2,
        const unsigned short* __restrict__ Wg, const float* __restrict__ bih,
        const float* __restrict__ bhh, unsigned short* __restrict__ din) {
    int t = threadIdx.x;
    int wv = t >> 6, l = t & 63;
    int lr = l & 15, lg = l >> 4;
    int rb = blockIdx.x * 128 + wv * 32;
    int rA = rb + lr;      if (rA >= N_NODES) rA = N_NODES - 1;
    int rB = rb + 16 + lr; if (rB >= N_NODES) rB = N_NODES - 1;
    bf16x8 afA[8], afB[8];
    const unsigned short* apA = h2 + (long long)rA * H + lg * 8;
    const unsigned short* apB = h2 + (long long)rB * H + lg * 8;
#pragma unroll
    for (int ks = 0; ks < 8; ++ks) {
        afA[ks] = __builtin_bit_cast(bf16x8, *(const u16x8*)(apA + ks * 32));
        afB[ks] = __builtin_bit_cast(bf16x8, *(const u16x8*)(apB + ks * 32));
    }
    for (int ct = 0; ct < 16; ++ct) {
        f32x4 z4 = (f32x4){0.f, 0.f, 0.f, 0.f};
        f32x4 aRA = z4, aZA = z4, aNA = z4, aRB = z4, aZB = z4, aNB = z4;
        const unsigned short* w0 = Wg + (ct * 16 + lr) * H + lg * 8;
        const unsigned short* w1 = w0 + 256 * H;
        const unsigned short* w2 = w0 + 512 * H;
#pragma unroll
        for (int ks = 0; ks < 8; ++ks) {
            bf16x8 b0 = __builtin_bit_cast(bf16x8, *(const u16x8*)(w0 + ks * 32));
            bf16x8 b1 = __builtin_bit_cast(bf16x8, *(const u16x8*)(w1 + ks * 32));
            bf16x8 b2 = __builtin_bit_cast(bf16x8, *(const u16x8*)(w2 + ks * 32));
            aRA = __builtin_amdgcn_mfma_f32_16x16x32_bf16(afA[ks], b0, aRA, 0, 0, 0);
            aRB = __builtin_amdgcn_mfma_f32_16x16x32_bf16(afB[ks], b0, aRB, 0, 0, 0);
            aZA = __builtin_amdgcn_mfma_f32_16x16x32_bf16(afA[ks], b1, aZA, 0, 0, 0);
            aZB = __builtin_amdgcn_mfma_f32_16x16x32_bf16(afB[ks], b1, aZB, 0, 0, 0);
            aNA = __builtin_amdgcn_mfma_f32_16x16x32_bf16(afA[ks], b2, aNA, 0, 0, 0);
            aNB = __builtin_amdgcn_mfma_f32_16x16x32_bf16(afB[ks], b2, aNB, 0, 0, 0);
        }
        int col = ct * 16 + lr;
        float bR = bih[col] + bhh[col];
        float bZ = bih[col + 256] + bhh[col + 256];
        float bN = bih[col + 512];
        float hN = bhh[col + 512];
#pragma unroll
        for (int q = 0; q < 4; ++q) {
            {
                int row = rb + lg * 4 + q;
                float r = 1.0f / (1.0f + expf(-(aRA[q] + bR)));
                float z = 1.0f / (1.0f + expf(-(aZA[q] + bZ)));
                float n = tanhf(aNA[q] + bN + r * hN);
                if (row < N_NODES) din[(long long)row * 288 + col] = f2bf((1.0f - z) * n);
            }
            {
                int row = rb + 16 + lg * 4 + q;
                float r = 1.0f / (1.0f + expf(-(aRB[q] + bR)));
                float z = 1.0f / (1.0f + expf(-(aZB[q] + bZ)));
                float n = tanhf(aNB[q] + bN + r * hN);
                if (row < N_NODES) din[(long long)row * 288 + col] = f2bf((1.0f - z) * n);
            }
        }
    }
}

// decoder layer 1: relu(din @ Wd1T + bd1), K=288, bf16 -> bf16
__global__ __launch_bounds__(256) void k_d1_mfma(const unsigned short* __restrict__ din,
        const unsigned short* __restrict__ WT, const float* __restrict__ bias,
        unsigned short* __restrict__ outbf) {
    int t = threadIdx.x;
    int wv = t >> 6, l = t & 63;
    int lr = l & 15, lg = l >> 4;
    int rb = blockIdx.x * 64 + wv * 16;
    int arow = rb + lr; if (arow >= N_NODES) arow = N_NODES - 1;
    bf16x8 af[9];
    const unsigned short* ap = din + (long long)arow * 288 + lg * 8;
#pragma unroll
    for (int ks = 0; ks < 9; ++ks) af[ks] = __builtin_bit_cast(bf16x8, *(const u16x8*)(ap + ks * 32));
    f32x4 acc[16];
#pragma unroll
    for (int ct = 0; ct < 16; ++ct) acc[ct] = (f32x4){0.f, 0.f, 0.f, 0.f};
    for (int ct = 0; ct < 16; ++ct) {
        const unsigned short* wr = WT + (ct * 16 + lr) * 288 + lg * 8;
#pragma unroll
        for (int ks = 0; ks < 9; ++ks) {
            bf16x8 bfv = __builtin_bit_cast(bf16x8, *(const u16x8*)(wr + ks * 32));
            acc[ct] = __builtin_amdgcn_mfma_f32_16x16x32_bf16(af[ks], bfv, acc[ct], 0, 0, 0);
        }
    }
#pragma unroll
    for (int ct = 0; ct < 16; ++ct) {
        int col = ct * 16 + lr;
        float bb = bias[col];
#pragma unroll
        for (int q = 0; q < 4; ++q) {
            int row = rb + lg * 4 + q;
            if (row < N_NODES) {
                float v = fmaxf(acc[ct][q] + bb, 0.0f);
                outbf[(long long)row * H + col] = f2bf(v);
            }
        }
    }
}

// decoder layers 2+3: d2 = relu(d1 @ Wd2T + bd2) [N=128]; pred = clip(d2 @ Wd3 + bd3)
__global__ __launch_bounds__(256) void k_d23_mfma(const unsigned short* __restrict__ d1,
        const unsigned short* __restrict__ WT, const float* __restrict__ bd2,
        const float* __restrict__ Wd3, const float* __restrict__ bd3, float* __restrict__ out) {
    int t = threadIdx.x;
    int wv = t >> 6, l = t & 63;
    int lr = l & 15, lg = l >> 4;
    int rb = blockIdx.x * 64 + wv * 16;
    int arow = rb + lr; if (arow >= N_NODES) arow = N_NODES - 1;
    bf16x8 af[8];
    const unsigned short* ap = d1 + (long long)arow * H + lg * 8;
#pragma unroll
    for (int ks = 0; ks < 8; ++ks) af[ks] = __builtin_bit_cast(bf16x8, *(const u16x8*)(ap + ks * 32));
    f32x4 acc[8];
#pragma unroll
    for (int ct = 0; ct < 8; ++ct) acc[ct] = (f32x4){0.f, 0.f, 0.f, 0.f};
    for (int ct = 0; ct < 8; ++ct) {
        const unsigned short* wr = WT + (ct * 16 + lr) * H + lg * 8;
#pragma unroll
        for (int ks = 0; ks < 8; ++ks) {
            bf16x8 bfv = __builtin_bit_cast(bf16x8, *(const u16x8*)(wr + ks * 32));
            acc[ct] = __builtin_amdgcn_mfma_f32_16x16x32_bf16(af[ks], bfv, acc[ct], 0, 0, 0);
        }
    }
    float p0[4] = {0.f, 0.f, 0.f, 0.f}, p1[4] = {0.f, 0.f, 0.f, 0.f};
#pragma unroll
    for (int ct = 0; ct < 8; ++ct) {
        int col = ct * 16 + lr;
        float bb = bd2[col];
        float2 w3 = *(const float2*)(Wd3 + col * 2);
#pragma unroll
        for (int q = 0; q < 4; ++q) {
            float v = fmaxf(acc[ct][q] + bb, 0.0f);
            p0[q] = fmaf(v, w3.x, p0[q]);
            p1[q] = fmaf(v, w3.y, p1[q]);
        }
    }
#pragma unroll
    for (int q = 0; q < 4; ++q) {
#pragma unroll
        for (int m = 1; m < 16; m <<= 1) {
            p0[q] += __shfl_xor(p0[q], m, 64);
            p1[q] += __shfl_xor(p1[q], m, 64);
        }
    }
    if (lr == 0) {
#pragma unroll
        for (int q = 0; q < 4; ++q) {
            int row = rb + lg * 4 + q;
            if (row < N_NODES) {
                float a = fminf(fmaxf(p0[q] + bd3[0], -5.0f), 5.0f);
                float b = fminf(fmaxf(p1[q] + bd3[1], -5.0f), 5.0f);
                out[(long long)row * 2] = a;
                out[(long long)row * 2 + 1] = b;
            }
        }
    }
}

extern "C" void kernel_launch(void* const* d_in, const int* in_sizes, int n_in,
                              void* d_out, int out_size, void* d_ws, size_t ws_size,
                              hipStream_t stream) {
    const float* x   = (const float*)d_in[0];
    const void*  ei  = d_in[1];
    const float* ew  = (const float*)d_in[2];
    const float* W1  = (const float*)d_in[3];
    const float* b1  = (const float*)d_in[4];
    const float* g1  = (const float*)d_in[5];
    const float* be1 = (const float*)d_in[6];
    const float* W2  = (const float*)d_in[7];
    const float* b2  = (const float*)d_in[8];
    const float* g2  = (const float*)d_in[9];
    const float* be2 = (const float*)d_in[10];
    const float* Wih = (const float*)d_in[11];
    const float* bih = (const float*)d_in[13];
    const float* bhh = (const float*)d_in[14];
    const float* Wd1 = (const float*)d_in[15];
    const float* bd1 = (const float*)d_in[16];
    const float* Wd2 = (const float*)d_in[17];
    const float* bd2 = (const float*)d_in[18];
    const float* Wd3 = (const float*)d_in[19];
    const float* bd3 = (const float*)d_in[20];
    float* out = (float*)d_out;

    char* w = (char*)d_ws;
    size_t pos = 0;
    auto carve = [&](size_t bytes) -> void* {
        void* p = w + pos;
        pos += (bytes + 255) & ~(size_t)255;
        return p;
    };
    int*   flag  = (int*)  carve(4);
    unsigned long long* hist = (unsigned long long*)carve(8 * 8 * (size_t)N_NODES);  // 64B-padded
    int*   cursor= (int*)  carve(sizeof(int) * 16 * (size_t)N_NODES);                // 64B-padded
    float* dis   = (float*)carve(sizeof(float) * N_NODES);
    int*   cnt   = (int*)  carve(sizeof(int) * N_NODES);
    int*   offs  = (int*)  carve(sizeof(int) * (N_NODES + 1));
    int*   bsum  = (int*)  carve(sizeof(int) * 64);
    int*   bsoff = (int*)  carve(sizeof(int) * 64);
    unsigned long long* csr = (unsigned long long*)carve(8 * (size_t)N_EDGES);
    unsigned short* xpb  = (unsigned short*)carve(2 * (size_t)N_NODES * DIN);
    unsigned short* Wg   = (unsigned short*)carve(2 * 768 * 256);
    unsigned short* W2T  = (unsigned short*)carve(2 * 256 * 256);
    unsigned short* Wd1T = (unsigned short*)carve(2 * 256 * 288);
    unsigned short* Wd2T = (unsigned short*)carve(2 * 128 * 256);
    float* agg0  = (float*)carve(sizeof(float) * (size_t)N_NODES * DIN);
    unsigned short* Abf = (unsigned short*)carve(2 * (size_t)N_NODES * H);  // h1p bf16
    unsigned short* Bbf = (unsigned short*)carve(2 * (size_t)N_NODES * H);  // agg2 bf16
    unsigned short* din = (unsigned short*)carve(2 * (size_t)N_NODES * 288); // [temporal, x] bf16
    // aliases over dead regions
    unsigned short* h2bf = Abf;   // after spmm consumed Abf
    unsigned short* d1bf = Bbf;   // after ln_mfma consumed Bbf
    (void)pos; (void)ws_size; (void)in_sizes; (void)n_in; (void)out_size;

    int gE = (N_EDGES + 255) / 256;
    int gN = (N_NODES + 255) / 256;
    int nscan = (N_NODES + 1023) / 1024;  // 49
    int nbm = (N_NODES + 63) / 64;        // 782 blocks for 16-row/wave MFMA kernels
    int nbg = (N_NODES + 127) / 128;      // 391 blocks for 32-row/wave GRU

    k_detect<<<1, 1, 0, stream>>>(ei, flag);
    k_init<<<gN, 256, 0, stream>>>(hist);
    k_hist<<<gE, 256, 0, stream>>>(ei, flag, ew, hist);
    k_decode<<<gN, 256, 0, stream>>>(hist, dis, cnt);
    k_xpb<<<(N_NODES * DIN + 255) / 256, 256, 0, stream>>>(x, dis, xpb);
    k_scan1<<<nscan, 256, 0, stream>>>(cnt, bsum);
    k_scan2<<<1, 64, 0, stream>>>(bsum, bsoff, offs, nscan);
    k_scan3<<<nscan, 256, 0, stream>>>(cnt, bsoff, offs, cursor);
    k_fill<<<gE, 256, 0, stream>>>(ei, flag, ew, cursor, csr);
    k_wihbf<<<(768 * 256 + 255) / 256, 256, 0, stream>>>(Wih, Wg);
    k_w2t<<<(256 * 256 + 255) / 256, 256, 0, stream>>>(W2, W2T);
    k_wd1t<<<(256 * 288 + 255) / 256, 256, 0, stream>>>(Wd1, Wd1T);
    k_wd2t<<<(256 * 128 + 255) / 256, 256, 0, stream>>>(Wd2, Wd2T);

    k_agg0<<<N_NODES / 16, 256, 0, stream>>>(xpb, offs, csr, dis, agg0);
    k_gemm_ln<DIN, true><<<N_NODES / RPB, 256, 0, stream>>>(agg0, Abf, W1, b1, g1, be1, dis);
    k_spmm<<<N_NODES / 4, 256, 0, stream>>>(Abf, Bbf, offs, csr, dis);
    k_ln_mfma<<<nbm, 256, 0, stream>>>(Bbf, W2T, b2, g2, be2, h2bf);    // Abf dead -> h2bf
    k_xfill<<<(N_NODES * 32 + 255) / 256, 256, 0, stream>>>(x, din);
    k_gru_mfma<<<nbg, 256, 0, stream>>>(h2bf, Wg, bih, bhh, din);
    k_d1_mfma<<<nbm, 256, 0, stream>>>(din, Wd1T, bd1, d1bf);           // Bbf dead -> d1bf
    k_d23_mfma<<<nbm, 256, 0, stream>>>(d1bf, Wd2T, bd2, Wd3, bd3, out);
}

// Round 6
// 542.570 us; speedup vs baseline: 2.5904x; 1.2587x over previous
//
#include <hip/hip_runtime.h>
#include <math.h>

#define N_NODES 50000
#define N_EDGES 1600000
#define DIN 16
#define H 256
#define RPB 16
#define LN_EPS 1e-5f
#define FIXS 8388608.0f   // 2^23
#define NB 391            // buckets of 128 dst nodes
#define TILEA 4096
#define NTILES 391        // ceil(1.6M / 4096)

typedef __attribute__((ext_vector_type(8))) unsigned short u16x8;
typedef __attribute__((ext_vector_type(8))) __bf16 bf16x8;
typedef __attribute__((ext_vector_type(4))) float f32x4;

__device__ inline unsigned short f2bf(float f) {
    unsigned u = __builtin_bit_cast(unsigned, f);
    return (unsigned short)((u + 0x7FFFu + ((u >> 16) & 1u)) >> 16);
}
__device__ inline float bf2f(unsigned short u) {
    return __builtin_bit_cast(float, ((unsigned)u) << 16);
}

// ---------------- edge dtype detect ----------------
__global__ void k_detect(const void* ei, int* flag) {
    const long long* p = (const long long*)ei;
    bool is64 = true;
    for (int i = 0; i < 8; ++i) {
        long long v = p[i];
        if (v < 0 || v >= N_NODES) is64 = false;
    }
    *flag = is64 ? 1 : 0;
}

__global__ void k_zeroi(int* p, int n) {
    int i = blockIdx.x * blockDim.x + threadIdx.x;
    if (i < n) p[i] = 0;
}

// ---------------- bucket counts (LDS-aggregated) ----------------
__global__ __launch_bounds__(256) void k_bucketcnt(const void* ei, const int* flag, int* bsize) {
    __shared__ int bh[512];
    int t = threadIdx.x;
    long long base = (long long)blockIdx.x * TILEA;
    for (int i = t; i < 512; i += 256) bh[i] = 0;
    __syncthreads();
    bool f64 = (*flag != 0);
#pragma unroll
    for (int k = 0; k < TILEA / 256; ++k) {
        long long e = base + k * 256 + t;
        if (e < N_EDGES) {
            int d = f64 ? (int)((const long long*)ei)[N_EDGES + e] : ((const int*)ei)[N_EDGES + e];
            atomicAdd(&bh[d >> 7], 1);
        }
    }
    __syncthreads();
    for (int i = t; i < 512; i += 256)
        if (bh[i]) atomicAdd(&bsize[i], bh[i]);
}

// ---------------- scan bucket sizes -> bstart, bcursor (single block) ----------------
__global__ __launch_bounds__(256) void k_bscan(const int* bsize, int* bstart, int* bcursor) {
    __shared__ int bh[512], bscn[512];
    __shared__ int ws4[4];
    int t = threadIdx.x;
    bh[2 * t]     = (2 * t < NB)     ? bsize[2 * t]     : 0;
    bh[2 * t + 1] = (2 * t + 1 < NB) ? bsize[2 * t + 1] : 0;
    __syncthreads();
    int a0 = bh[2 * t], a1 = bh[2 * t + 1];
    int s = a0 + a1;
    int lane = t & 63, wv = t >> 6;
    int sc = s;
    for (int d = 1; d < 64; d <<= 1) { int u = __shfl_up(sc, d, 64); if (lane >= d) sc += u; }
    if (lane == 63) ws4[wv] = sc;
    __syncthreads();
    int wpre = 0;
    for (int i = 0; i < wv; ++i) wpre += ws4[i];
    int excl = wpre + sc - s;
    bscn[2 * t] = excl;
    bscn[2 * t + 1] = excl + a0;
    __syncthreads();
    for (int i = t; i < NB; i += 256) { bstart[i] = bscn[i]; bcursor[i] = bscn[i]; }
    if (t == 0) bstart[NB] = N_EDGES;
}

// ---------------- phase A: multisplit edges into bucket-contiguous staging ----------------
// packed u64 = ew(32) << 32 | dstlow7 << 16 | src(16)
__global__ __launch_bounds__(256) void k_msplit(const void* ei, const int* flag, const float* ew,
                                                int* bcursor, unsigned long long* stage) {
    __shared__ int bh[512], bscn[512], cur[512], gbase[512];
    __shared__ int ws4[4];
    __shared__ unsigned long long sdata[TILEA];
    __shared__ unsigned short sbkt[TILEA];
    int t = threadIdx.x;
    long long base = (long long)blockIdx.x * TILEA;
    int nhere = (int)(((long long)N_EDGES - base) < TILEA ? (N_EDGES - base) : TILEA);
    for (int i = t; i < 512; i += 256) bh[i] = 0;
    __syncthreads();
    bool f64 = (*flag != 0);
    unsigned long long vreg[TILEA / 256];
    int breg[TILEA / 256];
#pragma unroll
    for (int k = 0; k < TILEA / 256; ++k) {
        long long e = base + k * 256 + t;
        if (e < N_EDGES) {
            int s, d;
            if (f64) {
                const long long* p = (const long long*)ei;
                s = (int)p[e]; d = (int)p[N_EDGES + e];
            } else {
                const int* p = (const int*)ei;
                s = p[e]; d = p[N_EDGES + e];
            }
            unsigned wbits = __builtin_bit_cast(unsigned, ew[e]);
            vreg[k] = ((unsigned long long)wbits << 32) |
                      ((unsigned long long)(d & 127) << 16) | (unsigned)(s & 0xFFFF);
            breg[k] = d >> 7;
            atomicAdd(&bh[breg[k]], 1);
        } else breg[k] = -1;
    }
    __syncthreads();
    // block exclusive scan over 512 entries
    int a0 = bh[2 * t], a1 = bh[2 * t + 1];
    int s = a0 + a1;
    int lane = t & 63, wv = t >> 6;
    int sc = s;
    for (int d = 1; d < 64; d <<= 1) { int u = __shfl_up(sc, d, 64); if (lane >= d) sc += u; }
    if (lane == 63) ws4[wv] = sc;
    __syncthreads();
    int wpre = 0;
    for (int i = 0; i < wv; ++i) wpre += ws4[i];
    int excl = wpre + sc - s;
    bscn[2 * t] = excl;      cur[2 * t] = excl;
    bscn[2 * t + 1] = excl + a0; cur[2 * t + 1] = excl + a0;
    __syncthreads();
    // reserve global space per bucket
    for (int i = t; i < NB; i += 256) {
        int c = bh[i];
        if (c) gbase[i] = atomicAdd(&bcursor[i], c);
    }
    __syncthreads();
    // local scatter into LDS (grouped by bucket)
#pragma unroll
    for (int k = 0; k < TILEA / 256; ++k) {
        if (breg[k] >= 0) {
            int p = atomicAdd(&cur[breg[k]], 1);
            sdata[p] = vreg[k];
            sbkt[p] = (unsigned short)breg[k];
        }
    }
    __syncthreads();
    // coalesced-ish writeout: consecutive LDS slots of same bucket -> consecutive global
    for (int i = t; i < nhere; i += 256) {
        int b = sbkt[i];
        stage[(long long)gbase[b] + (i - bscn[b])] = sdata[i];
    }
}

// ---------------- phase B1: per-bucket degree/count (no global atomics) ----------------
__global__ __launch_bounds__(256) void k_bstat(const unsigned long long* __restrict__ stage,
                                               const int* __restrict__ bstart,
                                               int* __restrict__ cnt, float* __restrict__ dis) {
    __shared__ unsigned long long acc[128];
    int b = blockIdx.x, t = threadIdx.x;
    if (t < 128) acc[t] = 0ULL;
    __syncthreads();
    int e0 = bstart[b], e1 = bstart[b + 1];
    for (int i = e0 + t; i < e1; i += 256) {
        unsigned long long v = stage[i];
        int nl = (int)((v >> 16) & 127);
        float w = __builtin_bit_cast(float, (unsigned)(v >> 32));
        atomicAdd(&acc[nl], (1ULL << 43) | (unsigned long long)llrintf(w * FIXS));
    }
    __syncthreads();
    if (t < 128) {
        int node = (b << 7) + t;
        if (node < N_NODES) {
            unsigned long long v = acc[t];
            cnt[node] = (int)(v >> 43);
            dis[node] = rsqrtf((float)(v & ((1ULL << 43) - 1)) * (1.0f / FIXS) + 2.0f);
        }
    }
}

// ---------------- phase B2: fine placement within bucket (L2-local scatter) ----------------
__global__ __launch_bounds__(256) void k_fine(const unsigned long long* __restrict__ stage,
                                              const int* __restrict__ bstart,
                                              const int* __restrict__ offs,
                                              unsigned long long* __restrict__ csr) {
    __shared__ int cur[128];
    int b = blockIdx.x, t = threadIdx.x;
    int e0 = bstart[b], e1 = bstart[b + 1];
    if (t < 128) {
        int node = (b << 7) + t;
        cur[t] = (node < N_NODES) ? (offs[node] - e0) : 0;
    }
    __syncthreads();
    for (int i = e0 + t; i < e1; i += 256) {
        unsigned long long v = stage[i];
        int nl = (int)((v >> 16) & 127);
        int p = atomicAdd(&cur[nl], 1);
        csr[(long long)e0 + p] = v;
    }
}

// ---------------- xp = bf16(dis[i] * x[i]) ----------------
__global__ void k_xpb(const float* x, const float* dis, unsigned short* xpb) {
    int idx = blockIdx.x * blockDim.x + threadIdx.x;
    if (idx >= N_NODES * DIN) return;
    xpb[idx] = f2bf(dis[idx >> 4] * x[idx]);
}

// ---------------- exclusive scan of cnt -> offs (chunk 1024) ----------------
__global__ void k_scan1(const int* cnt, int* bsum) {
    __shared__ int ws_[4];
    int b = blockIdx.x, t = threadIdx.x;
    int s = 0;
    for (int k = 0; k < 4; ++k) {
        int idx = b * 1024 + k * 256 + t;
        if (idx < N_NODES) s += cnt[idx];
    }
    for (int d = 32; d; d >>= 1) s += __shfl_down(s, d, 64);
    if ((t & 63) == 0) ws_[t >> 6] = s;
    __syncthreads();
    if (t == 0) bsum[b] = ws_[0] + ws_[1] + ws_[2] + ws_[3];
}

__global__ void k_scan2(const int* bsum, int* bsoff, int* offs, int nblk) {
    if (threadIdx.x == 0) {
        int run = 0;
        for (int i = 0; i < nblk; ++i) { bsoff[i] = run; run += bsum[i]; }
        offs[N_NODES] = run;
    }
}

__global__ void k_scan3(const int* cnt, const int* bsoff, int* offs) {
    __shared__ int wsum[4];
    int b = blockIdx.x, t = threadIdx.x;
    int lane = t & 63, wv = t >> 6;
    int base = b * 1024 + t * 4;
    int v[4];
    for (int k = 0; k < 4; ++k) {
        int idx = base + k;
        v[k] = (idx < N_NODES) ? cnt[idx] : 0;
    }
    int ts = v[0] + v[1] + v[2] + v[3];
    int sc = ts;
    for (int d = 1; d < 64; d <<= 1) {
        int u = __shfl_up(sc, d, 64);
        if (lane >= d) sc += u;
    }
    if (lane == 63) wsum[wv] = sc;
    __syncthreads();
    int wpre = 0;
    for (int i = 0; i < wv; ++i) wpre += wsum[i];
    int ex = wpre + sc - ts + bsoff[b];
    for (int k = 0; k < 4; ++k) {
        int idx = base + k;
        if (idx < N_NODES) offs[idx] = ex;
        ex += v[k];
    }
}

// ---------------- weight prep: fp32 -> bf16 (with transpose where needed) ----------------
__global__ void k_wihbf(const float* Wih, unsigned short* Wg) {
    int idx = blockIdx.x * blockDim.x + threadIdx.x;
    if (idx < 768 * 256) Wg[idx] = f2bf(Wih[idx]);   // already [out_col][k]
}

__global__ void k_w2t(const float* W2, unsigned short* W2T) {  // W2[k][n] -> W2T[n][k]
    int idx = blockIdx.x * blockDim.x + threadIdx.x;
    if (idx >= 256 * 256) return;
    int k = idx >> 8, n = idx & 255;
    W2T[n * 256 + k] = f2bf(W2[idx]);
}

__global__ void k_wd1t(const float* Wd1, unsigned short* T) {  // Wd1[272][256] -> T[n][288] (k padded)
    int idx = blockIdx.x * blockDim.x + threadIdx.x;
    if (idx >= 256 * 288) return;
    int n = idx / 288, k = idx % 288;
    T[idx] = (k < 272) ? f2bf(Wd1[k * 256 + n]) : (unsigned short)0;
}

__global__ void k_wd2t(const float* Wd2, unsigned short* T) {  // Wd2[256][128] -> T[n][256]
    int idx = blockIdx.x * blockDim.x + threadIdx.x;
    if (idx >= 256 * 128) return;
    int k = idx >> 7, n = idx & 127;
    T[n * 256 + k] = f2bf(Wd2[idx]);
}

// fill decoder-input x columns: din[row][256+j] = bf16(x[row][j]) (j<16), 0 pad to 288
__global__ void k_xfill(const float* x, unsigned short* din) {
    int idx = blockIdx.x * blockDim.x + threadIdx.x;
    if (idx >= N_NODES * 32) return;
    int row = idx >> 5, j = idx & 31;
    din[(long long)row * 288 + 256 + j] = (j < 16) ? f2bf(x[row * DIN + j]) : (unsigned short)0;
}

// ---------------- aggregation in DIN space (layer 1): agg = dis[r]*sum(ew*xp[s]) + 2*dis[r]*xp[r] ----------------
__global__ __launch_bounds__(256) void k_agg0(const unsigned short* __restrict__ xpb,
                                              const int* __restrict__ offs,
                                              const unsigned long long* __restrict__ csr,
                                              const float* __restrict__ dis, float* __restrict__ agg0) {
    int t = threadIdx.x;
    int r = blockIdx.x * 16 + (t >> 4);
    int dd = t & 15;
    float di = dis[r];
    float xself = bf2f(xpb[(long long)r * DIN + dd]);
    float acc = 0.0f;
    int e0 = offs[r], e1 = offs[r + 1];
    for (int e = e0; e < e1; e += 8) {
        unsigned long long vv[8];
#pragma unroll
        for (int j = 0; j < 8; ++j) {
            int idx = e + j;
            vv[j] = (idx < e1) ? csr[idx] : (unsigned long long)(unsigned)r;  // ew bits = 0
        }
        float xx[8];
#pragma unroll
        for (int j = 0; j < 8; ++j) {
            int s = (int)(vv[j] & 0xFFFFu);
            xx[j] = bf2f(xpb[(long long)s * DIN + dd]);
        }
#pragma unroll
        for (int j = 0; j < 8; ++j) {
            float c = __builtin_bit_cast(float, (unsigned)(vv[j] >> 32));
            acc = fmaf(c, xx[j], acc);
        }
    }
    agg0[(long long)r * DIN + dd] = di * acc + 2.0f * di * xself;
}

// ---------------- SpMM in H space: out = dis[d]*sum(ew*h1p[s]) + 2*dis[d]*h1p[d] ----------------
__global__ __launch_bounds__(256) void k_spmm(const unsigned short* __restrict__ hin,
                                              unsigned short* __restrict__ hout,
                                              const int* __restrict__ offs,
                                              const unsigned long long* __restrict__ csr,
                                              const float* __restrict__ dis) {
    int t = threadIdx.x;
    int wv = t >> 6, lane = t & 63;
    int row = blockIdx.x * 4 + wv;
    const ushort4* h4 = (const ushort4*)hin;
    float di = dis[row];
    ushort4 vs = h4[(long long)row * 64 + lane];
    float a0 = 0.f, a1 = 0.f, a2 = 0.f, a3 = 0.f;
    int e0 = offs[row], e1 = offs[row + 1];
    for (int e = e0; e < e1; e += 8) {
        unsigned long long vv[8];
#pragma unroll
        for (int j = 0; j < 8; ++j) {
            int idx = e + j;
            vv[j] = (idx < e1) ? csr[idx] : (unsigned long long)(unsigned)row;
        }
        ushort4 uu[8];
#pragma unroll
        for (int j = 0; j < 8; ++j) {
            int s = (int)(vv[j] & 0xFFFFu);
            uu[j] = h4[(long long)s * 64 + lane];
        }
#pragma unroll
        for (int j = 0; j < 8; ++j) {
            float c = __builtin_bit_cast(float, (unsigned)(vv[j] >> 32));
            a0 = fmaf(c, bf2f(uu[j].x), a0);
            a1 = fmaf(c, bf2f(uu[j].y), a1);
            a2 = fmaf(c, bf2f(uu[j].z), a2);
            a3 = fmaf(c, bf2f(uu[j].w), a3);
        }
    }
    ushort4 o;
    o.x = f2bf(di * a0 + 2.0f * di * bf2f(vs.x));
    o.y = f2bf(di * a1 + 2.0f * di * bf2f(vs.y));
    o.z = f2bf(di * a2 + 2.0f * di * bf2f(vs.z));
    o.w = f2bf(di * a3 + 2.0f * di * bf2f(vs.w));
    ((ushort4*)hout)[(long long)row * 64 + lane] = o;
}

// ---------------- layer-1 GEMM (16 -> 256) + bias + LN + relu, out scaled by dis (h1p) ----------------
template <int K, bool RELU>
__global__ __launch_bounds__(256) void k_gemm_ln(const float* in, unsigned short* out, const float* W,
                                                 const float* bias, const float* g, const float* be,
                                                 const float* dis) {
    __shared__ float s[RPB][H + 1];
    __shared__ float smu[RPB], srs[RPB];
    int t = threadIdx.x;
    long long rowbase = (long long)blockIdx.x * RPB;
    for (int idx = t; idx < RPB * K; idx += 256) {
        int r = idx / K, k = idx % K;
        s[r][k] = in[(rowbase + r) * K + k];
    }
    __syncthreads();
    float acc[RPB];
    float bb0 = bias[t];
#pragma unroll
    for (int r = 0; r < RPB; ++r) acc[r] = bb0;
    for (int k = 0; k < K; ++k) {
        float wv = W[k * H + t];
#pragma unroll
        for (int r = 0; r < RPB; ++r) acc[r] = fmaf(s[r][k], wv, acc[r]);
    }
    __syncthreads();
#pragma unroll
    for (int r = 0; r < RPB; ++r) s[r][t] = acc[r];
    __syncthreads();
    int lane = t & 63, wv2 = t >> 6;
    for (int rr = wv2; rr < RPB; rr += 4) {
        float v0 = s[rr][lane], v1 = s[rr][lane + 64], v2 = s[rr][lane + 128], v3 = s[rr][lane + 192];
        float sm = v0 + v1 + v2 + v3;
        float sq = v0 * v0 + v1 * v1 + v2 * v2 + v3 * v3;
        for (int d = 32; d; d >>= 1) {
            sm += __shfl_down(sm, d, 64);
            sq += __shfl_down(sq, d, 64);
        }
        if (lane == 0) {
            float mu = sm * (1.0f / H);
            float var = sq * (1.0f / H) - mu * mu;
            smu[rr] = mu;
            srs[rr] = rsqrtf(var + LN_EPS);
        }
    }
    __syncthreads();
    float gg = g[t], bb = be[t];
#pragma unroll
    for (int r = 0; r < RPB; ++r) {
        float h = (acc[r] - smu[r]) * srs[r] * gg + bb;
        if (RELU) h = fmaxf(h, 0.0f);
        out[(rowbase + r) * H + t] = f2bf(h * dis[rowbase + r]);
    }
}

// ---------------- MFMA row-GEMM kernels ----------------
// frag layout (16x16x32 bf16): A lane l: row l&15, k=8*(l>>4)+j ; B lane l: col l&15, same k ;
// D lane l: col l&15, row 4*(l>>4)+reg

// layer-2 GEMM + bias + LN, bf16 in -> bf16 out
__global__ __launch_bounds__(256) void k_ln_mfma(const unsigned short* __restrict__ in,
        const unsigned short* __restrict__ WT, const float* __restrict__ bias,
        const float* __restrict__ g, const float* __restrict__ be,
        unsigned short* __restrict__ outbf) {
    int t = threadIdx.x;
    int wv = t >> 6, l = t & 63;
    int lr = l & 15, lg = l >> 4;
    int rb = blockIdx.x * 64 + wv * 16;
    int arow = rb + lr; if (arow >= N_NODES) arow = N_NODES - 1;
    bf16x8 af[8];
    const unsigned short* ap = in + (long long)arow * H + lg * 8;
#pragma unroll
    for (int ks = 0; ks < 8; ++ks) af[ks] = __builtin_bit_cast(bf16x8, *(const u16x8*)(ap + ks * 32));
    f32x4 acc[16];
#pragma unroll
    for (int ct = 0; ct < 16; ++ct) acc[ct] = (f32x4){0.f, 0.f, 0.f, 0.f};
    for (int ct = 0; ct < 16; ++ct) {
        const unsigned short* wr = WT + (ct * 16 + lr) * H + lg * 8;
#pragma unroll
        for (int ks = 0; ks < 8; ++ks) {
            bf16x8 bfv = __builtin_bit_cast(bf16x8, *(const u16x8*)(wr + ks * 32));
            acc[ct] = __builtin_amdgcn_mfma_f32_16x16x32_bf16(af[ks], bfv, acc[ct], 0, 0, 0);
        }
    }
#pragma unroll
    for (int ct = 0; ct < 16; ++ct) {
        float bb = bias[ct * 16 + lr];
#pragma unroll
        for (int q = 0; q < 4; ++q) acc[ct][q] += bb;
    }
    float mean[4], rstd[4];
#pragma unroll
    for (int q = 0; q < 4; ++q) {
        float s = 0.f, s2 = 0.f;
#pragma unroll
        for (int ct = 0; ct < 16; ++ct) { float v = acc[ct][q]; s += v; s2 += v * v; }
#pragma unroll
        for (int m = 1; m < 16; m <<= 1) { s += __shfl_xor(s, m, 64); s2 += __shfl_xor(s2, m, 64); }
        float mu = s * (1.0f / H);
        mean[q] = mu;
        rstd[q] = rsqrtf(s2 * (1.0f / H) - mu * mu + LN_EPS);
    }
#pragma unroll
    for (int ct = 0; ct < 16; ++ct) {
        int col = ct * 16 + lr;
        float gg = g[col], bb = be[col];
#pragma unroll
        for (int q = 0; q < 4; ++q) {
            int row = rb + lg * 4 + q;
            if (row < N_NODES) {
                float nv = (acc[ct][q] - mean[q]) * rstd[q] * gg + bb;
                outbf[(long long)row * H + col] = f2bf(nv);
            }
        }
    }
}

// GRU step (h0=0): out = (1-z)*n, bf16 in -> bf16 din[.][0..255]; 32 rows/wave
__global__ __launch_bounds__(256) void k_gru_mfma(const unsigned short* __restrict__ h2,
        const unsigned short* __restrict__ Wg, const float* __restrict__ bih,
        const float* __restrict__ bhh, unsigned short* __restrict__ din) {
    int t = threadIdx.x;
    int wv = t >> 6, l = t & 63;
    int lr = l & 15, lg = l >> 4;
    int rb = blockIdx.x * 128 + wv * 32;
    int rA = rb + lr;      if (rA >= N_NODES) rA = N_NODES - 1;
    int rB = rb + 16 + lr; if (rB >= N_NODES) rB = N_NODES - 1;
    bf16x8 afA[8], afB[8];
    const unsigned short* apA = h2 + (long long)rA * H + lg * 8;
    const unsigned short* apB = h2 + (long long)rB * H + lg * 8;
#pragma unroll
    for (int ks = 0; ks < 8; ++ks) {
        afA[ks] = __builtin_bit_cast(bf16x8, *(const u16x8*)(apA + ks * 32));
        afB[ks] = __builtin_bit_cast(bf16x8, *(const u16x8*)(apB + ks * 32));
    }
    for (int ct = 0; ct < 16; ++ct) {
        f32x4 z4 = (f32x4){0.f, 0.f, 0.f, 0.f};
        f32x4 aRA = z4, aZA = z4, aNA = z4, aRB = z4, aZB = z4, aNB = z4;
        const unsigned short* w0 = Wg + (ct * 16 + lr) * H + lg * 8;
        const unsigned short* w1 = w0 + 256 * H;
        const unsigned short* w2 = w0 + 512 * H;
#pragma unroll
        for (int ks = 0; ks < 8; ++ks) {
            bf16x8 b0 = __builtin_bit_cast(bf16x8, *(const u16x8*)(w0 + ks * 32));
            bf16x8 b1 = __builtin_bit_cast(bf16x8, *(const u16x8*)(w1 + ks * 32));
            bf16x8 b2 = __builtin_bit_cast(bf16x8, *(const u16x8*)(w2 + ks * 32));
            aRA = __builtin_amdgcn_mfma_f32_16x16x32_bf16(afA[ks], b0, aRA, 0, 0, 0);
            aRB = __builtin_amdgcn_mfma_f32_16x16x32_bf16(afB[ks], b0, aRB, 0, 0, 0);
            aZA = __builtin_amdgcn_mfma_f32_16x16x32_bf16(afA[ks], b1, aZA, 0, 0, 0);
            aZB = __builtin_amdgcn_mfma_f32_16x16x32_bf16(afB[ks], b1, aZB, 0, 0, 0);
            aNA = __builtin_amdgcn_mfma_f32_16x16x32_bf16(afA[ks], b2, aNA, 0, 0, 0);
            aNB = __builtin_amdgcn_mfma_f32_16x16x32_bf16(afB[ks], b2, aNB, 0, 0, 0);
        }
        int col = ct * 16 + lr;
        float bR = bih[col] + bhh[col];
        float bZ = bih[col + 256] + bhh[col + 256];
        float bN = bih[col + 512];
        float hN = bhh[col + 512];
#pragma unroll
        for (int q = 0; q < 4; ++q) {
            {
                int row = rb + lg * 4 + q;
                float r = 1.0f / (1.0f + expf(-(aRA[q] + bR)));
                float z = 1.0f / (1.0f + expf(-(aZA[q] + bZ)));
                float n = tanhf(aNA[q] + bN + r * hN);
                if (row < N_NODES) din[(long long)row * 288 + col] = f2bf((1.0f - z) * n);
            }
            {
                int row = rb + 16 + lg * 4 + q;
                float r = 1.0f / (1.0f + expf(-(aRB[q] + bR)));
                float z = 1.0f / (1.0f + expf(-(aZB[q] + bZ)));
                float n = tanhf(aNB[q] + bN + r * hN);
                if (row < N_NODES) din[(long long)row * 288 + col] = f2bf((1.0f - z) * n);
            }
        }
    }
}

// decoder layer 1: relu(din @ Wd1T + bd1), K=288, bf16 -> bf16
__global__ __launch_bounds__(256) void k_d1_mfma(const unsigned short* __restrict__ din,
        const unsigned short* __restrict__ WT, const float* __restrict__ bias,
        unsigned short* __restrict__ outbf) {
    int t = threadIdx.x;
    int wv = t >> 6, l = t & 63;
    int lr = l & 15, lg = l >> 4;
    int rb = blockIdx.x * 64 + wv * 16;
    int arow = rb + lr; if (arow >= N_NODES) arow = N_NODES - 1;
    bf16x8 af[9];
    const unsigned short* ap = din + (long long)arow * 288 + lg * 8;
#pragma unroll
    for (int ks = 0; ks < 9; ++ks) af[ks] = __builtin_bit_cast(bf16x8, *(const u16x8*)(ap + ks * 32));
    f32x4 acc[16];
#pragma unroll
    for (int ct = 0; ct < 16; ++ct) acc[ct] = (f32x4){0.f, 0.f, 0.f, 0.f};
    for (int ct = 0; ct < 16; ++ct) {
        const unsigned short* wr = WT + (ct * 16 + lr) * 288 + lg * 8;
#pragma unroll
        for (int ks = 0; ks < 9; ++ks) {
            bf16x8 bfv = __builtin_bit_cast(bf16x8, *(const u16x8*)(wr + ks * 32));
            acc[ct] = __builtin_amdgcn_mfma_f32_16x16x32_bf16(af[ks], bfv, acc[ct], 0, 0, 0);
        }
    }
#pragma unroll
    for (int ct = 0; ct < 16; ++ct) {
        int col = ct * 16 + lr;
        float bb = bias[col];
#pragma unroll
        for (int q = 0; q < 4; ++q) {
            int row = rb + lg * 4 + q;
            if (row < N_NODES) {
                float v = fmaxf(acc[ct][q] + bb, 0.0f);
                outbf[(long long)row * H + col] = f2bf(v);
            }
        }
    }
}

// decoder layers 2+3: d2 = relu(d1 @ Wd2T + bd2) [N=128]; pred = clip(d2 @ Wd3 + bd3)
__global__ __launch_bounds__(256) void k_d23_mfma(const unsigned short* __restrict__ d1,
        const unsigned short* __restrict__ WT, const float* __restrict__ bd2,
        const float* __restrict__ Wd3, const float* __restrict__ bd3, float* __restrict__ out) {
    int t = threadIdx.x;
    int wv = t >> 6, l = t & 63;
    int lr = l & 15, lg = l >> 4;
    int rb = blockIdx.x * 64 + wv * 16;
    int arow = rb + lr; if (arow >= N_NODES) arow = N_NODES - 1;
    bf16x8 af[8];
    const unsigned short* ap = d1 + (long long)arow * H + lg * 8;
#pragma unroll
    for (int ks = 0; ks < 8; ++ks) af[ks] = __builtin_bit_cast(bf16x8, *(const u16x8*)(ap + ks * 32));
    f32x4 acc[8];
#pragma unroll
    for (int ct = 0; ct < 8; ++ct) acc[ct] = (f32x4){0.f, 0.f, 0.f, 0.f};
    for (int ct = 0; ct < 8; ++ct) {
        const unsigned short* wr = WT + (ct * 16 + lr) * H + lg * 8;
#pragma unroll
        for (int ks = 0; ks < 8; ++ks) {
            bf16x8 bfv = __builtin_bit_cast(bf16x8, *(const u16x8*)(wr + ks * 32));
            acc[ct] = __builtin_amdgcn_mfma_f32_16x16x32_bf16(af[ks], bfv, acc[ct], 0, 0, 0);
        }
    }
    float p0[4] = {0.f, 0.f, 0.f, 0.f}, p1[4] = {0.f, 0.f, 0.f, 0.f};
#pragma unroll
    for (int ct = 0; ct < 8; ++ct) {
        int col = ct * 16 + lr;
        float bb = bd2[col];
        float2 w3 = *(const float2*)(Wd3 + col * 2);
#pragma unroll
        for (int q = 0; q < 4; ++q) {
            float v = fmaxf(acc[ct][q] + bb, 0.0f);
            p0[q] = fmaf(v, w3.x, p0[q]);
            p1[q] = fmaf(v, w3.y, p1[q]);
        }
    }
#pragma unroll
    for (int q = 0; q < 4; ++q) {
#pragma unroll
        for (int m = 1; m < 16; m <<= 1) {
            p0[q] += __shfl_xor(p0[q], m, 64);
            p1[q] += __shfl_xor(p1[q], m, 64);
        }
    }
    if (lr == 0) {
#pragma unroll
        for (int q = 0; q < 4; ++q) {
            int row = rb + lg * 4 + q;
            if (row < N_NODES) {
                float a = fminf(fmaxf(p0[q] + bd3[0], -5.0f), 5.0f);
                float b = fminf(fmaxf(p1[q] + bd3[1], -5.0f), 5.0f);
                out[(long long)row * 2] = a;
                out[(long long)row * 2 + 1] = b;
            }
        }
    }
}

extern "C" void kernel_launch(void* const* d_in, const int* in_sizes, int n_in,
                              void* d_out, int out_size, void* d_ws, size_t ws_size,
                              hipStream_t stream) {
    const float* x   = (const float*)d_in[0];
    const void*  ei  = d_in[1];
    const float* ew  = (const float*)d_in[2];
    const float* W1  = (const float*)d_in[3];
    const float* b1  = (const float*)d_in[4];
    const float* g1  = (const float*)d_in[5];
    const float* be1 = (const float*)d_in[6];
    const float* W2  = (const float*)d_in[7];
    const float* b2  = (const float*)d_in[8];
    const float* g2  = (const float*)d_in[9];
    const float* be2 = (const float*)d_in[10];
    const float* Wih = (const float*)d_in[11];
    const float* bih = (const float*)d_in[13];
    const float* bhh = (const float*)d_in[14];
    const float* Wd1 = (const float*)d_in[15];
    const float* bd1 = (const float*)d_in[16];
    const float* Wd2 = (const float*)d_in[17];
    const float* bd2 = (const float*)d_in[18];
    const float* Wd3 = (const float*)d_in[19];
    const float* bd3 = (const float*)d_in[20];
    float* out = (float*)d_out;

    char* w = (char*)d_ws;
    size_t pos = 0;
    auto carve = [&](size_t bytes) -> void* {
        void* p = w + pos;
        pos += (bytes + 255) & ~(size_t)255;
        return p;
    };
    int*   flag   = (int*)carve(4);
    int*   bsize  = (int*)carve(sizeof(int) * 512);
    int*   bstart = (int*)carve(sizeof(int) * (NB + 1));
    int*   bcursor= (int*)carve(sizeof(int) * 512);
    float* dis    = (float*)carve(sizeof(float) * N_NODES);
    int*   cnt    = (int*)carve(sizeof(int) * N_NODES);
    int*   offs   = (int*)carve(sizeof(int) * (N_NODES + 1));
    int*   bsum   = (int*)carve(sizeof(int) * 64);
    int*   bsoff  = (int*)carve(sizeof(int) * 64);
    unsigned long long* stage = (unsigned long long*)carve(8 * (size_t)N_EDGES);
    unsigned long long* csr   = (unsigned long long*)carve(8 * (size_t)N_EDGES);
    unsigned short* xpb  = (unsigned short*)carve(2 * (size_t)N_NODES * DIN);
    unsigned short* Wg   = (unsigned short*)carve(2 * 768 * 256);
    unsigned short* W2T  = (unsigned short*)carve(2 * 256 * 256);
    unsigned short* Wd1T = (unsigned short*)carve(2 * 256 * 288);
    unsigned short* Wd2T = (unsigned short*)carve(2 * 128 * 256);
    float* agg0  = (float*)carve(sizeof(float) * (size_t)N_NODES * DIN);
    unsigned short* Abf = (unsigned short*)carve(2 * (size_t)N_NODES * H);  // h1p bf16
    unsigned short* Bbf = (unsigned short*)carve(2 * (size_t)N_NODES * H);  // agg2 bf16
    unsigned short* din = (unsigned short*)carve(2 * (size_t)N_NODES * 288); // [temporal, x] bf16
    unsigned short* h2bf = Abf;   // after spmm consumed Abf
    unsigned short* d1bf = Bbf;   // after ln_mfma consumed Bbf
    (void)pos; (void)ws_size; (void)in_sizes; (void)n_in; (void)out_size;

    int gN = (N_NODES + 255) / 256;
    int nscan = (N_NODES + 1023) / 1024;  // 49
    int nbm = (N_NODES + 63) / 64;        // 782 blocks for 16-row/wave MFMA kernels
    int nbg = (N_NODES + 127) / 128;      // 391 blocks for 32-row/wave GRU

    k_detect<<<1, 1, 0, stream>>>(ei, flag);
    k_zeroi<<<2, 256, 0, stream>>>(bsize, 512);
    k_bucketcnt<<<NTILES, 256, 0, stream>>>(ei, flag, bsize);
    k_bscan<<<1, 256, 0, stream>>>(bsize, bstart, bcursor);
    k_msplit<<<NTILES, 256, 0, stream>>>(ei, flag, ew, bcursor, stage);
    k_bstat<<<NB, 256, 0, stream>>>(stage, bstart, cnt, dis);
    k_xpb<<<(N_NODES * DIN + 255) / 256, 256, 0, stream>>>(x, dis, xpb);
    k_scan1<<<nscan, 256, 0, stream>>>(cnt, bsum);
    k_scan2<<<1, 64, 0, stream>>>(bsum, bsoff, offs, nscan);
    k_scan3<<<nscan, 256, 0, stream>>>(cnt, bsoff, offs);
    k_fine<<<NB, 256, 0, stream>>>(stage, bstart, offs, csr);
    k_wihbf<<<(768 * 256 + 255) / 256, 256, 0, stream>>>(Wih, Wg);
    k_w2t<<<(256 * 256 + 255) / 256, 256, 0, stream>>>(W2, W2T);
    k_wd1t<<<(256 * 288 + 255) / 256, 256, 0, stream>>>(Wd1, Wd1T);
    k_wd2t<<<(256 * 128 + 255) / 256, 256, 0, stream>>>(Wd2, Wd2T);

    k_agg0<<<N_NODES / 16, 256, 0, stream>>>(xpb, offs, csr, dis, agg0);
    k_gemm_ln<DIN, true><<<N_NODES / RPB, 256, 0, stream>>>(agg0, Abf, W1, b1, g1, be1, dis);
    k_spmm<<<N_NODES / 4, 256, 0, stream>>>(Abf, Bbf, offs, csr, dis);
    k_ln_mfma<<<nbm, 256, 0, stream>>>(Bbf, W2T, b2, g2, be2, h2bf);    // Abf dead -> h2bf
    k_xfill<<<(N_NODES * 32 + 255) / 256, 256, 0, stream>>>(x, din);
    k_gru_mfma<<<nbg, 256, 0, stream>>>(h2bf, Wg, bih, bhh, din);
    k_d1_mfma<<<nbm, 256, 0, stream>>>(din, Wd1T, bd1, d1bf);           // Bbf dead -> d1bf
    k_d23_mfma<<<nbm, 256, 0, stream>>>(d1bf, Wd2T, bd2, Wd3, bd3, out);
}

// Round 7
// 492.084 us; speedup vs baseline: 2.8561x; 1.1026x over previous
//
#include <hip/hip_runtime.h>
#include <math.h>

#define N_NODES 50000
#define N_EDGES 1600000
#define DIN 16
#define H 256
#define RPB 16
#define LN_EPS 1e-5f
#define FIXS 8388608.0f   // 2^23
#define NB 391            // buckets of 128 dst nodes
#define TILEA 4096
#define NTILES 391        // ceil(1.6M / 4096)
#define GRU_COLS 48       // 3 gates x 16 cols per ct step
#define GRU_STR 272       // LDS col stride in shorts (16B-aligned, +16B pad)

typedef __attribute__((ext_vector_type(8))) unsigned short u16x8;
typedef __attribute__((ext_vector_type(8))) __bf16 bf16x8;
typedef __attribute__((ext_vector_type(4))) float f32x4;

__device__ inline unsigned short f2bf(float f) {
    unsigned u = __builtin_bit_cast(unsigned, f);
    return (unsigned short)((u + 0x7FFFu + ((u >> 16) & 1u)) >> 16);
}
__device__ inline float bf2f(unsigned short u) {
    return __builtin_bit_cast(float, ((unsigned)u) << 16);
}
__device__ inline float fsig(float x) { return 1.0f / (1.0f + __expf(-x)); }
__device__ inline float ftanh(float x) { return 2.0f / (1.0f + __expf(-2.0f * x)) - 1.0f; }

// ---------------- edge dtype detect ----------------
__global__ void k_detect(const void* ei, int* flag) {
    const long long* p = (const long long*)ei;
    bool is64 = true;
    for (int i = 0; i < 8; ++i) {
        long long v = p[i];
        if (v < 0 || v >= N_NODES) is64 = false;
    }
    *flag = is64 ? 1 : 0;
}

__global__ void k_zeroi(int* p, int n) {
    int i = blockIdx.x * blockDim.x + threadIdx.x;
    if (i < n) p[i] = 0;
}

// ---------------- bucket counts (LDS-aggregated) ----------------
__global__ __launch_bounds__(256) void k_bucketcnt(const void* ei, const int* flag, int* bsize) {
    __shared__ int bh[512];
    int t = threadIdx.x;
    long long base = (long long)blockIdx.x * TILEA;
    for (int i = t; i < 512; i += 256) bh[i] = 0;
    __syncthreads();
    bool f64 = (*flag != 0);
#pragma unroll
    for (int k = 0; k < TILEA / 256; ++k) {
        long long e = base + k * 256 + t;
        if (e < N_EDGES) {
            int d = f64 ? (int)((const long long*)ei)[N_EDGES + e] : ((const int*)ei)[N_EDGES + e];
            atomicAdd(&bh[d >> 7], 1);
        }
    }
    __syncthreads();
    for (int i = t; i < 512; i += 256)
        if (bh[i]) atomicAdd(&bsize[i], bh[i]);
}

// ---------------- scan bucket sizes -> bstart, bcursor (single block) ----------------
__global__ __launch_bounds__(256) void k_bscan(const int* bsize, int* bstart, int* bcursor) {
    __shared__ int bh[512], bscn[512];
    __shared__ int ws4[4];
    int t = threadIdx.x;
    bh[2 * t]     = (2 * t < NB)     ? bsize[2 * t]     : 0;
    bh[2 * t + 1] = (2 * t + 1 < NB) ? bsize[2 * t + 1] : 0;
    __syncthreads();
    int a0 = bh[2 * t], a1 = bh[2 * t + 1];
    int s = a0 + a1;
    int lane = t & 63, wv = t >> 6;
    int sc = s;
    for (int d = 1; d < 64; d <<= 1) { int u = __shfl_up(sc, d, 64); if (lane >= d) sc += u; }
    if (lane == 63) ws4[wv] = sc;
    __syncthreads();
    int wpre = 0;
    for (int i = 0; i < wv; ++i) wpre += ws4[i];
    int excl = wpre + sc - s;
    bscn[2 * t] = excl;
    bscn[2 * t + 1] = excl + a0;
    __syncthreads();
    for (int i = t; i < NB; i += 256) { bstart[i] = bscn[i]; bcursor[i] = bscn[i]; }
    if (t == 0) bstart[NB] = N_EDGES;
}

// ---------------- phase A: multisplit edges into bucket-contiguous staging ----------------
// packed u64 = ew(32) << 32 | dstlow7 << 16 | src(16)
__global__ __launch_bounds__(256) void k_msplit(const void* ei, const int* flag, const float* ew,
                                                int* bcursor, unsigned long long* stage) {
    __shared__ int bh[512], bscn[512], cur[512], gbase[512];
    __shared__ int ws4[4];
    __shared__ unsigned long long sdata[TILEA];
    __shared__ unsigned short sbkt[TILEA];
    int t = threadIdx.x;
    long long base = (long long)blockIdx.x * TILEA;
    int nhere = (int)(((long long)N_EDGES - base) < TILEA ? (N_EDGES - base) : TILEA);
    for (int i = t; i < 512; i += 256) bh[i] = 0;
    __syncthreads();
    bool f64 = (*flag != 0);
    unsigned long long vreg[TILEA / 256];
    int breg[TILEA / 256];
#pragma unroll
    for (int k = 0; k < TILEA / 256; ++k) {
        long long e = base + k * 256 + t;
        if (e < N_EDGES) {
            int s, d;
            if (f64) {
                const long long* p = (const long long*)ei;
                s = (int)p[e]; d = (int)p[N_EDGES + e];
            } else {
                const int* p = (const int*)ei;
                s = p[e]; d = p[N_EDGES + e];
            }
            unsigned wbits = __builtin_bit_cast(unsigned, ew[e]);
            vreg[k] = ((unsigned long long)wbits << 32) |
                      ((unsigned long long)(d & 127) << 16) | (unsigned)(s & 0xFFFF);
            breg[k] = d >> 7;
            atomicAdd(&bh[breg[k]], 1);
        } else breg[k] = -1;
    }
    __syncthreads();
    // block exclusive scan over 512 entries
    int a0 = bh[2 * t], a1 = bh[2 * t + 1];
    int s = a0 + a1;
    int lane = t & 63, wv = t >> 6;
    int sc = s;
    for (int d = 1; d < 64; d <<= 1) { int u = __shfl_up(sc, d, 64); if (lane >= d) sc += u; }
    if (lane == 63) ws4[wv] = sc;
    __syncthreads();
    int wpre = 0;
    for (int i = 0; i < wv; ++i) wpre += ws4[i];
    int excl = wpre + sc - s;
    bscn[2 * t] = excl;      cur[2 * t] = excl;
    bscn[2 * t + 1] = excl + a0; cur[2 * t + 1] = excl + a0;
    __syncthreads();
    // reserve global space per bucket
    for (int i = t; i < NB; i += 256) {
        int c = bh[i];
        if (c) gbase[i] = atomicAdd(&bcursor[i], c);
    }
    __syncthreads();
    // local scatter into LDS (grouped by bucket)
#pragma unroll
    for (int k = 0; k < TILEA / 256; ++k) {
        if (breg[k] >= 0) {
            int p = atomicAdd(&cur[breg[k]], 1);
            sdata[p] = vreg[k];
            sbkt[p] = (unsigned short)breg[k];
        }
    }
    __syncthreads();
    // coalesced-ish writeout: consecutive LDS slots of same bucket -> consecutive global
    for (int i = t; i < nhere; i += 256) {
        int b = sbkt[i];
        stage[(long long)gbase[b] + (i - bscn[b])] = sdata[i];
    }
}

// ---------------- phase B1: per-bucket degree/count (no global atomics) ----------------
__global__ __launch_bounds__(256) void k_bstat(const unsigned long long* __restrict__ stage,
                                               const int* __restrict__ bstart,
                                               int* __restrict__ cnt, float* __restrict__ dis) {
    __shared__ unsigned long long acc[128];
    int b = blockIdx.x, t = threadIdx.x;
    if (t < 128) acc[t] = 0ULL;
    __syncthreads();
    int e0 = bstart[b], e1 = bstart[b + 1];
    for (int i = e0 + t; i < e1; i += 256) {
        unsigned long long v = stage[i];
        int nl = (int)((v >> 16) & 127);
        float w = __builtin_bit_cast(float, (unsigned)(v >> 32));
        atomicAdd(&acc[nl], (1ULL << 43) | (unsigned long long)llrintf(w * FIXS));
    }
    __syncthreads();
    if (t < 128) {
        int node = (b << 7) + t;
        if (node < N_NODES) {
            unsigned long long v = acc[t];
            cnt[node] = (int)(v >> 43);
            dis[node] = rsqrtf((float)(v & ((1ULL << 43) - 1)) * (1.0f / FIXS) + 2.0f);
        }
    }
}

// ---------------- phase B2: fine placement within bucket (L2-local scatter) ----------------
__global__ __launch_bounds__(256) void k_fine(const unsigned long long* __restrict__ stage,
                                              const int* __restrict__ bstart,
                                              const int* __restrict__ offs,
                                              unsigned long long* __restrict__ csr) {
    __shared__ int cur[128];
    int b = blockIdx.x, t = threadIdx.x;
    int e0 = bstart[b], e1 = bstart[b + 1];
    if (t < 128) {
        int node = (b << 7) + t;
        cur[t] = (node < N_NODES) ? (offs[node] - e0) : 0;
    }
    __syncthreads();
    for (int i = e0 + t; i < e1; i += 256) {
        unsigned long long v = stage[i];
        int nl = (int)((v >> 16) & 127);
        int p = atomicAdd(&cur[nl], 1);
        csr[(long long)e0 + p] = v;
    }
}

// ---------------- xp = bf16(dis[i] * x[i]) ----------------
__global__ void k_xpb(const float* x, const float* dis, unsigned short* xpb) {
    int idx = blockIdx.x * blockDim.x + threadIdx.x;
    if (idx >= N_NODES * DIN) return;
    xpb[idx] = f2bf(dis[idx >> 4] * x[idx]);
}

// ---------------- exclusive scan of cnt -> offs (chunk 1024) ----------------
__global__ void k_scan1(const int* cnt, int* bsum) {
    __shared__ int ws_[4];
    int b = blockIdx.x, t = threadIdx.x;
    int s = 0;
    for (int k = 0; k < 4; ++k) {
        int idx = b * 1024 + k * 256 + t;
        if (idx < N_NODES) s += cnt[idx];
    }
    for (int d = 32; d; d >>= 1) s += __shfl_down(s, d, 64);
    if ((t & 63) == 0) ws_[t >> 6] = s;
    __syncthreads();
    if (t == 0) bsum[b] = ws_[0] + ws_[1] + ws_[2] + ws_[3];
}

__global__ void k_scan2(const int* bsum, int* bsoff, int* offs, int nblk) {
    if (threadIdx.x == 0) {
        int run = 0;
        for (int i = 0; i < nblk; ++i) { bsoff[i] = run; run += bsum[i]; }
        offs[N_NODES] = run;
    }
}

__global__ void k_scan3(const int* cnt, const int* bsoff, int* offs) {
    __shared__ int wsum[4];
    int b = blockIdx.x, t = threadIdx.x;
    int lane = t & 63, wv = t >> 6;
    int base = b * 1024 + t * 4;
    int v[4];
    for (int k = 0; k < 4; ++k) {
        int idx = base + k;
        v[k] = (idx < N_NODES) ? cnt[idx] : 0;
    }
    int ts = v[0] + v[1] + v[2] + v[3];
    int sc = ts;
    for (int d = 1; d < 64; d <<= 1) {
        int u = __shfl_up(sc, d, 64);
        if (lane >= d) sc += u;
    }
    if (lane == 63) wsum[wv] = sc;
    __syncthreads();
    int wpre = 0;
    for (int i = 0; i < wv; ++i) wpre += wsum[i];
    int ex = wpre + sc - ts + bsoff[b];
    for (int k = 0; k < 4; ++k) {
        int idx = base + k;
        if (idx < N_NODES) offs[idx] = ex;
        ex += v[k];
    }
}

// ---------------- weight prep: fp32 -> bf16 (with transpose where needed) ----------------
__global__ void k_wihbf(const float* Wih, unsigned short* Wg) {
    int idx = blockIdx.x * blockDim.x + threadIdx.x;
    if (idx < 768 * 256) Wg[idx] = f2bf(Wih[idx]);   // already [out_col][k]
}

__global__ void k_w2t(const float* W2, unsigned short* W2T) {  // W2[k][n] -> W2T[n][k]
    int idx = blockIdx.x * blockDim.x + threadIdx.x;
    if (idx >= 256 * 256) return;
    int k = idx >> 8, n = idx & 255;
    W2T[n * 256 + k] = f2bf(W2[idx]);
}

__global__ void k_wd1t(const float* Wd1, unsigned short* T) {  // Wd1[272][256] -> T[n][288] (k padded)
    int idx = blockIdx.x * blockDim.x + threadIdx.x;
    if (idx >= 256 * 288) return;
    int n = idx / 288, k = idx % 288;
    T[idx] = (k < 272) ? f2bf(Wd1[k * 256 + n]) : (unsigned short)0;
}

__global__ void k_wd2t(const float* Wd2, unsigned short* T) {  // Wd2[256][128] -> T[n][256]
    int idx = blockIdx.x * blockDim.x + threadIdx.x;
    if (idx >= 256 * 128) return;
    int k = idx >> 7, n = idx & 127;
    T[n * 256 + k] = f2bf(Wd2[idx]);
}

// fill decoder-input x columns: din[row][256+j] = bf16(x[row][j]) (j<16), 0 pad to 288
__global__ void k_xfill(const float* x, unsigned short* din) {
    int idx = blockIdx.x * blockDim.x + threadIdx.x;
    if (idx >= N_NODES * 32) return;
    int row = idx >> 5, j = idx & 31;
    din[(long long)row * 288 + 256 + j] = (j < 16) ? f2bf(x[row * DIN + j]) : (unsigned short)0;
}

// ---------------- aggregation in DIN space (layer 1): agg = dis[r]*sum(ew*xp[s]) + 2*dis[r]*xp[r] ----------------
__global__ __launch_bounds__(256) void k_agg0(const unsigned short* __restrict__ xpb,
                                              const int* __restrict__ offs,
                                              const unsigned long long* __restrict__ csr,
                                              const float* __restrict__ dis, float* __restrict__ agg0) {
    int t = threadIdx.x;
    int r = blockIdx.x * 16 + (t >> 4);
    int dd = t & 15;
    float di = dis[r];
    float xself = bf2f(xpb[(long long)r * DIN + dd]);
    float acc = 0.0f;
    int e0 = offs[r], e1 = offs[r + 1];
    for (int e = e0; e < e1; e += 8) {
        unsigned long long vv[8];
#pragma unroll
        for (int j = 0; j < 8; ++j) {
            int idx = e + j;
            vv[j] = (idx < e1) ? csr[idx] : (unsigned long long)(unsigned)r;  // ew bits = 0
        }
        float xx[8];
#pragma unroll
        for (int j = 0; j < 8; ++j) {
            int s = (int)(vv[j] & 0xFFFFu);
            xx[j] = bf2f(xpb[(long long)s * DIN + dd]);
        }
#pragma unroll
        for (int j = 0; j < 8; ++j) {
            float c = __builtin_bit_cast(float, (unsigned)(vv[j] >> 32));
            acc = fmaf(c, xx[j], acc);
        }
    }
    agg0[(long long)r * DIN + dd] = di * acc + 2.0f * di * xself;
}

// ---------------- SpMM in H space: out = dis[d]*sum(ew*h1p[s]) + 2*dis[d]*h1p[d] ----------------
__global__ __launch_bounds__(256) void k_spmm(const unsigned short* __restrict__ hin,
                                              unsigned short* __restrict__ hout,
                                              const int* __restrict__ offs,
                                              const unsigned long long* __restrict__ csr,
                                              const float* __restrict__ dis) {
    int t = threadIdx.x;
    int wv = t >> 6, lane = t & 63;
    int row = blockIdx.x * 4 + wv;
    const ushort4* h4 = (const ushort4*)hin;
    float di = dis[row];
    ushort4 vs = h4[(long long)row * 64 + lane];
    float a0 = 0.f, a1 = 0.f, a2 = 0.f, a3 = 0.f;
    int e0 = offs[row], e1 = offs[row + 1];
    for (int e = e0; e < e1; e += 8) {
        unsigned long long vv[8];
#pragma unroll
        for (int j = 0; j < 8; ++j) {
            int idx = e + j;
            vv[j] = (idx < e1) ? csr[idx] : (unsigned long long)(unsigned)row;
        }
        ushort4 uu[8];
#pragma unroll
        for (int j = 0; j < 8; ++j) {
            int s = (int)(vv[j] & 0xFFFFu);
            uu[j] = h4[(long long)s * 64 + lane];
        }
#pragma unroll
        for (int j = 0; j < 8; ++j) {
            float c = __builtin_bit_cast(float, (unsigned)(vv[j] >> 32));
            a0 = fmaf(c, bf2f(uu[j].x), a0);
            a1 = fmaf(c, bf2f(uu[j].y), a1);
            a2 = fmaf(c, bf2f(uu[j].z), a2);
            a3 = fmaf(c, bf2f(uu[j].w), a3);
        }
    }
    ushort4 o;
    o.x = f2bf(di * a0 + 2.0f * di * bf2f(vs.x));
    o.y = f2bf(di * a1 + 2.0f * di * bf2f(vs.y));
    o.z = f2bf(di * a2 + 2.0f * di * bf2f(vs.z));
    o.w = f2bf(di * a3 + 2.0f * di * bf2f(vs.w));
    ((ushort4*)hout)[(long long)row * 64 + lane] = o;
}

// ---------------- layer-1 GEMM (16 -> 256) + bias + LN + relu, out scaled by dis (h1p) ----------------
template <int K, bool RELU>
__global__ __launch_bounds__(256) void k_gemm_ln(const float* in, unsigned short* out, const float* W,
                                                 const float* bias, const float* g, const float* be,
                                                 const float* dis) {
    __shared__ float s[RPB][H + 1];
    __shared__ float smu[RPB], srs[RPB];
    int t = threadIdx.x;
    long long rowbase = (long long)blockIdx.x * RPB;
    for (int idx = t; idx < RPB * K; idx += 256) {
        int r = idx / K, k = idx % K;
        s[r][k] = in[(rowbase + r) * K + k];
    }
    __syncthreads();
    float acc[RPB];
    float bb0 = bias[t];
#pragma unroll
    for (int r = 0; r < RPB; ++r) acc[r] = bb0;
    for (int k = 0; k < K; ++k) {
        float wv = W[k * H + t];
#pragma unroll
        for (int r = 0; r < RPB; ++r) acc[r] = fmaf(s[r][k], wv, acc[r]);
    }
    __syncthreads();
#pragma unroll
    for (int r = 0; r < RPB; ++r) s[r][t] = acc[r];
    __syncthreads();
    int lane = t & 63, wv2 = t >> 6;
    for (int rr = wv2; rr < RPB; rr += 4) {
        float v0 = s[rr][lane], v1 = s[rr][lane + 64], v2 = s[rr][lane + 128], v3 = s[rr][lane + 192];
        float sm = v0 + v1 + v2 + v3;
        float sq = v0 * v0 + v1 * v1 + v2 * v2 + v3 * v3;
        for (int d = 32; d; d >>= 1) {
            sm += __shfl_down(sm, d, 64);
            sq += __shfl_down(sq, d, 64);
        }
        if (lane == 0) {
            float mu = sm * (1.0f / H);
            float var = sq * (1.0f / H) - mu * mu;
            smu[rr] = mu;
            srs[rr] = rsqrtf(var + LN_EPS);
        }
    }
    __syncthreads();
    float gg = g[t], bb = be[t];
#pragma unroll
    for (int r = 0; r < RPB; ++r) {
        float h = (acc[r] - smu[r]) * srs[r] * gg + bb;
        if (RELU) h = fmaxf(h, 0.0f);
        out[(rowbase + r) * H + t] = f2bf(h * dis[rowbase + r]);
    }
}

// ---------------- MFMA row-GEMM kernels ----------------
// frag layout (16x16x32 bf16): A lane l: row l&15, k=8*(l>>4)+j ; B lane l: col l&15, same k ;
// D lane l: col l&15, row 4*(l>>4)+reg

// layer-2 GEMM + bias + LN, bf16 in -> bf16 out
__global__ __launch_bounds__(256) void k_ln_mfma(const unsigned short* __restrict__ in,
        const unsigned short* __restrict__ WT, const float* __restrict__ bias,
        const float* __restrict__ g, const float* __restrict__ be,
        unsigned short* __restrict__ outbf) {
    int t = threadIdx.x;
    int wv = t >> 6, l = t & 63;
    int lr = l & 15, lg = l >> 4;
    int rb = blockIdx.x * 64 + wv * 16;
    int arow = rb + lr; if (arow >= N_NODES) arow = N_NODES - 1;
    bf16x8 af[8];
    const unsigned short* ap = in + (long long)arow * H + lg * 8;
#pragma unroll
    for (int ks = 0; ks < 8; ++ks) af[ks] = __builtin_bit_cast(bf16x8, *(const u16x8*)(ap + ks * 32));
    f32x4 acc[16];
#pragma unroll
    for (int ct = 0; ct < 16; ++ct) acc[ct] = (f32x4){0.f, 0.f, 0.f, 0.f};
    for (int ct = 0; ct < 16; ++ct) {
        const unsigned short* wr = WT + (ct * 16 + lr) * H + lg * 8;
#pragma unroll
        for (int ks = 0; ks < 8; ++ks) {
            bf16x8 bfv = __builtin_bit_cast(bf16x8, *(const u16x8*)(wr + ks * 32));
            acc[ct] = __builtin_amdgcn_mfma_f32_16x16x32_bf16(af[ks], bfv, acc[ct], 0, 0, 0);
        }
    }
#pragma unroll
    for (int ct = 0; ct < 16; ++ct) {
        float bb = bias[ct * 16 + lr];
#pragma unroll
        for (int q = 0; q < 4; ++q) acc[ct][q] += bb;
    }
    float mean[4], rstd[4];
#pragma unroll
    for (int q = 0; q < 4; ++q) {
        float s = 0.f, s2 = 0.f;
#pragma unroll
        for (int ct = 0; ct < 16; ++ct) { float v = acc[ct][q]; s += v; s2 += v * v; }
#pragma unroll
        for (int m = 1; m < 16; m <<= 1) { s += __shfl_xor(s, m, 64); s2 += __shfl_xor(s2, m, 64); }
        float mu = s * (1.0f / H);
        mean[q] = mu;
        rstd[q] = rsqrtf(s2 * (1.0f / H) - mu * mu + LN_EPS);
    }
#pragma unroll
    for (int ct = 0; ct < 16; ++ct) {
        int col = ct * 16 + lr;
        float gg = g[col], bb = be[col];
#pragma unroll
        for (int q = 0; q < 4; ++q) {
            int row = rb + lg * 4 + q;
            if (row < N_NODES) {
                float nv = (acc[ct][q] - mean[q]) * rstd[q] * gg + bb;
                outbf[(long long)row * H + col] = f2bf(nv);
            }
        }
    }
}

// GRU step (h0=0): out = (1-z)*n; block-cooperative LDS-staged weights, double-buffered.
// Block: 4 waves x 16 rows = 64 rows. 16 ct-steps of (3 gates x 16 cols).
__global__ __launch_bounds__(256) void k_gru_lds(const unsigned short* __restrict__ h2,
        const unsigned short* __restrict__ Wg, const float* __restrict__ bih,
        const float* __restrict__ bhh, unsigned short* __restrict__ din) {
    __shared__ unsigned short wbuf[2][GRU_COLS * GRU_STR];
    int t = threadIdx.x;
    int wv = t >> 6, l = t & 63;
    int lr = l & 15, lg = l >> 4;
    int rb = blockIdx.x * 64 + wv * 16;
    int arow = rb + lr; if (arow >= N_NODES) arow = N_NODES - 1;
    bf16x8 af[8];
    const unsigned short* ap = h2 + (long long)arow * H + lg * 8;
#pragma unroll
    for (int ks = 0; ks < 8; ++ks) af[ks] = __builtin_bit_cast(bf16x8, *(const u16x8*)(ap + ks * 32));

    // stage weight tile for ct into buffer b: 48 cols x 512B, coalesced
    auto stage = [&](int ct, int b) {
#pragma unroll
        for (int j = 0; j < 6; ++j) {
            int i = t + j * 256;          // 0..1535
            int col = i >> 5;             // 0..47 (gate*16 + c)
            int off = (i & 31) * 8;       // shorts
            int gate = col >> 4, c = col & 15;
            u16x8 v = *(const u16x8*)(Wg + ((gate * 256 + ct * 16 + c) * 256 + off));
            *(u16x8*)(&wbuf[b][col * GRU_STR + off]) = v;
        }
    };
    stage(0, 0);
    __syncthreads();
    for (int ct = 0; ct < 16; ++ct) {
        if (ct < 15) stage(ct + 1, (ct + 1) & 1);
        const unsigned short* cur = wbuf[ct & 1];
        f32x4 aR = (f32x4){0.f, 0.f, 0.f, 0.f};
        f32x4 aZ = aR, aN = aR;
        const unsigned short* base = cur + lr * GRU_STR + lg * 8;
#pragma unroll
        for (int ks = 0; ks < 8; ++ks) {
            bf16x8 b0 = __builtin_bit_cast(bf16x8, *(const u16x8*)(base + ks * 32));
            bf16x8 b1 = __builtin_bit_cast(bf16x8, *(const u16x8*)(base + 16 * GRU_STR + ks * 32));
            bf16x8 b2 = __builtin_bit_cast(bf16x8, *(const u16x8*)(base + 32 * GRU_STR + ks * 32));
            aR = __builtin_amdgcn_mfma_f32_16x16x32_bf16(af[ks], b0, aR, 0, 0, 0);
            aZ = __builtin_amdgcn_mfma_f32_16x16x32_bf16(af[ks], b1, aZ, 0, 0, 0);
            aN = __builtin_amdgcn_mfma_f32_16x16x32_bf16(af[ks], b2, aN, 0, 0, 0);
        }
        int col = ct * 16 + lr;
        float bR = bih[col] + bhh[col];
        float bZ = bih[col + 256] + bhh[col + 256];
        float bN = bih[col + 512];
        float hN = bhh[col + 512];
#pragma unroll
        for (int q = 0; q < 4; ++q) {
            int row = rb + lg * 4 + q;
            float r = fsig(aR[q] + bR);
            float z = fsig(aZ[q] + bZ);
            float n = ftanh(aN[q] + bN + r * hN);
            if (row < N_NODES) din[(long long)row * 288 + col] = f2bf((1.0f - z) * n);
        }
        __syncthreads();
    }
}

// decoder layer 1: relu(din @ Wd1T + bd1), K=288, bf16 -> bf16
__global__ __launch_bounds__(256) void k_d1_mfma(const unsigned short* __restrict__ din,
        const unsigned short* __restrict__ WT, const float* __restrict__ bias,
        unsigned short* __restrict__ outbf) {
    int t = threadIdx.x;
    int wv = t >> 6, l = t & 63;
    int lr = l & 15, lg = l >> 4;
    int rb = blockIdx.x * 64 + wv * 16;
    int arow = rb + lr; if (arow >= N_NODES) arow = N_NODES - 1;
    bf16x8 af[9];
    const unsigned short* ap = din + (long long)arow * 288 + lg * 8;
#pragma unroll
    for (int ks = 0; ks < 9; ++ks) af[ks] = __builtin_bit_cast(bf16x8, *(const u16x8*)(ap + ks * 32));
    f32x4 acc[16];
#pragma unroll
    for (int ct = 0; ct < 16; ++ct) acc[ct] = (f32x4){0.f, 0.f, 0.f, 0.f};
    for (int ct = 0; ct < 16; ++ct) {
        const unsigned short* wr = WT + (ct * 16 + lr) * 288 + lg * 8;
#pragma unroll
        for (int ks = 0; ks < 9; ++ks) {
            bf16x8 bfv = __builtin_bit_cast(bf16x8, *(const u16x8*)(wr + ks * 32));
            acc[ct] = __builtin_amdgcn_mfma_f32_16x16x32_bf16(af[ks], bfv, acc[ct], 0, 0, 0);
        }
    }
#pragma unroll
    for (int ct = 0; ct < 16; ++ct) {
        int col = ct * 16 + lr;
        float bb = bias[col];
#pragma unroll
        for (int q = 0; q < 4; ++q) {
            int row = rb + lg * 4 + q;
            if (row < N_NODES) {
                float v = fmaxf(acc[ct][q] + bb, 0.0f);
                outbf[(long long)row * H + col] = f2bf(v);
            }
        }
    }
}

// decoder layers 2+3: d2 = relu(d1 @ Wd2T + bd2) [N=128]; pred = clip(d2 @ Wd3 + bd3)
__global__ __launch_bounds__(256) void k_d23_mfma(const unsigned short* __restrict__ d1,
        const unsigned short* __restrict__ WT, const float* __restrict__ bd2,
        const float* __restrict__ Wd3, const float* __restrict__ bd3, float* __restrict__ out) {
    int t = threadIdx.x;
    int wv = t >> 6, l = t & 63;
    int lr = l & 15, lg = l >> 4;
    int rb = blockIdx.x * 64 + wv * 16;
    int arow = rb + lr; if (arow >= N_NODES) arow = N_NODES - 1;
    bf16x8 af[8];
    const unsigned short* ap = d1 + (long long)arow * H + lg * 8;
#pragma unroll
    for (int ks = 0; ks < 8; ++ks) af[ks] = __builtin_bit_cast(bf16x8, *(const u16x8*)(ap + ks * 32));
    f32x4 acc[8];
#pragma unroll
    for (int ct = 0; ct < 8; ++ct) acc[ct] = (f32x4){0.f, 0.f, 0.f, 0.f};
    for (int ct = 0; ct < 8; ++ct) {
        const unsigned short* wr = WT + (ct * 16 + lr) * H + lg * 8;
#pragma unroll
        for (int ks = 0; ks < 8; ++ks) {
            bf16x8 bfv = __builtin_bit_cast(bf16x8, *(const u16x8*)(wr + ks * 32));
            acc[ct] = __builtin_amdgcn_mfma_f32_16x16x32_bf16(af[ks], bfv, acc[ct], 0, 0, 0);
        }
    }
    float p0[4] = {0.f, 0.f, 0.f, 0.f}, p1[4] = {0.f, 0.f, 0.f, 0.f};
#pragma unroll
    for (int ct = 0; ct < 8; ++ct) {
        int col = ct * 16 + lr;
        float bb = bd2[col];
        float2 w3 = *(const float2*)(Wd3 + col * 2);
#pragma unroll
        for (int q = 0; q < 4; ++q) {
            float v = fmaxf(acc[ct][q] + bb, 0.0f);
            p0[q] = fmaf(v, w3.x, p0[q]);
            p1[q] = fmaf(v, w3.y, p1[q]);
        }
    }
#pragma unroll
    for (int q = 0; q < 4; ++q) {
#pragma unroll
        for (int m = 1; m < 16; m <<= 1) {
            p0[q] += __shfl_xor(p0[q], m, 64);
            p1[q] += __shfl_xor(p1[q], m, 64);
        }
    }
    if (lr == 0) {
#pragma unroll
        for (int q = 0; q < 4; ++q) {
            int row = rb + lg * 4 + q;
            if (row < N_NODES) {
                float a = fminf(fmaxf(p0[q] + bd3[0], -5.0f), 5.0f);
                float b = fminf(fmaxf(p1[q] + bd3[1], -5.0f), 5.0f);
                out[(long long)row * 2] = a;
                out[(long long)row * 2 + 1] = b;
            }
        }
    }
}

extern "C" void kernel_launch(void* const* d_in, const int* in_sizes, int n_in,
                              void* d_out, int out_size, void* d_ws, size_t ws_size,
                              hipStream_t stream) {
    const float* x   = (const float*)d_in[0];
    const void*  ei  = d_in[1];
    const float* ew  = (const float*)d_in[2];
    const float* W1  = (const float*)d_in[3];
    const float* b1  = (const float*)d_in[4];
    const float* g1  = (const float*)d_in[5];
    const float* be1 = (const float*)d_in[6];
    const float* W2  = (const float*)d_in[7];
    const float* b2  = (const float*)d_in[8];
    const float* g2  = (const float*)d_in[9];
    const float* be2 = (const float*)d_in[10];
    const float* Wih = (const float*)d_in[11];
    const float* bih = (const float*)d_in[13];
    const float* bhh = (const float*)d_in[14];
    const float* Wd1 = (const float*)d_in[15];
    const float* bd1 = (const float*)d_in[16];
    const float* Wd2 = (const float*)d_in[17];
    const float* bd2 = (const float*)d_in[18];
    const float* Wd3 = (const float*)d_in[19];
    const float* bd3 = (const float*)d_in[20];
    float* out = (float*)d_out;

    char* w = (char*)d_ws;
    size_t pos = 0;
    auto carve = [&](size_t bytes) -> void* {
        void* p = w + pos;
        pos += (bytes + 255) & ~(size_t)255;
        return p;
    };
    int*   flag   = (int*)carve(4);
    int*   bsize  = (int*)carve(sizeof(int) * 512);
    int*   bstart = (int*)carve(sizeof(int) * (NB + 1));
    int*   bcursor= (int*)carve(sizeof(int) * 512);
    float* dis    = (float*)carve(sizeof(float) * N_NODES);
    int*   cnt    = (int*)carve(sizeof(int) * N_NODES);
    int*   offs   = (int*)carve(sizeof(int) * (N_NODES + 1));
    int*   bsum   = (int*)carve(sizeof(int) * 64);
    int*   bsoff  = (int*)carve(sizeof(int) * 64);
    unsigned long long* stage = (unsigned long long*)carve(8 * (size_t)N_EDGES);
    unsigned long long* csr   = (unsigned long long*)carve(8 * (size_t)N_EDGES);
    unsigned short* xpb  = (unsigned short*)carve(2 * (size_t)N_NODES * DIN);
    unsigned short* Wg   = (unsigned short*)carve(2 * 768 * 256);
    unsigned short* W2T  = (unsigned short*)carve(2 * 256 * 256);
    unsigned short* Wd1T = (unsigned short*)carve(2 * 256 * 288);
    unsigned short* Wd2T = (unsigned short*)carve(2 * 128 * 256);
    float* agg0  = (float*)carve(sizeof(float) * (size_t)N_NODES * DIN);
    unsigned short* Abf = (unsigned short*)carve(2 * (size_t)N_NODES * H);  // h1p bf16
    unsigned short* Bbf = (unsigned short*)carve(2 * (size_t)N_NODES * H);  // agg2 bf16
    unsigned short* din = (unsigned short*)carve(2 * (size_t)N_NODES * 288); // [temporal, x] bf16
    unsigned short* h2bf = Abf;   // after spmm consumed Abf
    unsigned short* d1bf = Bbf;   // after ln_mfma consumed Bbf
    (void)pos; (void)ws_size; (void)in_sizes; (void)n_in; (void)out_size;

    int gN = (N_NODES + 255) / 256;
    int nscan = (N_NODES + 1023) / 1024;  // 49
    int nbm = (N_NODES + 63) / 64;        // 782 blocks for 16-row/wave MFMA kernels

    k_detect<<<1, 1, 0, stream>>>(ei, flag);
    k_zeroi<<<2, 256, 0, stream>>>(bsize, 512);
    k_bucketcnt<<<NTILES, 256, 0, stream>>>(ei, flag, bsize);
    k_bscan<<<1, 256, 0, stream>>>(bsize, bstart, bcursor);
    k_msplit<<<NTILES, 256, 0, stream>>>(ei, flag, ew, bcursor, stage);
    k_bstat<<<NB, 256, 0, stream>>>(stage, bstart, cnt, dis);
    k_xpb<<<(N_NODES * DIN + 255) / 256, 256, 0, stream>>>(x, dis, xpb);
    k_scan1<<<nscan, 256, 0, stream>>>(cnt, bsum);
    k_scan2<<<1, 64, 0, stream>>>(bsum, bsoff, offs, nscan);
    k_scan3<<<nscan, 256, 0, stream>>>(cnt, bsoff, offs);
    k_fine<<<NB, 256, 0, stream>>>(stage, bstart, offs, csr);
    k_wihbf<<<(768 * 256 + 255) / 256, 256, 0, stream>>>(Wih, Wg);
    k_w2t<<<(256 * 256 + 255) / 256, 256, 0, stream>>>(W2, W2T);
    k_wd1t<<<(256 * 288 + 255) / 256, 256, 0, stream>>>(Wd1, Wd1T);
    k_wd2t<<<(256 * 128 + 255) / 256, 256, 0, stream>>>(Wd2, Wd2T);

    k_agg0<<<N_NODES / 16, 256, 0, stream>>>(xpb, offs, csr, dis, agg0);
    k_gemm_ln<DIN, true><<<N_NODES / RPB, 256, 0, stream>>>(agg0, Abf, W1, b1, g1, be1, dis);
    k_spmm<<<N_NODES / 4, 256, 0, stream>>>(Abf, Bbf, offs, csr, dis);
    k_ln_mfma<<<nbm, 256, 0, stream>>>(Bbf, W2T, b2, g2, be2, h2bf);    // Abf dead -> h2bf
    k_xfill<<<(N_NODES * 32 + 255) / 256, 256, 0, stream>>>(x, din);
    k_gru_lds<<<nbm, 256, 0, stream>>>(h2bf, Wg, bih, bhh, din);
    k_d1_mfma<<<nbm, 256, 0, stream>>>(din, Wd1T, bd1, d1bf);           // Bbf dead -> d1bf
    k_d23_mfma<<<nbm, 256, 0, stream>>>(d1bf, Wd2T, bd2, Wd3, bd3, out);
}